// Round 9
// baseline (274.861 us; speedup 1.0000x reference)
//
#include <hip/hip_runtime.h>
#include <math.h>

#define NN 65536
#define SIN 24
#define DD 64
#define HH 4
#define HDIM 16
#define NFRM 256
#define NE 1048576
#define BSZ 256
#define EPSLN 1e-5f
#define SCL 0.25f
#define RB 8
#define AKS 32   // K-splits for agg1 MFMA GEMM

typedef __attribute__((ext_vector_type(8))) short bf16x8;
typedef __attribute__((ext_vector_type(4))) float f32x4;

__device__ __forceinline__ unsigned short f2bf(float f) {
  unsigned u = __float_as_uint(f);
  return (unsigned short)((u + 0x7FFFu + ((u >> 16) & 1u)) >> 16);
}
__device__ __forceinline__ float bf2f(unsigned short b) {
  return __uint_as_float(((unsigned)b) << 16);
}
__device__ __forceinline__ float bflo(unsigned u) {
  return __uint_as_float(u << 16);
}
__device__ __forceinline__ float bfhi(unsigned u) {
  return __uint_as_float(u & 0xFFFF0000u);
}

// stage fp32 [rows][DK] -> bf16 LDS [rows][ST]
__device__ __forceinline__ void stage_f32(const float* __restrict__ src,
                                          unsigned short* dst, int n4, int DK, int ST, int tid) {
  int dk4 = DK >> 2;
  for (int idx = tid; idx < n4; idx += 256) {
    int row = idx / dk4, c = (idx % dk4) * 4;
    float4 v = *(const float4*)(src + (size_t)row * DK + c);
    uint2 p;
    p.x = (unsigned)f2bf(v.x) | ((unsigned)f2bf(v.y) << 16);
    p.y = (unsigned)f2bf(v.z) | ((unsigned)f2bf(v.w) << 16);
    *(uint2*)(dst + row * ST + c) = p;
  }
}

// stage bf16 [rows][DK] -> LDS [rows][ST]
__device__ __forceinline__ void stage_bf(const unsigned short* __restrict__ src,
                                         unsigned short* dst, int n8, int DK, int ST, int tid) {
  int dk8 = DK >> 3;
  for (int idx = tid; idx < n8; idx += 256) {
    int row = idx / dk8, c = (idx % dk8) * 8;
    *(uint4*)(dst + row * ST + c) = *(const uint4*)(src + (size_t)row * DK + c);
  }
}

// K1: h = x @ Wi + bi + pe[n % NF]
__global__ void k_input(const float* __restrict__ x, const float* __restrict__ Wi,
                        const float* __restrict__ bi, const float* __restrict__ pe,
                        float* __restrict__ h) {
  int lane = threadIdx.x & 63;
  int wid = __builtin_amdgcn_readfirstlane(threadIdx.x >> 6);
  int n0 = (blockIdx.x * 4 + wid) * RB;
  float b = bi[lane];
  float acc[RB];
#pragma unroll
  for (int r = 0; r < RB; ++r) acc[r] = b + pe[((n0 + r) & (NFRM - 1)) * DD + lane];
  for (int s = 0; s < SIN; ++s) {
    float w = Wi[s * DD + lane];
#pragma unroll
    for (int r = 0; r < RB; ++r) acc[r] += x[(size_t)(n0 + r) * SIN + s] * w;
  }
#pragma unroll
  for (int r = 0; r < RB; ++r) h[(size_t)(n0 + r) * DD + lane] = acc[r];
}

// Weight prep: transpose all dense weights to bf16 Wt[Nout][Dk]
__global__ void k_wprep(const float* __restrict__ Wo, const float* __restrict__ Wot,
                        const float* __restrict__ Wqt, const float* __restrict__ Wkt,
                        const float* __restrict__ Wvt, const float* __restrict__ W1,
                        const float* __restrict__ W2, const float* __restrict__ Wq,
                        const float* __restrict__ Wk, const float* __restrict__ Wv,
                        const float* __restrict__ Wsk, unsigned short* __restrict__ wt) {
  int i = blockIdx.x * 256 + threadIdx.x;
  if (i >= 53248) return;
  float v;
  if (i < 4096)       { int t = i;         int j = t >> 6, d = t & 63; v = Wo[d * 64 + j]; }
  else if (i < 8192)  { int t = i - 4096;  int j = t >> 6, d = t & 63; v = Wot[d * 64 + j]; }
  else if (i < 12288) { int t = i - 8192;  int j = t >> 6, d = t & 63; v = Wqt[d * 64 + j]; }
  else if (i < 16384) { int t = i - 12288; int j = t >> 6, d = t & 63; v = Wkt[d * 64 + j]; }
  else if (i < 20480) { int t = i - 16384; int j = t >> 6, d = t & 63; v = Wvt[d * 64 + j]; }
  else if (i < 28672) { int t = i - 20480; int j = t >> 6, d = t & 63; v = W1[d * 128 + j]; }
  else if (i < 36864) { int t = i - 28672; int j = t >> 7, d = t & 127; v = W2[d * 64 + j]; }
  else if (i < 40960) { int t = i - 36864; int j = t >> 6, d = t & 63; v = Wq[(j >> 4) * 1024 + d * 16 + (j & 15)]; }
  else if (i < 45056) { int t = i - 40960; int j = t >> 6, d = t & 63; v = Wk[(j >> 4) * 1024 + d * 16 + (j & 15)]; }
  else if (i < 49152) { int t = i - 45056; int j = t >> 6, d = t & 63; v = Wv[(j >> 4) * 1024 + d * 16 + (j & 15)]; }
  else                { int t = i - 49152; int j = t >> 6, d = t & 63; v = Wsk[(j >> 4) * 1024 + d * 16 + (j & 15)]; }
  wt[i] = f2bf(v);
}

// Wa1 [16384][64] fp32 -> wa1t [64][16384] bf16  (LDS-tiled transpose)
__global__ void k_wprep2(const float* __restrict__ Wa1, unsigned short* __restrict__ wa1t) {
  __shared__ float tile[64][65];
  int kb = blockIdx.x;
  int t = threadIdx.x;
  int c = t & 63, r0 = t >> 6;
  int k0 = kb * 64;
#pragma unroll
  for (int i = 0; i < 16; ++i) {
    int r = r0 + i * 4;
    tile[r][c] = Wa1[(size_t)(k0 + r) * 64 + c];
  }
  __syncthreads();
#pragma unroll
  for (int i = 0; i < 16; ++i) {
    int o = r0 + i * 4;
    wa1t[(size_t)o * 16384 + k0 + c] = f2bf(tile[c][o]);
  }
}

// K2 (MFMA): q fp32, kv packed bf16, sk fp32
__global__ void __launch_bounds__(256)
k_qkvs_m(const float* __restrict__ h, const unsigned short* __restrict__ wt,
         const float* __restrict__ bq, const float* __restrict__ bk,
         const float* __restrict__ bv, const float* __restrict__ bs,
         float* __restrict__ q, ushort2* __restrict__ kv, float* __restrict__ sk) {
  __shared__ unsigned short Xs[64 * 72];
  __shared__ unsigned short Ws4[4 * 64 * 72];
  int tid = threadIdx.x;
  int n0 = blockIdx.x * 64;
  stage_f32(h + (size_t)n0 * 64, Xs, 64 * 16, 64, 72, tid);
  stage_bf(wt + 36864, Ws4, 64 * 8, 64, 72, tid);
  stage_bf(wt + 40960, Ws4 + 4608, 64 * 8, 64, 72, tid);
  stage_bf(wt + 45056, Ws4 + 9216, 64 * 8, 64, 72, tid);
  stage_bf(wt + 49152, Ws4 + 13824, 64 * 8, 64, 72, tid);
  __syncthreads();
  int lane = tid & 63, w = tid >> 6;
  int c = lane & 15, g = lane >> 4;
  f32x4 aq[4], ak[4], av[4], as_[4];
#pragma unroll
  for (int j = 0; j < 4; ++j) {
#pragma unroll
    for (int r = 0; r < 4; ++r) { aq[j][r] = 0.f; ak[j][r] = 0.f; av[j][r] = 0.f; as_[j][r] = 0.f; }
  }
  const unsigned short* xrow = Xs + (w * 16 + c) * 72 + g * 8;
#pragma unroll
  for (int kk = 0; kk < 2; ++kk) {
    bf16x8 af = *(const bf16x8*)(xrow + kk * 32);
#pragma unroll
    for (int j = 0; j < 4; ++j) {
      int boff = (j * 16 + c) * 72 + kk * 32 + g * 8;
      aq[j] = __builtin_amdgcn_mfma_f32_16x16x32_bf16(af, *(const bf16x8*)(Ws4 + boff), aq[j], 0, 0, 0);
      ak[j] = __builtin_amdgcn_mfma_f32_16x16x32_bf16(af, *(const bf16x8*)(Ws4 + 4608 + boff), ak[j], 0, 0, 0);
      av[j] = __builtin_amdgcn_mfma_f32_16x16x32_bf16(af, *(const bf16x8*)(Ws4 + 9216 + boff), av[j], 0, 0, 0);
      as_[j] = __builtin_amdgcn_mfma_f32_16x16x32_bf16(af, *(const bf16x8*)(Ws4 + 13824 + boff), as_[j], 0, 0, 0);
    }
  }
  int rowb = n0 + w * 16 + 4 * g;
#pragma unroll
  for (int j = 0; j < 4; ++j) {
    int col = j * 16 + c;
    float bqj = bq[col], bkj = bk[col], bvj = bv[col], bsj = bs[col];
#pragma unroll
    for (int r = 0; r < 4; ++r) {
      size_t o = (size_t)(rowb + r) * 64 + col;
      q[o] = aq[j][r] + bqj;
      kv[o] = make_ushort2(f2bf(ak[j][r] + bkj), f2bf(av[j][r] + bvj));
      sk[o] = as_[j][r] + bsj;
    }
  }
}

// ---- Bucketed CSR build ----
__global__ void k_hist(const int* __restrict__ ei, int* __restrict__ hist) {
  __shared__ int h[256];
  int t = threadIdx.x;
  h[t] = 0;
  __syncthreads();
  int base = blockIdx.x * 4096;
#pragma unroll
  for (int r = 0; r < 16; ++r)
    atomicAdd(&h[ei[NE + base + r * 256 + t] >> 8], 1);
  __syncthreads();
  hist[t * 256 + blockIdx.x] = h[t];
}

__global__ void k_hscan(int* __restrict__ hist, int* __restrict__ btot) {
  __shared__ int s[256];
  int t = threadIdx.x, bkt = blockIdx.x;
  int v = hist[bkt * 256 + t];
  s[t] = v; __syncthreads();
  for (int off = 1; off < 256; off <<= 1) {
    int x = (t >= off) ? s[t - off] : 0;
    __syncthreads();
    s[t] += x;
    __syncthreads();
  }
  hist[bkt * 256 + t] = s[t] - v;
  if (t == 255) btot[bkt] = s[255];
}

__global__ void k_bscan(const int* __restrict__ btot, int* __restrict__ bbase) {
  __shared__ int s[256];
  int t = threadIdx.x;
  int v = btot[t];
  s[t] = v; __syncthreads();
  for (int off = 1; off < 256; off <<= 1) {
    int x = (t >= off) ? s[t - off] : 0;
    __syncthreads();
    s[t] += x;
    __syncthreads();
  }
  bbase[t] = s[t] - v;
}

__global__ void k_passB(const int* __restrict__ ei, const int* __restrict__ hist,
                        const int* __restrict__ bbase, int* __restrict__ pairs) {
  __shared__ int cur[256];
  int t = threadIdx.x;
  cur[t] = bbase[t] + hist[t * 256 + blockIdx.x];
  __syncthreads();
  int base = blockIdx.x * 4096;
#pragma unroll
  for (int r = 0; r < 16; ++r) {
    int e = base + r * 256 + t;
    int src = ei[e], dst = ei[NE + e];
    int pos = atomicAdd(&cur[dst >> 8], 1);
    pairs[pos] = ((dst & 255) << 16) | src;
  }
}

__global__ void k_passC(const int* __restrict__ pairs, const int* __restrict__ bbase,
                        const int* __restrict__ btot, int* __restrict__ rowptr,
                        int* __restrict__ srcs) {
  __shared__ int cnt[256];
  __shared__ int s[256];
  int t = threadIdx.x, bkt = blockIdx.x;
  cnt[t] = 0;
  __syncthreads();
  int base = bbase[bkt], n = btot[bkt];
  for (int i = t; i < n; i += 256) atomicAdd(&cnt[pairs[base + i] >> 16], 1);
  __syncthreads();
  int v = cnt[t];
  s[t] = v; __syncthreads();
  for (int off = 1; off < 256; off <<= 1) {
    int x = (t >= off) ? s[t - off] : 0;
    __syncthreads();
    s[t] += x;
    __syncthreads();
  }
  int rp = base + s[t] - v;
  rowptr[bkt * 256 + t] = rp;
  if (bkt == 0 && t == 0) rowptr[NN] = NE;
  __syncthreads();
  cnt[t] = rp;
  __syncthreads();
  for (int i = t; i < n; i += 256) {
    int p = pairs[base + i];
    int pos = atomicAdd(&cnt[p >> 16], 1);
    srcs[pos] = p & 0xFFFF;
  }
}

// Graph attention v3: wave per dst, lane = e*4+h. LDS-free: register
// reduce-scatter butterfly over e-lane bits; lane ends with dim h*16+bitrev4(e).
__global__ void __launch_bounds__(256)
k_gattn(const float* __restrict__ q, const unsigned* __restrict__ kv,
        const int* __restrict__ rowptr, const int* __restrict__ srcs,
        const float* __restrict__ sk, float* __restrict__ tmp) {
  int wid = threadIdx.x >> 6, lane = threadIdx.x & 63;
  int dst = (blockIdx.x << 2) + wid;
  int e = lane >> 2, h = lane & 3;
  float qv[16];
#pragma unroll
  for (int i = 0; i < 4; ++i)
    ((float4*)qv)[i] = *(const float4*)(q + (size_t)dst * 64 + h * 16 + i * 4);
  int beg = rowptr[dst], end = rowptr[dst + 1];
  float l = 0.f;
  float acc[16];
#pragma unroll
  for (int i = 0; i < 16; ++i) acc[i] = 0.f;
  for (int base = beg; base < end; base += 16) {
    int myidx = base + e;
    bool valid = myidx < end;
    int src = valid ? srcs[myidx] : 0;
    const uint4* kp = (const uint4*)(kv + (size_t)src * 64 + h * 16);
    uint4 ka = kp[0], kb = kp[1], kc_ = kp[2], kd = kp[3];
    float s;
    s  = bflo(ka.x) * qv[0]  + bflo(ka.y) * qv[1]  + bflo(ka.z) * qv[2]  + bflo(ka.w) * qv[3];
    s += bflo(kb.x) * qv[4]  + bflo(kb.y) * qv[5]  + bflo(kb.z) * qv[6]  + bflo(kb.w) * qv[7];
    s += bflo(kc_.x) * qv[8] + bflo(kc_.y) * qv[9] + bflo(kc_.z) * qv[10] + bflo(kc_.w) * qv[11];
    s += bflo(kd.x) * qv[12] + bflo(kd.y) * qv[13] + bflo(kd.z) * qv[14] + bflo(kd.w) * qv[15];
    float pex = valid ? __expf(s * SCL) : 0.f;
    l += pex;
    acc[0]  += pex * bfhi(ka.x);  acc[1]  += pex * bfhi(ka.y);
    acc[2]  += pex * bfhi(ka.z);  acc[3]  += pex * bfhi(ka.w);
    acc[4]  += pex * bfhi(kb.x);  acc[5]  += pex * bfhi(kb.y);
    acc[6]  += pex * bfhi(kb.z);  acc[7]  += pex * bfhi(kb.w);
    acc[8]  += pex * bfhi(kc_.x); acc[9]  += pex * bfhi(kc_.y);
    acc[10] += pex * bfhi(kc_.z); acc[11] += pex * bfhi(kc_.w);
    acc[12] += pex * bfhi(kd.x);  acc[13] += pex * bfhi(kd.y);
    acc[14] += pex * bfhi(kd.z);  acc[15] += pex * bfhi(kd.w);
  }
  // l: full butterfly over e-bits -> every lane holds its head's total
  l += __shfl_xor(l, 4); l += __shfl_xor(l, 8);
  l += __shfl_xor(l, 16); l += __shfl_xor(l, 32);
  // acc: reduce-scatter butterfly over e-bits
#pragma unroll
  for (int s_ = 0; s_ < 4; ++s_) {
    int cnt = 8 >> s_;
    bool hi = (lane >> (2 + s_)) & 1;
#pragma unroll
    for (int i = 0; i < cnt; ++i) {
      float keep = hi ? acc[i + cnt] : acc[i];
      float send = hi ? acc[i] : acc[i + cnt];
      acc[i] = keep + __shfl_xor(send, 4 << s_);
    }
  }
  int d = ((e & 1) << 3) | ((e & 2) << 1) | ((e & 4) >> 1) | ((e & 8) >> 3);
  float aggv = (end > beg) ? acc[0] / l : 0.f;
  size_t o = (size_t)dst * 64 + h * 16 + d;
  tmp[o] = aggv + sk[o];
}

// Fused: x = LN(f_h + tmp @ Wo + bo)  -> f_h (fp32) ; then qt,kt,vt = x @ W* + b* (bf16)
__global__ void __launch_bounds__(256)
k_mlqkvt(const float* __restrict__ in1, const unsigned short* __restrict__ wt,
         const float* __restrict__ bias, const float* __restrict__ gam,
         const float* __restrict__ bet, float* __restrict__ io,
         const float* __restrict__ bqt, const float* __restrict__ bkt,
         const float* __restrict__ bvt,
         unsigned short* __restrict__ qt, unsigned short* __restrict__ kt,
         unsigned short* __restrict__ vt) {
  __shared__ unsigned short A[64 * 72];
  __shared__ unsigned short B[3 * 64 * 72];
  int tid = threadIdx.x;
  int n0 = blockIdx.x * 64;
  stage_f32(in1 + (size_t)n0 * 64, A, 64 * 16, 64, 72, tid);
  stage_bf(wt + 0, B, 64 * 8, 64, 72, tid);       // Wo
  __syncthreads();
  int lane = tid & 63, w = tid >> 6;
  int c = lane & 15, g = lane >> 4;
  f32x4 acc[4];
#pragma unroll
  for (int j = 0; j < 4; ++j) { acc[j][0] = 0.f; acc[j][1] = 0.f; acc[j][2] = 0.f; acc[j][3] = 0.f; }
  const unsigned short* xrow = A + (w * 16 + c) * 72 + g * 8;
#pragma unroll
  for (int kk = 0; kk < 2; ++kk) {
    bf16x8 af = *(const bf16x8*)(xrow + kk * 32);
#pragma unroll
    for (int j = 0; j < 4; ++j)
      acc[j] = __builtin_amdgcn_mfma_f32_16x16x32_bf16(af,
                 *(const bf16x8*)(B + (j * 16 + c) * 72 + kk * 32 + g * 8), acc[j], 0, 0, 0);
  }
  int rowb = n0 + w * 16 + 4 * g;
  float o[4][4];
#pragma unroll
  for (int j = 0; j < 4; ++j) {
    int col = j * 16 + c;
    float bb = bias[col];
#pragma unroll
    for (int r = 0; r < 4; ++r)
      o[j][r] = acc[j][r] + bb + io[(size_t)(rowb + r) * 64 + col];
  }
#pragma unroll
  for (int r = 0; r < 4; ++r) {
    float s = (o[0][r] + o[1][r]) + (o[2][r] + o[3][r]);
    float s2 = (o[0][r] * o[0][r] + o[1][r] * o[1][r]) + (o[2][r] * o[2][r] + o[3][r] * o[3][r]);
#pragma unroll
    for (int off = 1; off <= 8; off <<= 1) {
      s += __shfl_xor(s, off);
      s2 += __shfl_xor(s2, off);
    }
    float mean = s * (1.0f / 64.0f);
    float var = s2 * (1.0f / 64.0f) - mean * mean;
    float rs = rsqrtf(var + EPSLN);
#pragma unroll
    for (int j = 0; j < 4; ++j)
      o[j][r] = (o[j][r] - mean) * rs * gam[j * 16 + c] + bet[j * 16 + c];
  }
  __syncthreads();   // all waves done reading A and B
  // write LN result to global (residual for later) and to LDS A (bf16)
#pragma unroll
  for (int j = 0; j < 4; ++j) {
    int col = j * 16 + c;
#pragma unroll
    for (int r = 0; r < 4; ++r) {
      io[(size_t)(rowb + r) * 64 + col] = o[j][r];
      A[(w * 16 + 4 * g + r) * 72 + col] = f2bf(o[j][r]);
    }
  }
  stage_bf(wt + 8192, B, 64 * 8, 64, 72, tid);        // Wqt
  stage_bf(wt + 12288, B + 4608, 64 * 8, 64, 72, tid);  // Wkt
  stage_bf(wt + 16384, B + 9216, 64 * 8, 64, 72, tid);  // Wvt
  __syncthreads();
  f32x4 aq[4], ak[4], av[4];
#pragma unroll
  for (int j = 0; j < 4; ++j) {
#pragma unroll
    for (int r = 0; r < 4; ++r) { aq[j][r] = 0.f; ak[j][r] = 0.f; av[j][r] = 0.f; }
  }
#pragma unroll
  for (int kk = 0; kk < 2; ++kk) {
    bf16x8 af = *(const bf16x8*)(xrow + kk * 32);
#pragma unroll
    for (int j = 0; j < 4; ++j) {
      int boff = (j * 16 + c) * 72 + kk * 32 + g * 8;
      aq[j] = __builtin_amdgcn_mfma_f32_16x16x32_bf16(af, *(const bf16x8*)(B + boff), aq[j], 0, 0, 0);
      ak[j] = __builtin_amdgcn_mfma_f32_16x16x32_bf16(af, *(const bf16x8*)(B + 4608 + boff), ak[j], 0, 0, 0);
      av[j] = __builtin_amdgcn_mfma_f32_16x16x32_bf16(af, *(const bf16x8*)(B + 9216 + boff), av[j], 0, 0, 0);
    }
  }
#pragma unroll
  for (int j = 0; j < 4; ++j) {
    int col = j * 16 + c;
    float bqj = bqt[col], bkj = bkt[col], bvj = bvt[col];
#pragma unroll
    for (int r = 0; r < 4; ++r) {
      size_t oo = (size_t)(rowb + r) * 64 + col;
      qt[oo] = f2bf(aq[j][r] + bqj);
      kt[oo] = f2bf(ak[j][r] + bkj);
      vt[oo] = f2bf(av[j][r] + bvj);
    }
  }
}

// K8: temporal attention via MFMA
#define VST 20
#define PST 40
__global__ void __launch_bounds__(256)
k_tattn(const unsigned short* __restrict__ qtb, const unsigned short* __restrict__ ktb,
        const unsigned short* __restrict__ vtb, float* __restrict__ attn) {
  int b = blockIdx.x >> 2, hh = blockIdx.x & 3;
  __shared__ unsigned short Qs[NFRM][16];
  __shared__ unsigned short Ks[NFRM][16];
  __shared__ unsigned short Vs[NFRM][VST];
  __shared__ unsigned short Ps[4][16][PST];
  int t = threadIdx.x;
  int wv = t >> 6, lane = t & 63;
  int g = lane >> 4, c = lane & 15;
  {
    size_t src = ((size_t)b * NFRM + t) * DD + hh * 16;
    const uint4* qsrc = (const uint4*)(qtb + src);
    const uint4* ksrc = (const uint4*)(ktb + src);
    const uint2* vsrc = (const uint2*)(vtb + src);
    ((uint4*)Qs[t])[0] = qsrc[0]; ((uint4*)Qs[t])[1] = qsrc[1];
    ((uint4*)Ks[t])[0] = ksrc[0]; ((uint4*)Ks[t])[1] = ksrc[1];
    uint2* vdst = (uint2*)Vs[t];
    vdst[0] = vsrc[0]; vdst[1] = vsrc[1]; vdst[2] = vsrc[2]; vdst[3] = vsrc[3];
  }
  __syncthreads();
  const bf16x8 zf = {0, 0, 0, 0, 0, 0, 0, 0};
  unsigned short (*P)[PST] = Ps[wv];
  for (int qt0 = wv; qt0 < 16; qt0 += 4) {
    bf16x8 qf = zf;
    if (g < 2) qf = *(const bf16x8*)&Qs[qt0 * 16 + c][g * 8];
    f32x4 O = {0.f, 0.f, 0.f, 0.f};
    float lacc[4] = {0.f, 0.f, 0.f, 0.f};
    for (int jp = 0; jp < 8; ++jp) {
#pragma unroll
      for (int half = 0; half < 2; ++half) {
        int jt = jp * 2 + half;
        bf16x8 kf = zf;
        if (g < 2) kf = *(const bf16x8*)&Ks[jt * 16 + c][g * 8];
        f32x4 S = __builtin_amdgcn_mfma_f32_16x16x32_bf16(qf, kf,
                    (f32x4){0.f, 0.f, 0.f, 0.f}, 0, 0, 0);
#pragma unroll
        for (int r = 0; r < 4; ++r) {
          float p = __expf(S[r] * SCL);
          lacc[r] += p;
          P[4 * g + r][half * 16 + c] = f2bf(p);
        }
      }
      bf16x8 pf = *(const bf16x8*)&P[c][g * 8];
      bf16x8 vf;
#pragma unroll
      for (int i = 0; i < 8; ++i) vf[i] = (short)Vs[jp * 32 + g * 8 + i][c];
      O = __builtin_amdgcn_mfma_f32_16x16x32_bf16(pf, vf, O, 0, 0, 0);
    }
#pragma unroll
    for (int r = 0; r < 4; ++r) {
      float s = lacc[r];
      s += __shfl_xor(s, 1); s += __shfl_xor(s, 2);
      s += __shfl_xor(s, 4); s += __shfl_xor(s, 8);
      lacc[r] = 1.0f / s;
    }
    size_t obase = ((size_t)b * NFRM + qt0 * 16) * DD + hh * 16;
#pragma unroll
    for (int r = 0; r < 4; ++r)
      attn[obase + (size_t)(4 * g + r) * DD + c] = O[r] * lacc[r];
  }
}

// Fused block2: x = LN1(f_h + attn @ Wot + bot); u = relu(x@W1+b1);
// xtb = LN2(x + u@W2 + b2)  (bf16 out)
__global__ void __launch_bounds__(256)
k_blk2(const float* __restrict__ attn, const unsigned short* __restrict__ wt,
       const float* __restrict__ res, const float* __restrict__ bot,
       const float* __restrict__ l1g, const float* __restrict__ l1b,
       const float* __restrict__ b1, const float* __restrict__ b2,
       const float* __restrict__ l2g, const float* __restrict__ l2b,
       unsigned short* __restrict__ xtb) {
  __shared__ unsigned short XLs[64 * 72];     // LN1 result
  __shared__ unsigned short BufW[128 * 72];   // Wot -> W1 -> W2
  __shared__ unsigned short BufX[64 * 136];   // attn Xs -> u
  int tid = threadIdx.x;
  int n0 = blockIdx.x * 64;
  int lane = tid & 63, w = tid >> 6;
  int c = lane & 15, g = lane >> 4;
  int rowb = n0 + w * 16 + 4 * g;
  // phase 1: attn @ Wot
  stage_f32(attn + (size_t)n0 * 64, BufX, 64 * 16, 64, 72, tid);
  stage_bf(wt + 4096, BufW, 64 * 8, 64, 72, tid);   // Wot
  __syncthreads();
  f32x4 acc[4];
#pragma unroll
  for (int j = 0; j < 4; ++j) { acc[j][0] = 0.f; acc[j][1] = 0.f; acc[j][2] = 0.f; acc[j][3] = 0.f; }
  const unsigned short* xrow = BufX + (w * 16 + c) * 72 + g * 8;
#pragma unroll
  for (int kk = 0; kk < 2; ++kk) {
    bf16x8 af = *(const bf16x8*)(xrow + kk * 32);
#pragma unroll
    for (int j = 0; j < 4; ++j)
      acc[j] = __builtin_amdgcn_mfma_f32_16x16x32_bf16(af,
                 *(const bf16x8*)(BufW + (j * 16 + c) * 72 + kk * 32 + g * 8), acc[j], 0, 0, 0);
  }
  float x[4][4];
#pragma unroll
  for (int j = 0; j < 4; ++j) {
    int col = j * 16 + c;
    float bb = bot[col];
#pragma unroll
    for (int r = 0; r < 4; ++r)
      x[j][r] = acc[j][r] + bb + res[(size_t)(rowb + r) * 64 + col];
  }
#pragma unroll
  for (int r = 0; r < 4; ++r) {
    float s = (x[0][r] + x[1][r]) + (x[2][r] + x[3][r]);
    float s2 = (x[0][r] * x[0][r] + x[1][r] * x[1][r]) + (x[2][r] * x[2][r] + x[3][r] * x[3][r]);
#pragma unroll
    for (int off = 1; off <= 8; off <<= 1) {
      s += __shfl_xor(s, off);
      s2 += __shfl_xor(s2, off);
    }
    float mean = s * (1.0f / 64.0f);
    float var = s2 * (1.0f / 64.0f) - mean * mean;
    float rs = rsqrtf(var + EPSLN);
#pragma unroll
    for (int j = 0; j < 4; ++j)
      x[j][r] = (x[j][r] - mean) * rs * l1g[j * 16 + c] + l1b[j * 16 + c];
  }
  __syncthreads();   // all done with BufX/BufW
  // phase 2: write x -> XLs, stage W1
#pragma unroll
  for (int j = 0; j < 4; ++j)
#pragma unroll
    for (int r = 0; r < 4; ++r)
      XLs[(w * 16 + 4 * g + r) * 72 + j * 16 + c] = f2bf(x[j][r]);
  stage_bf(wt + 20480, BufW, 128 * 8, 64, 72, tid);  // W1
  __syncthreads();
  // phase 3: u = relu(XLs @ W1)
  f32x4 ua[8];
#pragma unroll
  for (int j = 0; j < 8; ++j) { ua[j][0] = 0.f; ua[j][1] = 0.f; ua[j][2] = 0.f; ua[j][3] = 0.f; }
  const unsigned short* xrow2 = XLs + (w * 16 + c) * 72 + g * 8;
#pragma unroll
  for (int kk = 0; kk < 2; ++kk) {
    bf16x8 af = *(const bf16x8*)(xrow2 + kk * 32);
#pragma unroll
    for (int j = 0; j < 8; ++j)
      ua[j] = __builtin_amdgcn_mfma_f32_16x16x32_bf16(af,
                *(const bf16x8*)(BufW + (j * 16 + c) * 72 + kk * 32 + g * 8), ua[j], 0, 0, 0);
  }
  // write u -> BufX (stride 136) bf16
#pragma unroll
  for (int j = 0; j < 8; ++j) {
    int col = j * 16 + c;
    float bb = b1[col];
#pragma unroll
    for (int r = 0; r < 4; ++r)
      BufX[(w * 16 + 4 * g + r) * 136 + col] = f2bf(fmaxf(ua[j][r] + bb, 0.f));
  }
  __syncthreads();   // u complete; all waves done reading BufW (W1)
  stage_bf(wt + 28672, BufW, 64 * 16, 128, 136, tid);  // W2
  __syncthreads();
  // phase 4: y = u @ W2; LN2(x + y)
  f32x4 ya[4];
#pragma unroll
  for (int j = 0; j < 4; ++j) { ya[j][0] = 0.f; ya[j][1] = 0.f; ya[j][2] = 0.f; ya[j][3] = 0.f; }
  const unsigned short* urow = BufX + (w * 16 + c) * 136 + g * 8;
#pragma unroll
  for (int kk = 0; kk < 4; ++kk) {
    bf16x8 af = *(const bf16x8*)(urow + kk * 32);
#pragma unroll
    for (int j = 0; j < 4; ++j)
      ya[j] = __builtin_amdgcn_mfma_f32_16x16x32_bf16(af,
                *(const bf16x8*)(BufW + (j * 16 + c) * 136 + kk * 32 + g * 8), ya[j], 0, 0, 0);
  }
  float o2[4][4];
#pragma unroll
  for (int j = 0; j < 4; ++j) {
    int col = j * 16 + c;
    float bb = b2[col];
#pragma unroll
    for (int r = 0; r < 4; ++r)
      o2[j][r] = ya[j][r] + bb + x[j][r];
  }
#pragma unroll
  for (int r = 0; r < 4; ++r) {
    float s = (o2[0][r] + o2[1][r]) + (o2[2][r] + o2[3][r]);
    float s2 = (o2[0][r] * o2[0][r] + o2[1][r] * o2[1][r]) + (o2[2][r] * o2[2][r] + o2[3][r] * o2[3][r]);
#pragma unroll
    for (int off = 1; off <= 8; off <<= 1) {
      s += __shfl_xor(s, off);
      s2 += __shfl_xor(s2, off);
    }
    float mean = s * (1.0f / 64.0f);
    float var = s2 * (1.0f / 64.0f) - mean * mean;
    float rs = rsqrtf(var + EPSLN);
#pragma unroll
    for (int j = 0; j < 4; ++j)
      xtb[(size_t)(rowb + r) * 64 + j * 16 + c] =
          f2bf((o2[j][r] - mean) * rs * l2g[j * 16 + c] + l2b[j * 16 + c]);
  }
}

// agg1 GEMM via MFMA: part[ks][b][o] = sum_{k in chunk} xtb[b][k] * wa1t[o][k]
__global__ void __launch_bounds__(256)
k_agg1a_m(const unsigned short* __restrict__ xtb, const unsigned short* __restrict__ wa1t,
          float* __restrict__ part) {
  int ks = blockIdx.x >> 2, mt = blockIdx.x & 3;
  int t = threadIdx.x, lane = t & 63, w = t >> 6;
  int c = lane & 15, g = lane >> 4;
  int m0 = mt * 64;
  int k0 = ks * 512;
  f32x4 acc[4];
#pragma unroll
  for (int j = 0; j < 4; ++j) { acc[j][0] = 0.f; acc[j][1] = 0.f; acc[j][2] = 0.f; acc[j][3] = 0.f; }
  const unsigned short* arow = xtb + (size_t)(m0 + w * 16 + c) * 16384 + k0 + g * 8;
  const unsigned short* brow = wa1t + (size_t)c * 16384 + k0 + g * 8;
#pragma unroll 4
  for (int kk = 0; kk < 16; ++kk) {
    bf16x8 af = *(const bf16x8*)(arow + kk * 32);
#pragma unroll
    for (int j = 0; j < 4; ++j)
      acc[j] = __builtin_amdgcn_mfma_f32_16x16x32_bf16(af,
                 *(const bf16x8*)(brow + (size_t)j * 16 * 16384 + kk * 32), acc[j], 0, 0, 0);
  }
  int rowb = m0 + w * 16 + 4 * g;
#pragma unroll
  for (int j = 0; j < 4; ++j)
#pragma unroll
    for (int r = 0; r < 4; ++r)
      part[(size_t)ks * (BSZ * DD) + (size_t)(rowb + r) * 64 + j * 16 + c] = acc[j][r];
}

// K13: head MLP (+ fused partial reduce)
__global__ void k_head(const float* __restrict__ part, const float* __restrict__ ba1,
                       const float* __restrict__ Wa2, const float* __restrict__ ba2,
                       const float* __restrict__ Wh1, const float* __restrict__ bh1,
                       const float* __restrict__ Wh2, const float* __restrict__ bh2,
                       float* __restrict__ out) {
  int b = blockIdx.x, t = threadIdx.x;
  __shared__ float s1[64], s2[32], s3[16];
  float a0 = ba1[t];
#pragma unroll 8
  for (int ks = 0; ks < AKS; ++ks) a0 += part[(size_t)ks * (BSZ * DD) + b * 64 + t];
  s1[t] = fmaxf(a0, 0.f);
  __syncthreads();
  if (t < 32) {
    float a = ba2[t];
#pragma unroll 8
    for (int j = 0; j < 64; ++j) a += s1[j] * Wa2[j * 32 + t];
    s2[t] = fmaxf(a, 0.f);
  }
  __syncthreads();
  if (t < 16) {
    float a = bh1[t];
#pragma unroll
    for (int j = 0; j < 32; ++j) a += s2[j] * Wh1[j * 16 + t];
    s3[t] = fmaxf(a, 0.f);
  }
  __syncthreads();
  if (t == 0) {
    float a = bh2[0];
#pragma unroll
    for (int j = 0; j < 16; ++j) a += s3[j] * Wh2[j];
    out[b] = 1.0f / (1.0f + expf(-a));
  }
}

extern "C" void kernel_launch(void* const* d_in, const int* in_sizes, int n_in,
                              void* d_out, int out_size, void* d_ws, size_t ws_size,
                              hipStream_t stream) {
  const float* x   = (const float*)d_in[0];
  const int*   ei  = (const int*)d_in[1];
  const float* Wi  = (const float*)d_in[2];
  const float* bi  = (const float*)d_in[3];
  const float* pe  = (const float*)d_in[4];
  const float* Wq  = (const float*)d_in[5];
  const float* Wk  = (const float*)d_in[6];
  const float* Wv  = (const float*)d_in[7];
  const float* bq  = (const float*)d_in[8];
  const float* bk  = (const float*)d_in[9];
  const float* bv  = (const float*)d_in[10];
  const float* Ws  = (const float*)d_in[11];
  const float* bs  = (const float*)d_in[12];
  const float* Wo  = (const float*)d_in[13];
  const float* bo  = (const float*)d_in[14];
  const float* gg  = (const float*)d_in[15];
  const float* gb  = (const float*)d_in[16];
  const float* Wqt = (const float*)d_in[17];
  const float* Wkt = (const float*)d_in[18];
  const float* Wvt = (const float*)d_in[19];
  const float* bqt = (const float*)d_in[20];
  const float* bkt = (const float*)d_in[21];
  const float* bvt = (const float*)d_in[22];
  const float* Wot = (const float*)d_in[23];
  const float* bot = (const float*)d_in[24];
  const float* l1g = (const float*)d_in[25];
  const float* l1b = (const float*)d_in[26];
  const float* W1  = (const float*)d_in[27];
  const float* b1  = (const float*)d_in[28];
  const float* W2  = (const float*)d_in[29];
  const float* b2  = (const float*)d_in[30];
  const float* l2g = (const float*)d_in[31];
  const float* l2b = (const float*)d_in[32];
  const float* Wa1 = (const float*)d_in[33];
  const float* ba1 = (const float*)d_in[34];
  const float* Wa2 = (const float*)d_in[35];
  const float* ba2 = (const float*)d_in[36];
  const float* Wh1 = (const float*)d_in[37];
  const float* bh1 = (const float*)d_in[38];
  const float* Wh2 = (const float*)d_in[39];
  const float* bh2 = (const float*)d_in[40];
  float* out = (float*)d_out;

  const size_t ND = (size_t)NN * DD;

  float* wsf    = (float*)d_ws;
  float* f_h    = wsf;                 // h fp32 (residual chain)
  float* f_q    = f_h  + ND;           // q fp32 -> qt/kt bf16
  float* f_k    = f_q  + ND;           // kv packed -> vt bf16
  float* f_v    = f_k  + ND;           // spare
  float* f_sk   = f_v  + ND;           // skip -> attn
  float* f_u    = f_sk + ND;           // gattn tmp fp32 -> xtb bf16
  float* f_part = f_u  + 2 * ND;       // agg partials [AKS][256][64]
  float* f_a1   = f_part + (size_t)AKS * BSZ * DD;
  int* i_srcs   = (int*)(f_a1 + BSZ * DD);
  int* i_rowptr = i_srcs + NE;
  int* i_hist   = i_rowptr + NN + 1;
  int* i_btot   = i_hist + 65536;
  int* i_bbase  = i_btot + 256;
  int* i_pairs  = i_bbase + 256;
  unsigned short* wt = (unsigned short*)(i_pairs + NE);   // 53248 ushorts
  unsigned short* wa1t = wt + 53248;                      // [64][16384] bf16

  ushort2* f_kv = (ushort2*)f_k;
  float* f_tmp  = f_u;
  unsigned short* us_qt = (unsigned short*)f_q;
  unsigned short* us_kt = us_qt + ND;
  unsigned short* us_vt = (unsigned short*)f_k;
  unsigned short* us_xtb = (unsigned short*)f_u;

  dim3 B(256);
  k_wprep<<<dim3(208), B, 0, stream>>>(Wo, Wot, Wqt, Wkt, Wvt, W1, W2, Wq, Wk, Wv, Ws, wt);
  k_wprep2<<<dim3(256), B, 0, stream>>>(Wa1, wa1t);
  k_input<<<dim3(NN / (4 * RB)), B, 0, stream>>>(x, Wi, bi, pe, f_h);
  k_qkvs_m<<<dim3(NN / 64), B, 0, stream>>>(f_h, wt, bq, bk, bv, bs, f_q, f_kv, f_sk);
  k_hist <<<dim3(256), B, 0, stream>>>(ei, i_hist);
  k_hscan<<<dim3(256), B, 0, stream>>>(i_hist, i_btot);
  k_bscan<<<dim3(1),   B, 0, stream>>>(i_btot, i_bbase);
  k_passB<<<dim3(256), B, 0, stream>>>(ei, i_hist, i_bbase, i_pairs);
  k_passC<<<dim3(256), B, 0, stream>>>(i_pairs, i_bbase, i_btot, i_rowptr, i_srcs);
  k_gattn<<<dim3(NN / 4), B, 0, stream>>>(f_q, (const unsigned*)f_kv, i_rowptr, i_srcs,
                                          f_sk, f_tmp);
  k_mlqkvt<<<dim3(NN / 64), B, 0, stream>>>(f_tmp, wt, bo, gg, gb, f_h,
                                            bqt, bkt, bvt, us_qt, us_kt, us_vt);
  k_tattn<<<dim3(BSZ * HH), B, 0, stream>>>(us_qt, us_kt, us_vt, f_sk);
  k_blk2<<<dim3(NN / 64), B, 0, stream>>>(f_sk, wt, f_h, bot, l1g, l1b, b1, b2,
                                          l2g, l2b, us_xtb);
  k_agg1a_m<<<dim3(AKS * 4), B, 0, stream>>>(us_xtb, wa1t, f_part);
  k_head<<<dim3(BSZ), dim3(64), 0, stream>>>(f_part, ba1, Wa2, ba2, Wh1, bh1, Wh2, bh2, out);
}

// Round 10
// 216.951 us; speedup vs baseline: 1.2669x; 1.2669x over previous
//
#include <hip/hip_runtime.h>
#include <math.h>

#define NN 65536
#define SIN 24
#define DD 64
#define HH 4
#define HDIM 16
#define NFRM 256
#define NE 1048576
#define BSZ 256
#define EPSLN 1e-5f
#define SCL 0.25f
#define RB 8
#define AKS 32   // K-splits for agg1 MFMA GEMM

typedef __attribute__((ext_vector_type(8))) short bf16x8;
typedef __attribute__((ext_vector_type(4))) float f32x4;

__device__ __forceinline__ unsigned short f2bf(float f) {
  unsigned u = __float_as_uint(f);
  return (unsigned short)((u + 0x7FFFu + ((u >> 16) & 1u)) >> 16);
}
__device__ __forceinline__ float bf2f(unsigned short b) {
  return __uint_as_float(((unsigned)b) << 16);
}
__device__ __forceinline__ float bflo(unsigned u) {
  return __uint_as_float(u << 16);
}
__device__ __forceinline__ float bfhi(unsigned u) {
  return __uint_as_float(u & 0xFFFF0000u);
}

// stage fp32 [rows][DK] -> bf16 LDS [rows][ST]
__device__ __forceinline__ void stage_f32(const float* __restrict__ src,
                                          unsigned short* dst, int n4, int DK, int ST, int tid) {
  int dk4 = DK >> 2;
  for (int idx = tid; idx < n4; idx += 256) {
    int row = idx / dk4, c = (idx % dk4) * 4;
    float4 v = *(const float4*)(src + (size_t)row * DK + c);
    uint2 p;
    p.x = (unsigned)f2bf(v.x) | ((unsigned)f2bf(v.y) << 16);
    p.y = (unsigned)f2bf(v.z) | ((unsigned)f2bf(v.w) << 16);
    *(uint2*)(dst + row * ST + c) = p;
  }
}

// stage bf16 [rows][DK] -> LDS [rows][ST]
__device__ __forceinline__ void stage_bf(const unsigned short* __restrict__ src,
                                         unsigned short* dst, int n8, int DK, int ST, int tid) {
  int dk8 = DK >> 3;
  for (int idx = tid; idx < n8; idx += 256) {
    int row = idx / dk8, c = (idx % dk8) * 8;
    *(uint4*)(dst + row * ST + c) = *(const uint4*)(src + (size_t)row * DK + c);
  }
}

// K1: h = x @ Wi + bi + pe[n % NF]
__global__ void k_input(const float* __restrict__ x, const float* __restrict__ Wi,
                        const float* __restrict__ bi, const float* __restrict__ pe,
                        float* __restrict__ h) {
  int lane = threadIdx.x & 63;
  int wid = __builtin_amdgcn_readfirstlane(threadIdx.x >> 6);
  int n0 = (blockIdx.x * 4 + wid) * RB;
  float b = bi[lane];
  float acc[RB];
#pragma unroll
  for (int r = 0; r < RB; ++r) acc[r] = b + pe[((n0 + r) & (NFRM - 1)) * DD + lane];
  for (int s = 0; s < SIN; ++s) {
    float w = Wi[s * DD + lane];
#pragma unroll
    for (int r = 0; r < RB; ++r) acc[r] += x[(size_t)(n0 + r) * SIN + s] * w;
  }
#pragma unroll
  for (int r = 0; r < RB; ++r) h[(size_t)(n0 + r) * DD + lane] = acc[r];
}

// Weight prep: transpose all dense weights to bf16 Wt[Nout][Dk]
__global__ void k_wprep(const float* __restrict__ Wo, const float* __restrict__ Wot,
                        const float* __restrict__ Wqt, const float* __restrict__ Wkt,
                        const float* __restrict__ Wvt, const float* __restrict__ W1,
                        const float* __restrict__ W2, const float* __restrict__ Wq,
                        const float* __restrict__ Wk, const float* __restrict__ Wv,
                        const float* __restrict__ Wsk, unsigned short* __restrict__ wt) {
  int i = blockIdx.x * 256 + threadIdx.x;
  if (i >= 53248) return;
  float v;
  if (i < 4096)       { int t = i;         int j = t >> 6, d = t & 63; v = Wo[d * 64 + j]; }
  else if (i < 8192)  { int t = i - 4096;  int j = t >> 6, d = t & 63; v = Wot[d * 64 + j]; }
  else if (i < 12288) { int t = i - 8192;  int j = t >> 6, d = t & 63; v = Wqt[d * 64 + j]; }
  else if (i < 16384) { int t = i - 12288; int j = t >> 6, d = t & 63; v = Wkt[d * 64 + j]; }
  else if (i < 20480) { int t = i - 16384; int j = t >> 6, d = t & 63; v = Wvt[d * 64 + j]; }
  else if (i < 28672) { int t = i - 20480; int j = t >> 6, d = t & 63; v = W1[d * 128 + j]; }
  else if (i < 36864) { int t = i - 28672; int j = t >> 7, d = t & 127; v = W2[d * 64 + j]; }
  else if (i < 40960) { int t = i - 36864; int j = t >> 6, d = t & 63; v = Wq[(j >> 4) * 1024 + d * 16 + (j & 15)]; }
  else if (i < 45056) { int t = i - 40960; int j = t >> 6, d = t & 63; v = Wk[(j >> 4) * 1024 + d * 16 + (j & 15)]; }
  else if (i < 49152) { int t = i - 45056; int j = t >> 6, d = t & 63; v = Wv[(j >> 4) * 1024 + d * 16 + (j & 15)]; }
  else                { int t = i - 49152; int j = t >> 6, d = t & 63; v = Wsk[(j >> 4) * 1024 + d * 16 + (j & 15)]; }
  wt[i] = f2bf(v);
}

// Wa1 [16384][64] fp32 -> wa1t [64][16384] bf16  (LDS-tiled transpose)
__global__ void k_wprep2(const float* __restrict__ Wa1, unsigned short* __restrict__ wa1t) {
  __shared__ float tile[64][65];
  int kb = blockIdx.x;
  int t = threadIdx.x;
  int c = t & 63, r0 = t >> 6;
  int k0 = kb * 64;
#pragma unroll
  for (int i = 0; i < 16; ++i) {
    int r = r0 + i * 4;
    tile[r][c] = Wa1[(size_t)(k0 + r) * 64 + c];
  }
  __syncthreads();
#pragma unroll
  for (int i = 0; i < 16; ++i) {
    int o = r0 + i * 4;
    wa1t[(size_t)o * 16384 + k0 + c] = f2bf(tile[c][o]);
  }
}

// K2 (MFMA): q fp32, kv packed bf16, sk fp32
__global__ void __launch_bounds__(256)
k_qkvs_m(const float* __restrict__ h, const unsigned short* __restrict__ wt,
         const float* __restrict__ bq, const float* __restrict__ bk,
         const float* __restrict__ bv, const float* __restrict__ bs,
         float* __restrict__ q, ushort2* __restrict__ kv, float* __restrict__ sk) {
  __shared__ unsigned short Xs[64 * 72];
  __shared__ unsigned short Ws4[4 * 64 * 72];
  int tid = threadIdx.x;
  int n0 = blockIdx.x * 64;
  stage_f32(h + (size_t)n0 * 64, Xs, 64 * 16, 64, 72, tid);
  stage_bf(wt + 36864, Ws4, 64 * 8, 64, 72, tid);
  stage_bf(wt + 40960, Ws4 + 4608, 64 * 8, 64, 72, tid);
  stage_bf(wt + 45056, Ws4 + 9216, 64 * 8, 64, 72, tid);
  stage_bf(wt + 49152, Ws4 + 13824, 64 * 8, 64, 72, tid);
  __syncthreads();
  int lane = tid & 63, w = tid >> 6;
  int c = lane & 15, g = lane >> 4;
  f32x4 aq[4], ak[4], av[4], as_[4];
#pragma unroll
  for (int j = 0; j < 4; ++j) {
#pragma unroll
    for (int r = 0; r < 4; ++r) { aq[j][r] = 0.f; ak[j][r] = 0.f; av[j][r] = 0.f; as_[j][r] = 0.f; }
  }
  const unsigned short* xrow = Xs + (w * 16 + c) * 72 + g * 8;
#pragma unroll
  for (int kk = 0; kk < 2; ++kk) {
    bf16x8 af = *(const bf16x8*)(xrow + kk * 32);
#pragma unroll
    for (int j = 0; j < 4; ++j) {
      int boff = (j * 16 + c) * 72 + kk * 32 + g * 8;
      aq[j] = __builtin_amdgcn_mfma_f32_16x16x32_bf16(af, *(const bf16x8*)(Ws4 + boff), aq[j], 0, 0, 0);
      ak[j] = __builtin_amdgcn_mfma_f32_16x16x32_bf16(af, *(const bf16x8*)(Ws4 + 4608 + boff), ak[j], 0, 0, 0);
      av[j] = __builtin_amdgcn_mfma_f32_16x16x32_bf16(af, *(const bf16x8*)(Ws4 + 9216 + boff), av[j], 0, 0, 0);
      as_[j] = __builtin_amdgcn_mfma_f32_16x16x32_bf16(af, *(const bf16x8*)(Ws4 + 13824 + boff), as_[j], 0, 0, 0);
    }
  }
  int rowb = n0 + w * 16 + 4 * g;
#pragma unroll
  for (int j = 0; j < 4; ++j) {
    int col = j * 16 + c;
    float bqj = bq[col], bkj = bk[col], bvj = bv[col], bsj = bs[col];
#pragma unroll
    for (int r = 0; r < 4; ++r) {
      size_t o = (size_t)(rowb + r) * 64 + col;
      q[o] = aq[j][r] + bqj;
      kv[o] = make_ushort2(f2bf(ak[j][r] + bkj), f2bf(av[j][r] + bvj));
      sk[o] = as_[j][r] + bsj;
    }
  }
}

// ---- Bucketed CSR build ----
__global__ void k_hist(const int* __restrict__ ei, int* __restrict__ hist) {
  __shared__ int h[256];
  int t = threadIdx.x;
  h[t] = 0;
  __syncthreads();
  int base = blockIdx.x * 4096;
#pragma unroll
  for (int r = 0; r < 16; ++r)
    atomicAdd(&h[ei[NE + base + r * 256 + t] >> 8], 1);
  __syncthreads();
  hist[t * 256 + blockIdx.x] = h[t];
}

__global__ void k_hscan(int* __restrict__ hist, int* __restrict__ btot) {
  __shared__ int s[256];
  int t = threadIdx.x, bkt = blockIdx.x;
  int v = hist[bkt * 256 + t];
  s[t] = v; __syncthreads();
  for (int off = 1; off < 256; off <<= 1) {
    int x = (t >= off) ? s[t - off] : 0;
    __syncthreads();
    s[t] += x;
    __syncthreads();
  }
  hist[bkt * 256 + t] = s[t] - v;
  if (t == 255) btot[bkt] = s[255];
}

__global__ void k_bscan(const int* __restrict__ btot, int* __restrict__ bbase) {
  __shared__ int s[256];
  int t = threadIdx.x;
  int v = btot[t];
  s[t] = v; __syncthreads();
  for (int off = 1; off < 256; off <<= 1) {
    int x = (t >= off) ? s[t - off] : 0;
    __syncthreads();
    s[t] += x;
    __syncthreads();
  }
  bbase[t] = s[t] - v;
}

__global__ void k_passB(const int* __restrict__ ei, const int* __restrict__ hist,
                        const int* __restrict__ bbase, int* __restrict__ pairs) {
  __shared__ int cur[256];
  int t = threadIdx.x;
  cur[t] = bbase[t] + hist[t * 256 + blockIdx.x];
  __syncthreads();
  int base = blockIdx.x * 4096;
#pragma unroll
  for (int r = 0; r < 16; ++r) {
    int e = base + r * 256 + t;
    int src = ei[e], dst = ei[NE + e];
    int pos = atomicAdd(&cur[dst >> 8], 1);
    pairs[pos] = ((dst & 255) << 16) | src;
  }
}

__global__ void k_passC(const int* __restrict__ pairs, const int* __restrict__ bbase,
                        const int* __restrict__ btot, int* __restrict__ rowptr,
                        int* __restrict__ srcs) {
  __shared__ int cnt[256];
  __shared__ int s[256];
  int t = threadIdx.x, bkt = blockIdx.x;
  cnt[t] = 0;
  __syncthreads();
  int base = bbase[bkt], n = btot[bkt];
  for (int i = t; i < n; i += 256) atomicAdd(&cnt[pairs[base + i] >> 16], 1);
  __syncthreads();
  int v = cnt[t];
  s[t] = v; __syncthreads();
  for (int off = 1; off < 256; off <<= 1) {
    int x = (t >= off) ? s[t - off] : 0;
    __syncthreads();
    s[t] += x;
    __syncthreads();
  }
  int rp = base + s[t] - v;
  rowptr[bkt * 256 + t] = rp;
  if (bkt == 0 && t == 0) rowptr[NN] = NE;
  __syncthreads();
  cnt[t] = rp;
  __syncthreads();
  for (int i = t; i < n; i += 256) {
    int p = pairs[base + i];
    int pos = atomicAdd(&cnt[p >> 16], 1);
    srcs[pos] = p & 0xFFFF;
  }
}

// Graph attention v2-fixed: wave per dst, lane = e*4+h (16 edge slots x 4 heads).
// No max-subtraction. In-register dots + per-lane p*v accum; LDS transpose-reduce
// with stride 17 (conflict-free; gcd(17,32)=1).
__global__ void __launch_bounds__(256)
k_gattn(const float* __restrict__ q, const unsigned* __restrict__ kv,
        const int* __restrict__ rowptr, const int* __restrict__ srcs,
        const float* __restrict__ sk, float* __restrict__ tmp) {
  __shared__ float red[4][64][17];
  int wid = threadIdx.x >> 6, lane = threadIdx.x & 63;
  int dst = (blockIdx.x << 2) + wid;
  int e = lane >> 2, h = lane & 3;
  float qv[16];
#pragma unroll
  for (int i = 0; i < 4; ++i)
    ((float4*)qv)[i] = *(const float4*)(q + (size_t)dst * 64 + h * 16 + i * 4);
  int beg = rowptr[dst], end = rowptr[dst + 1];
  float l = 0.f;
  float acc[16];
#pragma unroll
  for (int i = 0; i < 16; ++i) acc[i] = 0.f;
  for (int base = beg; base < end; base += 16) {
    int myidx = base + e;
    bool valid = myidx < end;
    int src = valid ? srcs[myidx] : 0;
    const uint4* kp = (const uint4*)(kv + (size_t)src * 64 + h * 16);
    uint4 ka = kp[0], kb = kp[1], kc_ = kp[2], kd = kp[3];
    float s;
    s  = bflo(ka.x) * qv[0]  + bflo(ka.y) * qv[1]  + bflo(ka.z) * qv[2]  + bflo(ka.w) * qv[3];
    s += bflo(kb.x) * qv[4]  + bflo(kb.y) * qv[5]  + bflo(kb.z) * qv[6]  + bflo(kb.w) * qv[7];
    s += bflo(kc_.x) * qv[8] + bflo(kc_.y) * qv[9] + bflo(kc_.z) * qv[10] + bflo(kc_.w) * qv[11];
    s += bflo(kd.x) * qv[12] + bflo(kd.y) * qv[13] + bflo(kd.z) * qv[14] + bflo(kd.w) * qv[15];
    float pex = valid ? __expf(s * SCL) : 0.f;
    l += pex;
    acc[0]  += pex * bfhi(ka.x);  acc[1]  += pex * bfhi(ka.y);
    acc[2]  += pex * bfhi(ka.z);  acc[3]  += pex * bfhi(ka.w);
    acc[4]  += pex * bfhi(kb.x);  acc[5]  += pex * bfhi(kb.y);
    acc[6]  += pex * bfhi(kb.z);  acc[7]  += pex * bfhi(kb.w);
    acc[8]  += pex * bfhi(kc_.x); acc[9]  += pex * bfhi(kc_.y);
    acc[10] += pex * bfhi(kc_.z); acc[11] += pex * bfhi(kc_.w);
    acc[12] += pex * bfhi(kd.x);  acc[13] += pex * bfhi(kd.y);
    acc[14] += pex * bfhi(kd.z);  acc[15] += pex * bfhi(kd.w);
  }
  // reduce l over the 16 e-lanes (e bits are lane bits 2..5)
  l += __shfl_xor(l, 4); l += __shfl_xor(l, 8);
  l += __shfl_xor(l, 16); l += __shfl_xor(l, 32);
  // LDS transpose-reduce of acc (intra-wave; stride 17 conflict-free)
  float* rw = &red[wid][lane][0];
#pragma unroll
  for (int i = 0; i < 16; ++i) rw[i] = acc[i];
  int h2 = lane >> 4, d2 = lane & 15;
  float lsum = __shfl(l, h2);
  float ssum = 0.f;
#pragma unroll
  for (int ep = 0; ep < 16; ++ep) ssum += red[wid][ep * 4 + h2][d2];
  float aggv = (end > beg) ? ssum / lsum : 0.f;
  size_t o = (size_t)dst * 64 + lane;
  tmp[o] = aggv + sk[o];
}

// Fused: x = LN(f_h + tmp @ Wo + bo)  -> f_h (fp32) ; then qt,kt,vt = x @ W* + b* (bf16)
__global__ void __launch_bounds__(256)
k_mlqkvt(const float* __restrict__ in1, const unsigned short* __restrict__ wt,
         const float* __restrict__ bias, const float* __restrict__ gam,
         const float* __restrict__ bet, float* __restrict__ io,
         const float* __restrict__ bqt, const float* __restrict__ bkt,
         const float* __restrict__ bvt,
         unsigned short* __restrict__ qt, unsigned short* __restrict__ kt,
         unsigned short* __restrict__ vt) {
  __shared__ unsigned short A[64 * 72];
  __shared__ unsigned short B[3 * 64 * 72];
  int tid = threadIdx.x;
  int n0 = blockIdx.x * 64;
  stage_f32(in1 + (size_t)n0 * 64, A, 64 * 16, 64, 72, tid);
  stage_bf(wt + 0, B, 64 * 8, 64, 72, tid);       // Wo
  __syncthreads();
  int lane = tid & 63, w = tid >> 6;
  int c = lane & 15, g = lane >> 4;
  f32x4 acc[4];
#pragma unroll
  for (int j = 0; j < 4; ++j) { acc[j][0] = 0.f; acc[j][1] = 0.f; acc[j][2] = 0.f; acc[j][3] = 0.f; }
  const unsigned short* xrow = A + (w * 16 + c) * 72 + g * 8;
#pragma unroll
  for (int kk = 0; kk < 2; ++kk) {
    bf16x8 af = *(const bf16x8*)(xrow + kk * 32);
#pragma unroll
    for (int j = 0; j < 4; ++j)
      acc[j] = __builtin_amdgcn_mfma_f32_16x16x32_bf16(af,
                 *(const bf16x8*)(B + (j * 16 + c) * 72 + kk * 32 + g * 8), acc[j], 0, 0, 0);
  }
  int rowb = n0 + w * 16 + 4 * g;
  float o[4][4];
#pragma unroll
  for (int j = 0; j < 4; ++j) {
    int col = j * 16 + c;
    float bb = bias[col];
#pragma unroll
    for (int r = 0; r < 4; ++r)
      o[j][r] = acc[j][r] + bb + io[(size_t)(rowb + r) * 64 + col];
  }
#pragma unroll
  for (int r = 0; r < 4; ++r) {
    float s = (o[0][r] + o[1][r]) + (o[2][r] + o[3][r]);
    float s2 = (o[0][r] * o[0][r] + o[1][r] * o[1][r]) + (o[2][r] * o[2][r] + o[3][r] * o[3][r]);
#pragma unroll
    for (int off = 1; off <= 8; off <<= 1) {
      s += __shfl_xor(s, off);
      s2 += __shfl_xor(s2, off);
    }
    float mean = s * (1.0f / 64.0f);
    float var = s2 * (1.0f / 64.0f) - mean * mean;
    float rs = rsqrtf(var + EPSLN);
#pragma unroll
    for (int j = 0; j < 4; ++j)
      o[j][r] = (o[j][r] - mean) * rs * gam[j * 16 + c] + bet[j * 16 + c];
  }
  __syncthreads();   // all waves done reading A and B
#pragma unroll
  for (int j = 0; j < 4; ++j) {
    int col = j * 16 + c;
#pragma unroll
    for (int r = 0; r < 4; ++r) {
      io[(size_t)(rowb + r) * 64 + col] = o[j][r];
      A[(w * 16 + 4 * g + r) * 72 + col] = f2bf(o[j][r]);
    }
  }
  stage_bf(wt + 8192, B, 64 * 8, 64, 72, tid);        // Wqt
  stage_bf(wt + 12288, B + 4608, 64 * 8, 64, 72, tid);  // Wkt
  stage_bf(wt + 16384, B + 9216, 64 * 8, 64, 72, tid);  // Wvt
  __syncthreads();
  f32x4 aq[4], ak[4], av[4];
#pragma unroll
  for (int j = 0; j < 4; ++j) {
#pragma unroll
    for (int r = 0; r < 4; ++r) { aq[j][r] = 0.f; ak[j][r] = 0.f; av[j][r] = 0.f; }
  }
#pragma unroll
  for (int kk = 0; kk < 2; ++kk) {
    bf16x8 af = *(const bf16x8*)(xrow + kk * 32);
#pragma unroll
    for (int j = 0; j < 4; ++j) {
      int boff = (j * 16 + c) * 72 + kk * 32 + g * 8;
      aq[j] = __builtin_amdgcn_mfma_f32_16x16x32_bf16(af, *(const bf16x8*)(B + boff), aq[j], 0, 0, 0);
      ak[j] = __builtin_amdgcn_mfma_f32_16x16x32_bf16(af, *(const bf16x8*)(B + 4608 + boff), ak[j], 0, 0, 0);
      av[j] = __builtin_amdgcn_mfma_f32_16x16x32_bf16(af, *(const bf16x8*)(B + 9216 + boff), av[j], 0, 0, 0);
    }
  }
#pragma unroll
  for (int j = 0; j < 4; ++j) {
    int col = j * 16 + c;
    float bqj = bqt[col], bkj = bkt[col], bvj = bvt[col];
#pragma unroll
    for (int r = 0; r < 4; ++r) {
      size_t oo = (size_t)(rowb + r) * 64 + col;
      qt[oo] = f2bf(aq[j][r] + bqj);
      kt[oo] = f2bf(ak[j][r] + bkj);
      vt[oo] = f2bf(av[j][r] + bvj);
    }
  }
}

// K8: temporal attention via MFMA
#define VST 20
#define PST 40
__global__ void __launch_bounds__(256)
k_tattn(const unsigned short* __restrict__ qtb, const unsigned short* __restrict__ ktb,
        const unsigned short* __restrict__ vtb, float* __restrict__ attn) {
  int b = blockIdx.x >> 2, hh = blockIdx.x & 3;
  __shared__ unsigned short Qs[NFRM][16];
  __shared__ unsigned short Ks[NFRM][16];
  __shared__ unsigned short Vs[NFRM][VST];
  __shared__ unsigned short Ps[4][16][PST];
  int t = threadIdx.x;
  int wv = t >> 6, lane = t & 63;
  int g = lane >> 4, c = lane & 15;
  {
    size_t src = ((size_t)b * NFRM + t) * DD + hh * 16;
    const uint4* qsrc = (const uint4*)(qtb + src);
    const uint4* ksrc = (const uint4*)(ktb + src);
    const uint2* vsrc = (const uint2*)(vtb + src);
    ((uint4*)Qs[t])[0] = qsrc[0]; ((uint4*)Qs[t])[1] = qsrc[1];
    ((uint4*)Ks[t])[0] = ksrc[0]; ((uint4*)Ks[t])[1] = ksrc[1];
    uint2* vdst = (uint2*)Vs[t];
    vdst[0] = vsrc[0]; vdst[1] = vsrc[1]; vdst[2] = vsrc[2]; vdst[3] = vsrc[3];
  }
  __syncthreads();
  const bf16x8 zf = {0, 0, 0, 0, 0, 0, 0, 0};
  unsigned short (*P)[PST] = Ps[wv];
  for (int qt0 = wv; qt0 < 16; qt0 += 4) {
    bf16x8 qf = zf;
    if (g < 2) qf = *(const bf16x8*)&Qs[qt0 * 16 + c][g * 8];
    f32x4 O = {0.f, 0.f, 0.f, 0.f};
    float lacc[4] = {0.f, 0.f, 0.f, 0.f};
    for (int jp = 0; jp < 8; ++jp) {
#pragma unroll
      for (int half = 0; half < 2; ++half) {
        int jt = jp * 2 + half;
        bf16x8 kf = zf;
        if (g < 2) kf = *(const bf16x8*)&Ks[jt * 16 + c][g * 8];
        f32x4 S = __builtin_amdgcn_mfma_f32_16x16x32_bf16(qf, kf,
                    (f32x4){0.f, 0.f, 0.f, 0.f}, 0, 0, 0);
#pragma unroll
        for (int r = 0; r < 4; ++r) {
          float p = __expf(S[r] * SCL);
          lacc[r] += p;
          P[4 * g + r][half * 16 + c] = f2bf(p);
        }
      }
      bf16x8 pf = *(const bf16x8*)&P[c][g * 8];
      bf16x8 vf;
#pragma unroll
      for (int i = 0; i < 8; ++i) vf[i] = (short)Vs[jp * 32 + g * 8 + i][c];
      O = __builtin_amdgcn_mfma_f32_16x16x32_bf16(pf, vf, O, 0, 0, 0);
    }
#pragma unroll
    for (int r = 0; r < 4; ++r) {
      float s = lacc[r];
      s += __shfl_xor(s, 1); s += __shfl_xor(s, 2);
      s += __shfl_xor(s, 4); s += __shfl_xor(s, 8);
      lacc[r] = 1.0f / s;
    }
    size_t obase = ((size_t)b * NFRM + qt0 * 16) * DD + hh * 16;
#pragma unroll
    for (int r = 0; r < 4; ++r)
      attn[obase + (size_t)(4 * g + r) * DD + c] = O[r] * lacc[r];
  }
}

// Fused block2: x = LN1(f_h + attn @ Wot + bot); u = relu(x@W1+b1);
// xtb = LN2(x + u@W2 + b2)  (bf16 out)
__global__ void __launch_bounds__(256)
k_blk2(const float* __restrict__ attn, const unsigned short* __restrict__ wt,
       const float* __restrict__ res, const float* __restrict__ bot,
       const float* __restrict__ l1g, const float* __restrict__ l1b,
       const float* __restrict__ b1, const float* __restrict__ b2,
       const float* __restrict__ l2g, const float* __restrict__ l2b,
       unsigned short* __restrict__ xtb) {
  __shared__ unsigned short XLs[64 * 72];     // LN1 result
  __shared__ unsigned short BufW[128 * 72];   // Wot -> W1 -> W2
  __shared__ unsigned short BufX[64 * 136];   // attn Xs -> u
  int tid = threadIdx.x;
  int n0 = blockIdx.x * 64;
  int lane = tid & 63, w = tid >> 6;
  int c = lane & 15, g = lane >> 4;
  int rowb = n0 + w * 16 + 4 * g;
  // phase 1: attn @ Wot
  stage_f32(attn + (size_t)n0 * 64, BufX, 64 * 16, 64, 72, tid);
  stage_bf(wt + 4096, BufW, 64 * 8, 64, 72, tid);   // Wot
  __syncthreads();
  f32x4 acc[4];
#pragma unroll
  for (int j = 0; j < 4; ++j) { acc[j][0] = 0.f; acc[j][1] = 0.f; acc[j][2] = 0.f; acc[j][3] = 0.f; }
  const unsigned short* xrow = BufX + (w * 16 + c) * 72 + g * 8;
#pragma unroll
  for (int kk = 0; kk < 2; ++kk) {
    bf16x8 af = *(const bf16x8*)(xrow + kk * 32);
#pragma unroll
    for (int j = 0; j < 4; ++j)
      acc[j] = __builtin_amdgcn_mfma_f32_16x16x32_bf16(af,
                 *(const bf16x8*)(BufW + (j * 16 + c) * 72 + kk * 32 + g * 8), acc[j], 0, 0, 0);
  }
  float x[4][4];
#pragma unroll
  for (int j = 0; j < 4; ++j) {
    int col = j * 16 + c;
    float bb = bot[col];
#pragma unroll
    for (int r = 0; r < 4; ++r)
      x[j][r] = acc[j][r] + bb + res[(size_t)(rowb + r) * 64 + col];
  }
#pragma unroll
  for (int r = 0; r < 4; ++r) {
    float s = (x[0][r] + x[1][r]) + (x[2][r] + x[3][r]);
    float s2 = (x[0][r] * x[0][r] + x[1][r] * x[1][r]) + (x[2][r] * x[2][r] + x[3][r] * x[3][r]);
#pragma unroll
    for (int off = 1; off <= 8; off <<= 1) {
      s += __shfl_xor(s, off);
      s2 += __shfl_xor(s2, off);
    }
    float mean = s * (1.0f / 64.0f);
    float var = s2 * (1.0f / 64.0f) - mean * mean;
    float rs = rsqrtf(var + EPSLN);
#pragma unroll
    for (int j = 0; j < 4; ++j)
      x[j][r] = (x[j][r] - mean) * rs * l1g[j * 16 + c] + l1b[j * 16 + c];
  }
  __syncthreads();   // all done with BufX/BufW
  // phase 2: write x -> XLs, stage W1
#pragma unroll
  for (int j = 0; j < 4; ++j)
#pragma unroll
    for (int r = 0; r < 4; ++r)
      XLs[(w * 16 + 4 * g + r) * 72 + j * 16 + c] = f2bf(x[j][r]);
  stage_bf(wt + 20480, BufW, 128 * 8, 64, 72, tid);  // W1
  __syncthreads();
  // phase 3: u = relu(XLs @ W1)
  f32x4 ua[8];
#pragma unroll
  for (int j = 0; j < 8; ++j) { ua[j][0] = 0.f; ua[j][1] = 0.f; ua[j][2] = 0.f; ua[j][3] = 0.f; }
  const unsigned short* xrow2 = XLs + (w * 16 + c) * 72 + g * 8;
#pragma unroll
  for (int kk = 0; kk < 2; ++kk) {
    bf16x8 af = *(const bf16x8*)(xrow2 + kk * 32);
#pragma unroll
    for (int j = 0; j < 8; ++j)
      ua[j] = __builtin_amdgcn_mfma_f32_16x16x32_bf16(af,
                *(const bf16x8*)(BufW + (j * 16 + c) * 72 + kk * 32 + g * 8), ua[j], 0, 0, 0);
  }
#pragma unroll
  for (int j = 0; j < 8; ++j) {
    int col = j * 16 + c;
    float bb = b1[col];
#pragma unroll
    for (int r = 0; r < 4; ++r)
      BufX[(w * 16 + 4 * g + r) * 136 + col] = f2bf(fmaxf(ua[j][r] + bb, 0.f));
  }
  __syncthreads();   // u complete; all waves done reading BufW (W1)
  stage_bf(wt + 28672, BufW, 64 * 16, 128, 136, tid);  // W2
  __syncthreads();
  // phase 4: y = u @ W2; LN2(x + y)
  f32x4 ya[4];
#pragma unroll
  for (int j = 0; j < 4; ++j) { ya[j][0] = 0.f; ya[j][1] = 0.f; ya[j][2] = 0.f; ya[j][3] = 0.f; }
  const unsigned short* urow = BufX + (w * 16 + c) * 136 + g * 8;
#pragma unroll
  for (int kk = 0; kk < 4; ++kk) {
    bf16x8 af = *(const bf16x8*)(urow + kk * 32);
#pragma unroll
    for (int j = 0; j < 4; ++j)
      ya[j] = __builtin_amdgcn_mfma_f32_16x16x32_bf16(af,
                *(const bf16x8*)(BufW + (j * 16 + c) * 136 + kk * 32 + g * 8), ya[j], 0, 0, 0);
  }
  float o2[4][4];
#pragma unroll
  for (int j = 0; j < 4; ++j) {
    int col = j * 16 + c;
    float bb = b2[col];
#pragma unroll
    for (int r = 0; r < 4; ++r)
      o2[j][r] = ya[j][r] + bb + x[j][r];
  }
#pragma unroll
  for (int r = 0; r < 4; ++r) {
    float s = (o2[0][r] + o2[1][r]) + (o2[2][r] + o2[3][r]);
    float s2 = (o2[0][r] * o2[0][r] + o2[1][r] * o2[1][r]) + (o2[2][r] * o2[2][r] + o2[3][r] * o2[3][r]);
#pragma unroll
    for (int off = 1; off <= 8; off <<= 1) {
      s += __shfl_xor(s, off);
      s2 += __shfl_xor(s2, off);
    }
    float mean = s * (1.0f / 64.0f);
    float var = s2 * (1.0f / 64.0f) - mean * mean;
    float rs = rsqrtf(var + EPSLN);
#pragma unroll
    for (int j = 0; j < 4; ++j)
      xtb[(size_t)(rowb + r) * 64 + j * 16 + c] =
          f2bf((o2[j][r] - mean) * rs * l2g[j * 16 + c] + l2b[j * 16 + c]);
  }
}

// agg1 GEMM via MFMA: part[ks][b][o] = sum_{k in chunk} xtb[b][k] * wa1t[o][k]
__global__ void __launch_bounds__(256)
k_agg1a_m(const unsigned short* __restrict__ xtb, const unsigned short* __restrict__ wa1t,
          float* __restrict__ part) {
  int ks = blockIdx.x >> 2, mt = blockIdx.x & 3;
  int t = threadIdx.x, lane = t & 63, w = t >> 6;
  int c = lane & 15, g = lane >> 4;
  int m0 = mt * 64;
  int k0 = ks * 512;
  f32x4 acc[4];
#pragma unroll
  for (int j = 0; j < 4; ++j) { acc[j][0] = 0.f; acc[j][1] = 0.f; acc[j][2] = 0.f; acc[j][3] = 0.f; }
  const unsigned short* arow = xtb + (size_t)(m0 + w * 16 + c) * 16384 + k0 + g * 8;
  const unsigned short* brow = wa1t + (size_t)c * 16384 + k0 + g * 8;
#pragma unroll 4
  for (int kk = 0; kk < 16; ++kk) {
    bf16x8 af = *(const bf16x8*)(arow + kk * 32);
#pragma unroll
    for (int j = 0; j < 4; ++j)
      acc[j] = __builtin_amdgcn_mfma_f32_16x16x32_bf16(af,
                 *(const bf16x8*)(brow + (size_t)j * 16 * 16384 + kk * 32), acc[j], 0, 0, 0);
  }
  int rowb = m0 + w * 16 + 4 * g;
#pragma unroll
  for (int j = 0; j < 4; ++j)
#pragma unroll
    for (int r = 0; r < 4; ++r)
      part[(size_t)ks * (BSZ * DD) + (size_t)(rowb + r) * 64 + j * 16 + c] = acc[j][r];
}

// K13: head MLP (+ fused partial reduce)
__global__ void k_head(const float* __restrict__ part, const float* __restrict__ ba1,
                       const float* __restrict__ Wa2, const float* __restrict__ ba2,
                       const float* __restrict__ Wh1, const float* __restrict__ bh1,
                       const float* __restrict__ Wh2, const float* __restrict__ bh2,
                       float* __restrict__ out) {
  int b = blockIdx.x, t = threadIdx.x;
  __shared__ float s1[64], s2[32], s3[16];
  float a0 = ba1[t];
#pragma unroll 8
  for (int ks = 0; ks < AKS; ++ks) a0 += part[(size_t)ks * (BSZ * DD) + b * 64 + t];
  s1[t] = fmaxf(a0, 0.f);
  __syncthreads();
  if (t < 32) {
    float a = ba2[t];
#pragma unroll 8
    for (int j = 0; j < 64; ++j) a += s1[j] * Wa2[j * 32 + t];
    s2[t] = fmaxf(a, 0.f);
  }
  __syncthreads();
  if (t < 16) {
    float a = bh1[t];
#pragma unroll
    for (int j = 0; j < 32; ++j) a += s2[j] * Wh1[j * 16 + t];
    s3[t] = fmaxf(a, 0.f);
  }
  __syncthreads();
  if (t == 0) {
    float a = bh2[0];
#pragma unroll
    for (int j = 0; j < 16; ++j) a += s3[j] * Wh2[j];
    out[b] = 1.0f / (1.0f + expf(-a));
  }
}

extern "C" void kernel_launch(void* const* d_in, const int* in_sizes, int n_in,
                              void* d_out, int out_size, void* d_ws, size_t ws_size,
                              hipStream_t stream) {
  const float* x   = (const float*)d_in[0];
  const int*   ei  = (const int*)d_in[1];
  const float* Wi  = (const float*)d_in[2];
  const float* bi  = (const float*)d_in[3];
  const float* pe  = (const float*)d_in[4];
  const float* Wq  = (const float*)d_in[5];
  const float* Wk  = (const float*)d_in[6];
  const float* Wv  = (const float*)d_in[7];
  const float* bq  = (const float*)d_in[8];
  const float* bk  = (const float*)d_in[9];
  const float* bv  = (const float*)d_in[10];
  const float* Ws  = (const float*)d_in[11];
  const float* bs  = (const float*)d_in[12];
  const float* Wo  = (const float*)d_in[13];
  const float* bo  = (const float*)d_in[14];
  const float* gg  = (const float*)d_in[15];
  const float* gb  = (const float*)d_in[16];
  const float* Wqt = (const float*)d_in[17];
  const float* Wkt = (const float*)d_in[18];
  const float* Wvt = (const float*)d_in[19];
  const float* bqt = (const float*)d_in[20];
  const float* bkt = (const float*)d_in[21];
  const float* bvt = (const float*)d_in[22];
  const float* Wot = (const float*)d_in[23];
  const float* bot = (const float*)d_in[24];
  const float* l1g = (const float*)d_in[25];
  const float* l1b = (const float*)d_in[26];
  const float* W1  = (const float*)d_in[27];
  const float* b1  = (const float*)d_in[28];
  const float* W2  = (const float*)d_in[29];
  const float* b2  = (const float*)d_in[30];
  const float* l2g = (const float*)d_in[31];
  const float* l2b = (const float*)d_in[32];
  const float* Wa1 = (const float*)d_in[33];
  const float* ba1 = (const float*)d_in[34];
  const float* Wa2 = (const float*)d_in[35];
  const float* ba2 = (const float*)d_in[36];
  const float* Wh1 = (const float*)d_in[37];
  const float* bh1 = (const float*)d_in[38];
  const float* Wh2 = (const float*)d_in[39];
  const float* bh2 = (const float*)d_in[40];
  float* out = (float*)d_out;

  const size_t ND = (size_t)NN * DD;

  float* wsf    = (float*)d_ws;
  float* f_h    = wsf;                 // h fp32 (residual chain)
  float* f_q    = f_h  + ND;           // q fp32 -> qt/kt bf16
  float* f_k    = f_q  + ND;           // kv packed -> vt bf16
  float* f_v    = f_k  + ND;           // spare
  float* f_sk   = f_v  + ND;           // skip -> attn
  float* f_u    = f_sk + ND;           // gattn tmp fp32 -> xtb bf16
  float* f_part = f_u  + 2 * ND;       // agg partials [AKS][256][64]
  float* f_a1   = f_part + (size_t)AKS * BSZ * DD;
  int* i_srcs   = (int*)(f_a1 + BSZ * DD);
  int* i_rowptr = i_srcs + NE;
  int* i_hist   = i_rowptr + NN + 1;
  int* i_btot   = i_hist + 65536;
  int* i_bbase  = i_btot + 256;
  int* i_pairs  = i_bbase + 256;
  unsigned short* wt = (unsigned short*)(i_pairs + NE);   // 53248 ushorts
  unsigned short* wa1t = wt + 53248;                      // [64][16384] bf16

  ushort2* f_kv = (ushort2*)f_k;
  float* f_tmp  = f_u;
  unsigned short* us_qt = (unsigned short*)f_q;
  unsigned short* us_kt = us_qt + ND;
  unsigned short* us_vt = (unsigned short*)f_k;
  unsigned short* us_xtb = (unsigned short*)f_u;

  dim3 B(256);
  k_wprep<<<dim3(208), B, 0, stream>>>(Wo, Wot, Wqt, Wkt, Wvt, W1, W2, Wq, Wk, Wv, Ws, wt);
  k_wprep2<<<dim3(256), B, 0, stream>>>(Wa1, wa1t);
  k_input<<<dim3(NN / (4 * RB)), B, 0, stream>>>(x, Wi, bi, pe, f_h);
  k_qkvs_m<<<dim3(NN / 64), B, 0, stream>>>(f_h, wt, bq, bk, bv, bs, f_q, f_kv, f_sk);
  k_hist <<<dim3(256), B, 0, stream>>>(ei, i_hist);
  k_hscan<<<dim3(256), B, 0, stream>>>(i_hist, i_btot);
  k_bscan<<<dim3(1),   B, 0, stream>>>(i_btot, i_bbase);
  k_passB<<<dim3(256), B, 0, stream>>>(ei, i_hist, i_bbase, i_pairs);
  k_passC<<<dim3(256), B, 0, stream>>>(i_pairs, i_bbase, i_btot, i_rowptr, i_srcs);
  k_gattn<<<dim3(NN / 4), B, 0, stream>>>(f_q, (const unsigned*)f_kv, i_rowptr, i_srcs,
                                          f_sk, f_tmp);
  k_mlqkvt<<<dim3(NN / 64), B, 0, stream>>>(f_tmp, wt, bo, gg, gb, f_h,
                                            bqt, bkt, bvt, us_qt, us_kt, us_vt);
  k_tattn<<<dim3(BSZ * HH), B, 0, stream>>>(us_qt, us_kt, us_vt, f_sk);
  k_blk2<<<dim3(NN / 64), B, 0, stream>>>(f_sk, wt, f_h, bot, l1g, l1b, b1, b2,
                                          l2g, l2b, us_xtb);
  k_agg1a_m<<<dim3(AKS * 4), B, 0, stream>>>(us_xtb, wa1t, f_part);
  k_head<<<dim3(BSZ), dim3(64), 0, stream>>>(f_part, ba1, Wa2, ba2, Wh1, bh1, Wh2, bh2, out);
}

// Round 11
// 209.157 us; speedup vs baseline: 1.3141x; 1.0373x over previous
//
#include <hip/hip_runtime.h>
#include <math.h>

#define NN 65536
#define SIN 24
#define DD 64
#define HH 4
#define HDIM 16
#define NFRM 256
#define NE 1048576
#define BSZ 256
#define EPSLN 1e-5f
#define SCL 0.25f
#define RB 8
#define AKS 32   // K-splits for agg1 MFMA GEMM

typedef __attribute__((ext_vector_type(8))) short bf16x8;
typedef __attribute__((ext_vector_type(4))) float f32x4;

__device__ __forceinline__ unsigned short f2bf(float f) {
  unsigned u = __float_as_uint(f);
  return (unsigned short)((u + 0x7FFFu + ((u >> 16) & 1u)) >> 16);
}
__device__ __forceinline__ float bf2f(unsigned short b) {
  return __uint_as_float(((unsigned)b) << 16);
}
__device__ __forceinline__ float bflo(unsigned u) {
  return __uint_as_float(u << 16);
}
__device__ __forceinline__ float bfhi(unsigned u) {
  return __uint_as_float(u & 0xFFFF0000u);
}

// stage fp32 [rows][DK] -> bf16 LDS [rows][ST]
__device__ __forceinline__ void stage_f32(const float* __restrict__ src,
                                          unsigned short* dst, int n4, int DK, int ST, int tid) {
  int dk4 = DK >> 2;
  for (int idx = tid; idx < n4; idx += 256) {
    int row = idx / dk4, c = (idx % dk4) * 4;
    float4 v = *(const float4*)(src + (size_t)row * DK + c);
    uint2 p;
    p.x = (unsigned)f2bf(v.x) | ((unsigned)f2bf(v.y) << 16);
    p.y = (unsigned)f2bf(v.z) | ((unsigned)f2bf(v.w) << 16);
    *(uint2*)(dst + row * ST + c) = p;
  }
}

// stage bf16 [rows][DK] -> LDS [rows][ST]
__device__ __forceinline__ void stage_bf(const unsigned short* __restrict__ src,
                                         unsigned short* dst, int n8, int DK, int ST, int tid) {
  int dk8 = DK >> 3;
  for (int idx = tid; idx < n8; idx += 256) {
    int row = idx / dk8, c = (idx % dk8) * 8;
    *(uint4*)(dst + row * ST + c) = *(const uint4*)(src + (size_t)row * DK + c);
  }
}

// K1: h = x @ Wi + bi + pe[n % NF]
__global__ void k_input(const float* __restrict__ x, const float* __restrict__ Wi,
                        const float* __restrict__ bi, const float* __restrict__ pe,
                        float* __restrict__ h) {
  int lane = threadIdx.x & 63;
  int wid = __builtin_amdgcn_readfirstlane(threadIdx.x >> 6);
  int n0 = (blockIdx.x * 4 + wid) * RB;
  float b = bi[lane];
  float acc[RB];
#pragma unroll
  for (int r = 0; r < RB; ++r) acc[r] = b + pe[((n0 + r) & (NFRM - 1)) * DD + lane];
  for (int s = 0; s < SIN; ++s) {
    float w = Wi[s * DD + lane];
#pragma unroll
    for (int r = 0; r < RB; ++r) acc[r] += x[(size_t)(n0 + r) * SIN + s] * w;
  }
#pragma unroll
  for (int r = 0; r < RB; ++r) h[(size_t)(n0 + r) * DD + lane] = acc[r];
}

// Weight prep: transpose all dense weights to bf16 Wt[Nout][Dk]
__global__ void k_wprep(const float* __restrict__ Wo, const float* __restrict__ Wot,
                        const float* __restrict__ Wqt, const float* __restrict__ Wkt,
                        const float* __restrict__ Wvt, const float* __restrict__ W1,
                        const float* __restrict__ W2, const float* __restrict__ Wq,
                        const float* __restrict__ Wk, const float* __restrict__ Wv,
                        const float* __restrict__ Wsk, unsigned short* __restrict__ wt) {
  int i = blockIdx.x * 256 + threadIdx.x;
  if (i >= 53248) return;
  float v;
  if (i < 4096)       { int t = i;         int j = t >> 6, d = t & 63; v = Wo[d * 64 + j]; }
  else if (i < 8192)  { int t = i - 4096;  int j = t >> 6, d = t & 63; v = Wot[d * 64 + j]; }
  else if (i < 12288) { int t = i - 8192;  int j = t >> 6, d = t & 63; v = Wqt[d * 64 + j]; }
  else if (i < 16384) { int t = i - 12288; int j = t >> 6, d = t & 63; v = Wkt[d * 64 + j]; }
  else if (i < 20480) { int t = i - 16384; int j = t >> 6, d = t & 63; v = Wvt[d * 64 + j]; }
  else if (i < 28672) { int t = i - 20480; int j = t >> 6, d = t & 63; v = W1[d * 128 + j]; }
  else if (i < 36864) { int t = i - 28672; int j = t >> 7, d = t & 127; v = W2[d * 64 + j]; }
  else if (i < 40960) { int t = i - 36864; int j = t >> 6, d = t & 63; v = Wq[(j >> 4) * 1024 + d * 16 + (j & 15)]; }
  else if (i < 45056) { int t = i - 40960; int j = t >> 6, d = t & 63; v = Wk[(j >> 4) * 1024 + d * 16 + (j & 15)]; }
  else if (i < 49152) { int t = i - 45056; int j = t >> 6, d = t & 63; v = Wv[(j >> 4) * 1024 + d * 16 + (j & 15)]; }
  else                { int t = i - 49152; int j = t >> 6, d = t & 63; v = Wsk[(j >> 4) * 1024 + d * 16 + (j & 15)]; }
  wt[i] = f2bf(v);
}

// Wa1 [16384][64] fp32 -> wa1t [64][16384] bf16  (LDS-tiled transpose)
__global__ void k_wprep2(const float* __restrict__ Wa1, unsigned short* __restrict__ wa1t) {
  __shared__ float tile[64][65];
  int kb = blockIdx.x;
  int t = threadIdx.x;
  int c = t & 63, r0 = t >> 6;
  int k0 = kb * 64;
#pragma unroll
  for (int i = 0; i < 16; ++i) {
    int r = r0 + i * 4;
    tile[r][c] = Wa1[(size_t)(k0 + r) * 64 + c];
  }
  __syncthreads();
#pragma unroll
  for (int i = 0; i < 16; ++i) {
    int o = r0 + i * 4;
    wa1t[(size_t)o * 16384 + k0 + c] = f2bf(tile[c][o]);
  }
}

// K2 (MFMA): q fp32, kv packed bf16, sk fp32
__global__ void __launch_bounds__(256)
k_qkvs_m(const float* __restrict__ h, const unsigned short* __restrict__ wt,
         const float* __restrict__ bq, const float* __restrict__ bk,
         const float* __restrict__ bv, const float* __restrict__ bs,
         float* __restrict__ q, ushort2* __restrict__ kv, float* __restrict__ sk) {
  __shared__ unsigned short Xs[64 * 72];
  __shared__ unsigned short Ws4[4 * 64 * 72];
  int tid = threadIdx.x;
  int n0 = blockIdx.x * 64;
  stage_f32(h + (size_t)n0 * 64, Xs, 64 * 16, 64, 72, tid);
  stage_bf(wt + 36864, Ws4, 64 * 8, 64, 72, tid);
  stage_bf(wt + 40960, Ws4 + 4608, 64 * 8, 64, 72, tid);
  stage_bf(wt + 45056, Ws4 + 9216, 64 * 8, 64, 72, tid);
  stage_bf(wt + 49152, Ws4 + 13824, 64 * 8, 64, 72, tid);
  __syncthreads();
  int lane = tid & 63, w = tid >> 6;
  int c = lane & 15, g = lane >> 4;
  f32x4 aq[4], ak[4], av[4], as_[4];
#pragma unroll
  for (int j = 0; j < 4; ++j) {
#pragma unroll
    for (int r = 0; r < 4; ++r) { aq[j][r] = 0.f; ak[j][r] = 0.f; av[j][r] = 0.f; as_[j][r] = 0.f; }
  }
  const unsigned short* xrow = Xs + (w * 16 + c) * 72 + g * 8;
#pragma unroll
  for (int kk = 0; kk < 2; ++kk) {
    bf16x8 af = *(const bf16x8*)(xrow + kk * 32);
#pragma unroll
    for (int j = 0; j < 4; ++j) {
      int boff = (j * 16 + c) * 72 + kk * 32 + g * 8;
      aq[j] = __builtin_amdgcn_mfma_f32_16x16x32_bf16(af, *(const bf16x8*)(Ws4 + boff), aq[j], 0, 0, 0);
      ak[j] = __builtin_amdgcn_mfma_f32_16x16x32_bf16(af, *(const bf16x8*)(Ws4 + 4608 + boff), ak[j], 0, 0, 0);
      av[j] = __builtin_amdgcn_mfma_f32_16x16x32_bf16(af, *(const bf16x8*)(Ws4 + 9216 + boff), av[j], 0, 0, 0);
      as_[j] = __builtin_amdgcn_mfma_f32_16x16x32_bf16(af, *(const bf16x8*)(Ws4 + 13824 + boff), as_[j], 0, 0, 0);
    }
  }
  int rowb = n0 + w * 16 + 4 * g;
#pragma unroll
  for (int j = 0; j < 4; ++j) {
    int col = j * 16 + c;
    float bqj = bq[col], bkj = bk[col], bvj = bv[col], bsj = bs[col];
#pragma unroll
    for (int r = 0; r < 4; ++r) {
      size_t o = (size_t)(rowb + r) * 64 + col;
      q[o] = aq[j][r] + bqj;
      kv[o] = make_ushort2(f2bf(ak[j][r] + bkj), f2bf(av[j][r] + bvj));
      sk[o] = as_[j][r] + bsj;
    }
  }
}

// ---- Bucketed CSR build ----
__global__ void k_hist(const int* __restrict__ ei, int* __restrict__ hist) {
  __shared__ int h[256];
  int t = threadIdx.x;
  h[t] = 0;
  __syncthreads();
  int base = blockIdx.x * 4096;
#pragma unroll
  for (int r = 0; r < 16; ++r)
    atomicAdd(&h[ei[NE + base + r * 256 + t] >> 8], 1);
  __syncthreads();
  hist[t * 256 + blockIdx.x] = h[t];
}

__global__ void k_hscan(int* __restrict__ hist, int* __restrict__ btot) {
  __shared__ int s[256];
  int t = threadIdx.x, bkt = blockIdx.x;
  int v = hist[bkt * 256 + t];
  s[t] = v; __syncthreads();
  for (int off = 1; off < 256; off <<= 1) {
    int x = (t >= off) ? s[t - off] : 0;
    __syncthreads();
    s[t] += x;
    __syncthreads();
  }
  hist[bkt * 256 + t] = s[t] - v;
  if (t == 255) btot[bkt] = s[255];
}

__global__ void k_bscan(const int* __restrict__ btot, int* __restrict__ bbase) {
  __shared__ int s[256];
  int t = threadIdx.x;
  int v = btot[t];
  s[t] = v; __syncthreads();
  for (int off = 1; off < 256; off <<= 1) {
    int x = (t >= off) ? s[t - off] : 0;
    __syncthreads();
    s[t] += x;
    __syncthreads();
  }
  bbase[t] = s[t] - v;
}

__global__ void k_passB(const int* __restrict__ ei, const int* __restrict__ hist,
                        const int* __restrict__ bbase, int* __restrict__ pairs) {
  __shared__ int cur[256];
  int t = threadIdx.x;
  cur[t] = bbase[t] + hist[t * 256 + blockIdx.x];
  __syncthreads();
  int base = blockIdx.x * 4096;
#pragma unroll
  for (int r = 0; r < 16; ++r) {
    int e = base + r * 256 + t;
    int src = ei[e], dst = ei[NE + e];
    int pos = atomicAdd(&cur[dst >> 8], 1);
    pairs[pos] = ((dst & 255) << 16) | src;
  }
}

__global__ void k_passC(const int* __restrict__ pairs, const int* __restrict__ bbase,
                        const int* __restrict__ btot, int* __restrict__ rowptr,
                        int* __restrict__ srcs) {
  __shared__ int cnt[256];
  __shared__ int s[256];
  int t = threadIdx.x, bkt = blockIdx.x;
  cnt[t] = 0;
  __syncthreads();
  int base = bbase[bkt], n = btot[bkt];
  for (int i = t; i < n; i += 256) atomicAdd(&cnt[pairs[base + i] >> 16], 1);
  __syncthreads();
  int v = cnt[t];
  s[t] = v; __syncthreads();
  for (int off = 1; off < 256; off <<= 1) {
    int x = (t >= off) ? s[t - off] : 0;
    __syncthreads();
    s[t] += x;
    __syncthreads();
  }
  int rp = base + s[t] - v;
  rowptr[bkt * 256 + t] = rp;
  if (bkt == 0 && t == 0) rowptr[NN] = NE;
  __syncthreads();
  cnt[t] = rp;
  __syncthreads();
  for (int i = t; i < n; i += 256) {
    int p = pairs[base + i];
    int pos = atomicAdd(&cnt[p >> 16], 1);
    srcs[pos] = p & 0xFFFF;
  }
}

// Graph attention v4: half-wave per dst (8 dsts/block), lane = d*32 + e*8... lane = (d,e,h):
// d=lane>>5 (2 dsts/wave), e=(lane>>2)&7 (8 edge slots), h=lane&3 (4 heads).
// Two independent chains per wave + software-prefetched next batch. No max-subtraction.
__global__ void __launch_bounds__(256)
k_gattn(const float* __restrict__ q, const unsigned* __restrict__ kv,
        const int* __restrict__ rowptr, const int* __restrict__ srcs,
        const float* __restrict__ sk, float* __restrict__ tmp) {
  __shared__ float red[8][32][17];
  int tid = threadIdx.x;
  int lane = tid & 63;
  int slot = (tid >> 5) & 7;          // wave*2 + d
  int e = (lane >> 2) & 7, h = lane & 3;
  int dst = (blockIdx.x << 3) + slot;
  float qv[16];
#pragma unroll
  for (int i = 0; i < 4; ++i)
    ((float4*)qv)[i] = *(const float4*)(q + (size_t)dst * 64 + h * 16 + i * 4);
  int beg = rowptr[dst], end = rowptr[dst + 1];
  float l = 0.f;
  float acc[16];
#pragma unroll
  for (int i = 0; i < 16; ++i) acc[i] = 0.f;

  int idx = beg + e;
  int src = (idx < end) ? srcs[idx] : 0;
  const uint4* kp = (const uint4*)(kv + (size_t)src * 64 + h * 16);
  uint4 ka = kp[0], kb = kp[1], kc_ = kp[2], kd = kp[3];
  for (;;) {
    int nidx = idx + 8;
    bool any_next = __any(nidx < end);
    int nsrc = 0;
    uint4 na, nb, nc, nd;
    if (any_next) {
      nsrc = (nidx < end) ? srcs[nidx] : 0;
      const uint4* np = (const uint4*)(kv + (size_t)nsrc * 64 + h * 16);
      na = np[0]; nb = np[1]; nc = np[2]; nd = np[3];
    }
    bool valid = idx < end;
    float s;
    s  = bflo(ka.x) * qv[0]  + bflo(ka.y) * qv[1]  + bflo(ka.z) * qv[2]  + bflo(ka.w) * qv[3];
    s += bflo(kb.x) * qv[4]  + bflo(kb.y) * qv[5]  + bflo(kb.z) * qv[6]  + bflo(kb.w) * qv[7];
    s += bflo(kc_.x) * qv[8] + bflo(kc_.y) * qv[9] + bflo(kc_.z) * qv[10] + bflo(kc_.w) * qv[11];
    s += bflo(kd.x) * qv[12] + bflo(kd.y) * qv[13] + bflo(kd.z) * qv[14] + bflo(kd.w) * qv[15];
    float pex = valid ? __expf(s * SCL) : 0.f;
    l += pex;
    acc[0]  += pex * bfhi(ka.x);  acc[1]  += pex * bfhi(ka.y);
    acc[2]  += pex * bfhi(ka.z);  acc[3]  += pex * bfhi(ka.w);
    acc[4]  += pex * bfhi(kb.x);  acc[5]  += pex * bfhi(kb.y);
    acc[6]  += pex * bfhi(kb.z);  acc[7]  += pex * bfhi(kb.w);
    acc[8]  += pex * bfhi(kc_.x); acc[9]  += pex * bfhi(kc_.y);
    acc[10] += pex * bfhi(kc_.z); acc[11] += pex * bfhi(kc_.w);
    acc[12] += pex * bfhi(kd.x);  acc[13] += pex * bfhi(kd.y);
    acc[14] += pex * bfhi(kd.z);  acc[15] += pex * bfhi(kd.w);
    if (!any_next) break;
    ka = na; kb = nb; kc_ = nc; kd = nd;
    idx = nidx;
  }
  // l: butterfly over e-bits (lane bits 2,3,4) -> all lanes of (d,h) hold total
  l += __shfl_xor(l, 4); l += __shfl_xor(l, 8); l += __shfl_xor(l, 16);
  // acc transpose-reduce via LDS (intra-wave; stride 17)
  float* rw = &red[slot][lane & 31][0];
#pragma unroll
  for (int i = 0; i < 16; ++i) rw[i] = acc[i];
  int r32 = lane & 31;
  int h0 = r32 >> 4, i0 = r32 & 15;      // dim0 = h0*16+i0 (dims 0..31)
  float l0 = __shfl(l, (lane & 32) + h0);
  float l1 = __shfl(l, (lane & 32) + h0 + 2);
  float s0 = 0.f, s1 = 0.f;
#pragma unroll
  for (int ep = 0; ep < 8; ++ep) {
    s0 += red[slot][ep * 4 + h0][i0];
    s1 += red[slot][ep * 4 + h0 + 2][i0];
  }
  bool nonempty = end > beg;
  float a0 = nonempty ? s0 / l0 : 0.f;
  float a1 = nonempty ? s1 / l1 : 0.f;
  size_t o0 = (size_t)dst * 64 + r32;
  tmp[o0] = a0 + sk[o0];
  tmp[o0 + 32] = a1 + sk[o0 + 32];
}

// Fused: x = LN(f_h + tmp @ Wo + bo)  -> f_h (fp32) ; then qt,kt,vt = x @ W* + b* (bf16)
__global__ void __launch_bounds__(256)
k_mlqkvt(const float* __restrict__ in1, const unsigned short* __restrict__ wt,
         const float* __restrict__ bias, const float* __restrict__ gam,
         const float* __restrict__ bet, float* __restrict__ io,
         const float* __restrict__ bqt, const float* __restrict__ bkt,
         const float* __restrict__ bvt,
         unsigned short* __restrict__ qt, unsigned short* __restrict__ kt,
         unsigned short* __restrict__ vt) {
  __shared__ unsigned short A[64 * 72];
  __shared__ unsigned short B[3 * 64 * 72];
  int tid = threadIdx.x;
  int n0 = blockIdx.x * 64;
  stage_f32(in1 + (size_t)n0 * 64, A, 64 * 16, 64, 72, tid);
  stage_bf(wt + 0, B, 64 * 8, 64, 72, tid);       // Wo
  __syncthreads();
  int lane = tid & 63, w = tid >> 6;
  int c = lane & 15, g = lane >> 4;
  f32x4 acc[4];
#pragma unroll
  for (int j = 0; j < 4; ++j) { acc[j][0] = 0.f; acc[j][1] = 0.f; acc[j][2] = 0.f; acc[j][3] = 0.f; }
  const unsigned short* xrow = A + (w * 16 + c) * 72 + g * 8;
#pragma unroll
  for (int kk = 0; kk < 2; ++kk) {
    bf16x8 af = *(const bf16x8*)(xrow + kk * 32);
#pragma unroll
    for (int j = 0; j < 4; ++j)
      acc[j] = __builtin_amdgcn_mfma_f32_16x16x32_bf16(af,
                 *(const bf16x8*)(B + (j * 16 + c) * 72 + kk * 32 + g * 8), acc[j], 0, 0, 0);
  }
  int rowb = n0 + w * 16 + 4 * g;
  float o[4][4];
#pragma unroll
  for (int j = 0; j < 4; ++j) {
    int col = j * 16 + c;
    float bb = bias[col];
#pragma unroll
    for (int r = 0; r < 4; ++r)
      o[j][r] = acc[j][r] + bb + io[(size_t)(rowb + r) * 64 + col];
  }
#pragma unroll
  for (int r = 0; r < 4; ++r) {
    float s = (o[0][r] + o[1][r]) + (o[2][r] + o[3][r]);
    float s2 = (o[0][r] * o[0][r] + o[1][r] * o[1][r]) + (o[2][r] * o[2][r] + o[3][r] * o[3][r]);
#pragma unroll
    for (int off = 1; off <= 8; off <<= 1) {
      s += __shfl_xor(s, off);
      s2 += __shfl_xor(s2, off);
    }
    float mean = s * (1.0f / 64.0f);
    float var = s2 * (1.0f / 64.0f) - mean * mean;
    float rs = rsqrtf(var + EPSLN);
#pragma unroll
    for (int j = 0; j < 4; ++j)
      o[j][r] = (o[j][r] - mean) * rs * gam[j * 16 + c] + bet[j * 16 + c];
  }
  __syncthreads();   // all waves done reading A and B
#pragma unroll
  for (int j = 0; j < 4; ++j) {
    int col = j * 16 + c;
#pragma unroll
    for (int r = 0; r < 4; ++r) {
      io[(size_t)(rowb + r) * 64 + col] = o[j][r];
      A[(w * 16 + 4 * g + r) * 72 + col] = f2bf(o[j][r]);
    }
  }
  stage_bf(wt + 8192, B, 64 * 8, 64, 72, tid);        // Wqt
  stage_bf(wt + 12288, B + 4608, 64 * 8, 64, 72, tid);  // Wkt
  stage_bf(wt + 16384, B + 9216, 64 * 8, 64, 72, tid);  // Wvt
  __syncthreads();
  f32x4 aq[4], ak[4], av[4];
#pragma unroll
  for (int j = 0; j < 4; ++j) {
#pragma unroll
    for (int r = 0; r < 4; ++r) { aq[j][r] = 0.f; ak[j][r] = 0.f; av[j][r] = 0.f; }
  }
#pragma unroll
  for (int kk = 0; kk < 2; ++kk) {
    bf16x8 af = *(const bf16x8*)(xrow + kk * 32);
#pragma unroll
    for (int j = 0; j < 4; ++j) {
      int boff = (j * 16 + c) * 72 + kk * 32 + g * 8;
      aq[j] = __builtin_amdgcn_mfma_f32_16x16x32_bf16(af, *(const bf16x8*)(B + boff), aq[j], 0, 0, 0);
      ak[j] = __builtin_amdgcn_mfma_f32_16x16x32_bf16(af, *(const bf16x8*)(B + 4608 + boff), ak[j], 0, 0, 0);
      av[j] = __builtin_amdgcn_mfma_f32_16x16x32_bf16(af, *(const bf16x8*)(B + 9216 + boff), av[j], 0, 0, 0);
    }
  }
#pragma unroll
  for (int j = 0; j < 4; ++j) {
    int col = j * 16 + c;
    float bqj = bqt[col], bkj = bkt[col], bvj = bvt[col];
#pragma unroll
    for (int r = 0; r < 4; ++r) {
      size_t oo = (size_t)(rowb + r) * 64 + col;
      qt[oo] = f2bf(aq[j][r] + bqj);
      kt[oo] = f2bf(ak[j][r] + bkj);
      vt[oo] = f2bf(av[j][r] + bvj);
    }
  }
}

// K8: temporal attention via MFMA
#define VST 20
#define PST 40
__global__ void __launch_bounds__(256)
k_tattn(const unsigned short* __restrict__ qtb, const unsigned short* __restrict__ ktb,
        const unsigned short* __restrict__ vtb, float* __restrict__ attn) {
  int b = blockIdx.x >> 2, hh = blockIdx.x & 3;
  __shared__ unsigned short Qs[NFRM][16];
  __shared__ unsigned short Ks[NFRM][16];
  __shared__ unsigned short Vs[NFRM][VST];
  __shared__ unsigned short Ps[4][16][PST];
  int t = threadIdx.x;
  int wv = t >> 6, lane = t & 63;
  int g = lane >> 4, c = lane & 15;
  {
    size_t src = ((size_t)b * NFRM + t) * DD + hh * 16;
    const uint4* qsrc = (const uint4*)(qtb + src);
    const uint4* ksrc = (const uint4*)(ktb + src);
    const uint2* vsrc = (const uint2*)(vtb + src);
    ((uint4*)Qs[t])[0] = qsrc[0]; ((uint4*)Qs[t])[1] = qsrc[1];
    ((uint4*)Ks[t])[0] = ksrc[0]; ((uint4*)Ks[t])[1] = ksrc[1];
    uint2* vdst = (uint2*)Vs[t];
    vdst[0] = vsrc[0]; vdst[1] = vsrc[1]; vdst[2] = vsrc[2]; vdst[3] = vsrc[3];
  }
  __syncthreads();
  const bf16x8 zf = {0, 0, 0, 0, 0, 0, 0, 0};
  unsigned short (*P)[PST] = Ps[wv];
  for (int qt0 = wv; qt0 < 16; qt0 += 4) {
    bf16x8 qf = zf;
    if (g < 2) qf = *(const bf16x8*)&Qs[qt0 * 16 + c][g * 8];
    f32x4 O = {0.f, 0.f, 0.f, 0.f};
    float lacc[4] = {0.f, 0.f, 0.f, 0.f};
    for (int jp = 0; jp < 8; ++jp) {
#pragma unroll
      for (int half = 0; half < 2; ++half) {
        int jt = jp * 2 + half;
        bf16x8 kf = zf;
        if (g < 2) kf = *(const bf16x8*)&Ks[jt * 16 + c][g * 8];
        f32x4 S = __builtin_amdgcn_mfma_f32_16x16x32_bf16(qf, kf,
                    (f32x4){0.f, 0.f, 0.f, 0.f}, 0, 0, 0);
#pragma unroll
        for (int r = 0; r < 4; ++r) {
          float p = __expf(S[r] * SCL);
          lacc[r] += p;
          P[4 * g + r][half * 16 + c] = f2bf(p);
        }
      }
      bf16x8 pf = *(const bf16x8*)&P[c][g * 8];
      bf16x8 vf;
#pragma unroll
      for (int i = 0; i < 8; ++i) vf[i] = (short)Vs[jp * 32 + g * 8 + i][c];
      O = __builtin_amdgcn_mfma_f32_16x16x32_bf16(pf, vf, O, 0, 0, 0);
    }
#pragma unroll
    for (int r = 0; r < 4; ++r) {
      float s = lacc[r];
      s += __shfl_xor(s, 1); s += __shfl_xor(s, 2);
      s += __shfl_xor(s, 4); s += __shfl_xor(s, 8);
      lacc[r] = 1.0f / s;
    }
    size_t obase = ((size_t)b * NFRM + qt0 * 16) * DD + hh * 16;
#pragma unroll
    for (int r = 0; r < 4; ++r)
      attn[obase + (size_t)(4 * g + r) * DD + c] = O[r] * lacc[r];
  }
}

// Fused block2: x = LN1(f_h + attn @ Wot + bot); u = relu(x@W1+b1);
// xtb = LN2(x + u@W2 + b2)  (bf16 out)
__global__ void __launch_bounds__(256)
k_blk2(const float* __restrict__ attn, const unsigned short* __restrict__ wt,
       const float* __restrict__ res, const float* __restrict__ bot,
       const float* __restrict__ l1g, const float* __restrict__ l1b,
       const float* __restrict__ b1, const float* __restrict__ b2,
       const float* __restrict__ l2g, const float* __restrict__ l2b,
       unsigned short* __restrict__ xtb) {
  __shared__ unsigned short XLs[64 * 72];     // LN1 result
  __shared__ unsigned short BufW[128 * 72];   // Wot -> W1 -> W2
  __shared__ unsigned short BufX[64 * 136];   // attn Xs -> u
  int tid = threadIdx.x;
  int n0 = blockIdx.x * 64;
  int lane = tid & 63, w = tid >> 6;
  int c = lane & 15, g = lane >> 4;
  int rowb = n0 + w * 16 + 4 * g;
  // phase 1: attn @ Wot
  stage_f32(attn + (size_t)n0 * 64, BufX, 64 * 16, 64, 72, tid);
  stage_bf(wt + 4096, BufW, 64 * 8, 64, 72, tid);   // Wot
  __syncthreads();
  f32x4 acc[4];
#pragma unroll
  for (int j = 0; j < 4; ++j) { acc[j][0] = 0.f; acc[j][1] = 0.f; acc[j][2] = 0.f; acc[j][3] = 0.f; }
  const unsigned short* xrow = BufX + (w * 16 + c) * 72 + g * 8;
#pragma unroll
  for (int kk = 0; kk < 2; ++kk) {
    bf16x8 af = *(const bf16x8*)(xrow + kk * 32);
#pragma unroll
    for (int j = 0; j < 4; ++j)
      acc[j] = __builtin_amdgcn_mfma_f32_16x16x32_bf16(af,
                 *(const bf16x8*)(BufW + (j * 16 + c) * 72 + kk * 32 + g * 8), acc[j], 0, 0, 0);
  }
  float x[4][4];
#pragma unroll
  for (int j = 0; j < 4; ++j) {
    int col = j * 16 + c;
    float bb = bot[col];
#pragma unroll
    for (int r = 0; r < 4; ++r)
      x[j][r] = acc[j][r] + bb + res[(size_t)(rowb + r) * 64 + col];
  }
#pragma unroll
  for (int r = 0; r < 4; ++r) {
    float s = (x[0][r] + x[1][r]) + (x[2][r] + x[3][r]);
    float s2 = (x[0][r] * x[0][r] + x[1][r] * x[1][r]) + (x[2][r] * x[2][r] + x[3][r] * x[3][r]);
#pragma unroll
    for (int off = 1; off <= 8; off <<= 1) {
      s += __shfl_xor(s, off);
      s2 += __shfl_xor(s2, off);
    }
    float mean = s * (1.0f / 64.0f);
    float var = s2 * (1.0f / 64.0f) - mean * mean;
    float rs = rsqrtf(var + EPSLN);
#pragma unroll
    for (int j = 0; j < 4; ++j)
      x[j][r] = (x[j][r] - mean) * rs * l1g[j * 16 + c] + l1b[j * 16 + c];
  }
  __syncthreads();   // all done with BufX/BufW
  // phase 2: write x -> XLs, stage W1
#pragma unroll
  for (int j = 0; j < 4; ++j)
#pragma unroll
    for (int r = 0; r < 4; ++r)
      XLs[(w * 16 + 4 * g + r) * 72 + j * 16 + c] = f2bf(x[j][r]);
  stage_bf(wt + 20480, BufW, 128 * 8, 64, 72, tid);  // W1
  __syncthreads();
  // phase 3: u = relu(XLs @ W1)
  f32x4 ua[8];
#pragma unroll
  for (int j = 0; j < 8; ++j) { ua[j][0] = 0.f; ua[j][1] = 0.f; ua[j][2] = 0.f; ua[j][3] = 0.f; }
  const unsigned short* xrow2 = XLs + (w * 16 + c) * 72 + g * 8;
#pragma unroll
  for (int kk = 0; kk < 2; ++kk) {
    bf16x8 af = *(const bf16x8*)(xrow2 + kk * 32);
#pragma unroll
    for (int j = 0; j < 8; ++j)
      ua[j] = __builtin_amdgcn_mfma_f32_16x16x32_bf16(af,
                *(const bf16x8*)(BufW + (j * 16 + c) * 72 + kk * 32 + g * 8), ua[j], 0, 0, 0);
  }
#pragma unroll
  for (int j = 0; j < 8; ++j) {
    int col = j * 16 + c;
    float bb = b1[col];
#pragma unroll
    for (int r = 0; r < 4; ++r)
      BufX[(w * 16 + 4 * g + r) * 136 + col] = f2bf(fmaxf(ua[j][r] + bb, 0.f));
  }
  __syncthreads();   // u complete; all waves done reading BufW (W1)
  stage_bf(wt + 28672, BufW, 64 * 16, 128, 136, tid);  // W2
  __syncthreads();
  // phase 4: y = u @ W2; LN2(x + y)
  f32x4 ya[4];
#pragma unroll
  for (int j = 0; j < 4; ++j) { ya[j][0] = 0.f; ya[j][1] = 0.f; ya[j][2] = 0.f; ya[j][3] = 0.f; }
  const unsigned short* urow = BufX + (w * 16 + c) * 136 + g * 8;
#pragma unroll
  for (int kk = 0; kk < 4; ++kk) {
    bf16x8 af = *(const bf16x8*)(urow + kk * 32);
#pragma unroll
    for (int j = 0; j < 4; ++j)
      ya[j] = __builtin_amdgcn_mfma_f32_16x16x32_bf16(af,
                *(const bf16x8*)(BufW + (j * 16 + c) * 136 + kk * 32 + g * 8), ya[j], 0, 0, 0);
  }
  float o2[4][4];
#pragma unroll
  for (int j = 0; j < 4; ++j) {
    int col = j * 16 + c;
    float bb = b2[col];
#pragma unroll
    for (int r = 0; r < 4; ++r)
      o2[j][r] = ya[j][r] + bb + x[j][r];
  }
#pragma unroll
  for (int r = 0; r < 4; ++r) {
    float s = (o2[0][r] + o2[1][r]) + (o2[2][r] + o2[3][r]);
    float s2 = (o2[0][r] * o2[0][r] + o2[1][r] * o2[1][r]) + (o2[2][r] * o2[2][r] + o2[3][r] * o2[3][r]);
#pragma unroll
    for (int off = 1; off <= 8; off <<= 1) {
      s += __shfl_xor(s, off);
      s2 += __shfl_xor(s2, off);
    }
    float mean = s * (1.0f / 64.0f);
    float var = s2 * (1.0f / 64.0f) - mean * mean;
    float rs = rsqrtf(var + EPSLN);
#pragma unroll
    for (int j = 0; j < 4; ++j)
      xtb[(size_t)(rowb + r) * 64 + j * 16 + c] =
          f2bf((o2[j][r] - mean) * rs * l2g[j * 16 + c] + l2b[j * 16 + c]);
  }
}

// agg1 GEMM via MFMA: part[ks][b][o] = sum_{k in chunk} xtb[b][k] * wa1t[o][k]
__global__ void __launch_bounds__(256)
k_agg1a_m(const unsigned short* __restrict__ xtb, const unsigned short* __restrict__ wa1t,
          float* __restrict__ part) {
  int ks = blockIdx.x >> 2, mt = blockIdx.x & 3;
  int t = threadIdx.x, lane = t & 63, w = t >> 6;
  int c = lane & 15, g = lane >> 4;
  int m0 = mt * 64;
  int k0 = ks * 512;
  f32x4 acc[4];
#pragma unroll
  for (int j = 0; j < 4; ++j) { acc[j][0] = 0.f; acc[j][1] = 0.f; acc[j][2] = 0.f; acc[j][3] = 0.f; }
  const unsigned short* arow = xtb + (size_t)(m0 + w * 16 + c) * 16384 + k0 + g * 8;
  const unsigned short* brow = wa1t + (size_t)c * 16384 + k0 + g * 8;
#pragma unroll 4
  for (int kk = 0; kk < 16; ++kk) {
    bf16x8 af = *(const bf16x8*)(arow + kk * 32);
#pragma unroll
    for (int j = 0; j < 4; ++j)
      acc[j] = __builtin_amdgcn_mfma_f32_16x16x32_bf16(af,
                 *(const bf16x8*)(brow + (size_t)j * 16 * 16384 + kk * 32), acc[j], 0, 0, 0);
  }
  int rowb = m0 + w * 16 + 4 * g;
#pragma unroll
  for (int j = 0; j < 4; ++j)
#pragma unroll
    for (int r = 0; r < 4; ++r)
      part[(size_t)ks * (BSZ * DD) + (size_t)(rowb + r) * 64 + j * 16 + c] = acc[j][r];
}

// K13: head MLP (+ fused partial reduce)
__global__ void k_head(const float* __restrict__ part, const float* __restrict__ ba1,
                       const float* __restrict__ Wa2, const float* __restrict__ ba2,
                       const float* __restrict__ Wh1, const float* __restrict__ bh1,
                       const float* __restrict__ Wh2, const float* __restrict__ bh2,
                       float* __restrict__ out) {
  int b = blockIdx.x, t = threadIdx.x;
  __shared__ float s1[64], s2[32], s3[16];
  float a0 = ba1[t];
#pragma unroll 8
  for (int ks = 0; ks < AKS; ++ks) a0 += part[(size_t)ks * (BSZ * DD) + b * 64 + t];
  s1[t] = fmaxf(a0, 0.f);
  __syncthreads();
  if (t < 32) {
    float a = ba2[t];
#pragma unroll 8
    for (int j = 0; j < 64; ++j) a += s1[j] * Wa2[j * 32 + t];
    s2[t] = fmaxf(a, 0.f);
  }
  __syncthreads();
  if (t < 16) {
    float a = bh1[t];
#pragma unroll
    for (int j = 0; j < 32; ++j) a += s2[j] * Wh1[j * 16 + t];
    s3[t] = fmaxf(a, 0.f);
  }
  __syncthreads();
  if (t == 0) {
    float a = bh2[0];
#pragma unroll
    for (int j = 0; j < 16; ++j) a += s3[j] * Wh2[j];
    out[b] = 1.0f / (1.0f + expf(-a));
  }
}

extern "C" void kernel_launch(void* const* d_in, const int* in_sizes, int n_in,
                              void* d_out, int out_size, void* d_ws, size_t ws_size,
                              hipStream_t stream) {
  const float* x   = (const float*)d_in[0];
  const int*   ei  = (const int*)d_in[1];
  const float* Wi  = (const float*)d_in[2];
  const float* bi  = (const float*)d_in[3];
  const float* pe  = (const float*)d_in[4];
  const float* Wq  = (const float*)d_in[5];
  const float* Wk  = (const float*)d_in[6];
  const float* Wv  = (const float*)d_in[7];
  const float* bq  = (const float*)d_in[8];
  const float* bk  = (const float*)d_in[9];
  const float* bv  = (const float*)d_in[10];
  const float* Ws  = (const float*)d_in[11];
  const float* bs  = (const float*)d_in[12];
  const float* Wo  = (const float*)d_in[13];
  const float* bo  = (const float*)d_in[14];
  const float* gg  = (const float*)d_in[15];
  const float* gb  = (const float*)d_in[16];
  const float* Wqt = (const float*)d_in[17];
  const float* Wkt = (const float*)d_in[18];
  const float* Wvt = (const float*)d_in[19];
  const float* bqt = (const float*)d_in[20];
  const float* bkt = (const float*)d_in[21];
  const float* bvt = (const float*)d_in[22];
  const float* Wot = (const float*)d_in[23];
  const float* bot = (const float*)d_in[24];
  const float* l1g = (const float*)d_in[25];
  const float* l1b = (const float*)d_in[26];
  const float* W1  = (const float*)d_in[27];
  const float* b1  = (const float*)d_in[28];
  const float* W2  = (const float*)d_in[29];
  const float* b2  = (const float*)d_in[30];
  const float* l2g = (const float*)d_in[31];
  const float* l2b = (const float*)d_in[32];
  const float* Wa1 = (const float*)d_in[33];
  const float* ba1 = (const float*)d_in[34];
  const float* Wa2 = (const float*)d_in[35];
  const float* ba2 = (const float*)d_in[36];
  const float* Wh1 = (const float*)d_in[37];
  const float* bh1 = (const float*)d_in[38];
  const float* Wh2 = (const float*)d_in[39];
  const float* bh2 = (const float*)d_in[40];
  float* out = (float*)d_out;

  const size_t ND = (size_t)NN * DD;

  float* wsf    = (float*)d_ws;
  float* f_h    = wsf;                 // h fp32 (residual chain)
  float* f_q    = f_h  + ND;           // q fp32 -> qt/kt bf16
  float* f_k    = f_q  + ND;           // kv packed -> vt bf16
  float* f_v    = f_k  + ND;           // spare
  float* f_sk   = f_v  + ND;           // skip -> attn
  float* f_u    = f_sk + ND;           // gattn tmp fp32 -> xtb bf16
  float* f_part = f_u  + 2 * ND;       // agg partials [AKS][256][64]
  float* f_a1   = f_part + (size_t)AKS * BSZ * DD;
  int* i_srcs   = (int*)(f_a1 + BSZ * DD);
  int* i_rowptr = i_srcs + NE;
  int* i_hist   = i_rowptr + NN + 1;
  int* i_btot   = i_hist + 65536;
  int* i_bbase  = i_btot + 256;
  int* i_pairs  = i_bbase + 256;
  unsigned short* wt = (unsigned short*)(i_pairs + NE);   // 53248 ushorts
  unsigned short* wa1t = wt + 53248;                      // [64][16384] bf16

  ushort2* f_kv = (ushort2*)f_k;
  float* f_tmp  = f_u;
  unsigned short* us_qt = (unsigned short*)f_q;
  unsigned short* us_kt = us_qt + ND;
  unsigned short* us_vt = (unsigned short*)f_k;
  unsigned short* us_xtb = (unsigned short*)f_u;

  dim3 B(256);
  k_wprep<<<dim3(208), B, 0, stream>>>(Wo, Wot, Wqt, Wkt, Wvt, W1, W2, Wq, Wk, Wv, Ws, wt);
  k_wprep2<<<dim3(256), B, 0, stream>>>(Wa1, wa1t);
  k_input<<<dim3(NN / (4 * RB)), B, 0, stream>>>(x, Wi, bi, pe, f_h);
  k_qkvs_m<<<dim3(NN / 64), B, 0, stream>>>(f_h, wt, bq, bk, bv, bs, f_q, f_kv, f_sk);
  k_hist <<<dim3(256), B, 0, stream>>>(ei, i_hist);
  k_hscan<<<dim3(256), B, 0, stream>>>(i_hist, i_btot);
  k_bscan<<<dim3(1),   B, 0, stream>>>(i_btot, i_bbase);
  k_passB<<<dim3(256), B, 0, stream>>>(ei, i_hist, i_bbase, i_pairs);
  k_passC<<<dim3(256), B, 0, stream>>>(i_pairs, i_bbase, i_btot, i_rowptr, i_srcs);
  k_gattn<<<dim3(NN / 8), B, 0, stream>>>(f_q, (const unsigned*)f_kv, i_rowptr, i_srcs,
                                          f_sk, f_tmp);
  k_mlqkvt<<<dim3(NN / 64), B, 0, stream>>>(f_tmp, wt, bo, gg, gb, f_h,
                                            bqt, bkt, bvt, us_qt, us_kt, us_vt);
  k_tattn<<<dim3(BSZ * HH), B, 0, stream>>>(us_qt, us_kt, us_vt, f_sk);
  k_blk2<<<dim3(NN / 64), B, 0, stream>>>(f_sk, wt, f_h, bot, l1g, l1b, b1, b2,
                                          l2g, l2b, us_xtb);
  k_agg1a_m<<<dim3(AKS * 4), B, 0, stream>>>(us_xtb, wa1t, f_part);
  k_head<<<dim3(BSZ), dim3(64), 0, stream>>>(f_part, ba1, Wa2, ba2, Wh1, bh1, Wh2, bh2, out);
}

// Round 12
// 183.232 us; speedup vs baseline: 1.5001x; 1.1415x over previous
//
#include <hip/hip_runtime.h>
#include <hip/hip_fp16.h>
#include <math.h>

#define NN 65536
#define SIN 24
#define DD 64
#define HH 4
#define HDIM 16
#define NFRM 256
#define NE 1048576
#define BSZ 256
#define EPSLN 1e-5f
#define SCL 0.25f
#define AKS 32   // K-splits for agg1 MFMA GEMM

typedef __attribute__((ext_vector_type(8))) short bf16x8;
typedef __attribute__((ext_vector_type(4))) float f32x4;

__device__ __forceinline__ unsigned short f2bf(float f) {
  unsigned u = __float_as_uint(f);
  return (unsigned short)((u + 0x7FFFu + ((u >> 16) & 1u)) >> 16);
}
__device__ __forceinline__ float bf2f(unsigned short b) {
  return __uint_as_float(((unsigned)b) << 16);
}
__device__ __forceinline__ float bflo(unsigned u) {
  return __uint_as_float(u << 16);
}
__device__ __forceinline__ float bfhi(unsigned u) {
  return __uint_as_float(u & 0xFFFF0000u);
}
// fp32 -> e5m2 byte (fp16 high byte, round-to-nearest)
__device__ __forceinline__ unsigned f2e5(float f) {
  unsigned short h = __half_as_ushort(__float2half(f));
  unsigned r = (unsigned)h + 0x7Fu + ((h >> 8) & 1u);
  return (r >> 8) & 0xFFu;
}
__device__ __forceinline__ float h2fb(unsigned short b) {
  return __half2float(__ushort_as_half(b));
}
#define KLO(u) h2fb((unsigned short)((u) & 0xFF00u))
#define KHI(u) h2fb((unsigned short)(((u) >> 16) & 0xFF00u))
#define VLO(u) h2fb((unsigned short)(((u) << 8) & 0xFF00u))
#define VHI(u) h2fb((unsigned short)(((u) >> 8) & 0xFF00u))

// stage bf16 [rows][DK] -> LDS [rows][ST]
__device__ __forceinline__ void stage_bf(const unsigned short* __restrict__ src,
                                         unsigned short* dst, int n8, int DK, int ST, int tid) {
  int dk8 = DK >> 3;
  for (int idx = tid; idx < n8; idx += 256) {
    int row = idx / dk8, c = (idx % dk8) * 8;
    *(uint4*)(dst + row * ST + c) = *(const uint4*)(src + (size_t)row * DK + c);
  }
}

// Weight prep: transpose all dense weights to bf16 Wt[Nout][Dk]
__global__ void k_wprep(const float* __restrict__ Wo, const float* __restrict__ Wot,
                        const float* __restrict__ Wqt, const float* __restrict__ Wkt,
                        const float* __restrict__ Wvt, const float* __restrict__ W1,
                        const float* __restrict__ W2, const float* __restrict__ Wq,
                        const float* __restrict__ Wk, const float* __restrict__ Wv,
                        const float* __restrict__ Wsk, unsigned short* __restrict__ wt) {
  int i = blockIdx.x * 256 + threadIdx.x;
  if (i >= 53248) return;
  float v;
  if (i < 4096)       { int t = i;         int j = t >> 6, d = t & 63; v = Wo[d * 64 + j]; }
  else if (i < 8192)  { int t = i - 4096;  int j = t >> 6, d = t & 63; v = Wot[d * 64 + j]; }
  else if (i < 12288) { int t = i - 8192;  int j = t >> 6, d = t & 63; v = Wqt[d * 64 + j]; }
  else if (i < 16384) { int t = i - 12288; int j = t >> 6, d = t & 63; v = Wkt[d * 64 + j]; }
  else if (i < 20480) { int t = i - 16384; int j = t >> 6, d = t & 63; v = Wvt[d * 64 + j]; }
  else if (i < 28672) { int t = i - 20480; int j = t >> 6, d = t & 63; v = W1[d * 128 + j]; }
  else if (i < 36864) { int t = i - 28672; int j = t >> 7, d = t & 127; v = W2[d * 64 + j]; }
  else if (i < 40960) { int t = i - 36864; int j = t >> 6, d = t & 63; v = Wq[(j >> 4) * 1024 + d * 16 + (j & 15)]; }
  else if (i < 45056) { int t = i - 40960; int j = t >> 6, d = t & 63; v = Wk[(j >> 4) * 1024 + d * 16 + (j & 15)]; }
  else if (i < 49152) { int t = i - 45056; int j = t >> 6, d = t & 63; v = Wv[(j >> 4) * 1024 + d * 16 + (j & 15)]; }
  else                { int t = i - 49152; int j = t >> 6, d = t & 63; v = Wsk[(j >> 4) * 1024 + d * 16 + (j & 15)]; }
  wt[i] = f2bf(v);
}

// Wa1 [16384][64] fp32 -> wa1t [64][16384] bf16
__global__ void k_wprep2(const float* __restrict__ Wa1, unsigned short* __restrict__ wa1t) {
  __shared__ float tile[64][65];
  int kb = blockIdx.x;
  int t = threadIdx.x;
  int c = t & 63, r0 = t >> 6;
  int k0 = kb * 64;
#pragma unroll
  for (int i = 0; i < 16; ++i) {
    int r = r0 + i * 4;
    tile[r][c] = Wa1[(size_t)(k0 + r) * 64 + c];
  }
  __syncthreads();
#pragma unroll
  for (int i = 0; i < 16; ++i) {
    int o = r0 + i * 4;
    wa1t[(size_t)o * 16384 + k0 + c] = f2bf(tile[c][o]);
  }
}

// Fused input + qkvs: h = x@Wi + bi + pe (phase 0, VALU); f_h fp32;
// then MFMA: q bf16, kv8 (e5m2 packed k|v), sk bf16.
__global__ void __launch_bounds__(256)
k_qkvs_m(const float* __restrict__ x, const float* __restrict__ Wi,
         const float* __restrict__ bi, const float* __restrict__ pe,
         const unsigned short* __restrict__ wt,
         const float* __restrict__ bq, const float* __restrict__ bk,
         const float* __restrict__ bv, const float* __restrict__ bs,
         float* __restrict__ f_h, unsigned short* __restrict__ us_q,
         unsigned short* __restrict__ kv8, unsigned short* __restrict__ us_sk) {
  __shared__ unsigned short Xs[64 * 72];
  __shared__ unsigned short Ws4[4 * 64 * 72];
  float* Xs32 = (float*)Ws4;   // 64*25 floats = 6.4 KB, overlaps Ws4 (phase 0 only)
  int tid = threadIdx.x;
  int n0 = blockIdx.x * 64;
  // phase 0a: stage x
  for (int idx = tid; idx < 64 * SIN; idx += 256) {
    int row = idx / SIN, c = idx % SIN;
    Xs32[row * 25 + c] = x[(size_t)(n0 + row) * SIN + c];
  }
  __syncthreads();
  // phase 0b: compute h rows r0+4i, col j
  int j = tid & 63, r0 = tid >> 6;
  float hacc[16];
  {
    float bb = bi[j];
#pragma unroll
    for (int i = 0; i < 16; ++i) {
      int row = r0 + 4 * i;
      hacc[i] = bb + pe[((n0 + row) & (NFRM - 1)) * DD + j];
    }
    for (int s = 0; s < SIN; ++s) {
      float w = Wi[s * DD + j];
#pragma unroll
      for (int i = 0; i < 16; ++i)
        hacc[i] += Xs32[(r0 + 4 * i) * 25 + s] * w;
    }
  }
  __syncthreads();   // done reading Xs32 (Ws4 region)
  // phase 0c: write f_h + bf16 LDS; stage weights
#pragma unroll
  for (int i = 0; i < 16; ++i) {
    int row = r0 + 4 * i;
    f_h[(size_t)(n0 + row) * DD + j] = hacc[i];
    Xs[row * 72 + j] = f2bf(hacc[i]);
  }
  stage_bf(wt + 36864, Ws4, 64 * 8, 64, 72, tid);
  stage_bf(wt + 40960, Ws4 + 4608, 64 * 8, 64, 72, tid);
  stage_bf(wt + 45056, Ws4 + 9216, 64 * 8, 64, 72, tid);
  stage_bf(wt + 49152, Ws4 + 13824, 64 * 8, 64, 72, tid);
  __syncthreads();
  // phase 1: MFMA projections
  int lane = tid & 63, w = tid >> 6;
  int c = lane & 15, g = lane >> 4;
  f32x4 aq[4], ak[4], av[4], as_[4];
#pragma unroll
  for (int jj = 0; jj < 4; ++jj) {
#pragma unroll
    for (int r = 0; r < 4; ++r) { aq[jj][r] = 0.f; ak[jj][r] = 0.f; av[jj][r] = 0.f; as_[jj][r] = 0.f; }
  }
  const unsigned short* xrow = Xs + (w * 16 + c) * 72 + g * 8;
#pragma unroll
  for (int kk = 0; kk < 2; ++kk) {
    bf16x8 af = *(const bf16x8*)(xrow + kk * 32);
#pragma unroll
    for (int jj = 0; jj < 4; ++jj) {
      int boff = (jj * 16 + c) * 72 + kk * 32 + g * 8;
      aq[jj] = __builtin_amdgcn_mfma_f32_16x16x32_bf16(af, *(const bf16x8*)(Ws4 + boff), aq[jj], 0, 0, 0);
      ak[jj] = __builtin_amdgcn_mfma_f32_16x16x32_bf16(af, *(const bf16x8*)(Ws4 + 4608 + boff), ak[jj], 0, 0, 0);
      av[jj] = __builtin_amdgcn_mfma_f32_16x16x32_bf16(af, *(const bf16x8*)(Ws4 + 9216 + boff), av[jj], 0, 0, 0);
      as_[jj] = __builtin_amdgcn_mfma_f32_16x16x32_bf16(af, *(const bf16x8*)(Ws4 + 13824 + boff), as_[jj], 0, 0, 0);
    }
  }
  int rowb = n0 + w * 16 + 4 * g;
#pragma unroll
  for (int jj = 0; jj < 4; ++jj) {
    int col = jj * 16 + c;
    float bqj = bq[col], bkj = bk[col], bvj = bv[col], bsj = bs[col];
#pragma unroll
    for (int r = 0; r < 4; ++r) {
      size_t o = (size_t)(rowb + r) * 64 + col;
      us_q[o] = f2bf(aq[jj][r] + bqj);
      kv8[o] = (unsigned short)((f2e5(ak[jj][r] + bkj) << 8) | f2e5(av[jj][r] + bvj));
      us_sk[o] = f2bf(as_[jj][r] + bsj);
    }
  }
}

// ---- Bucketed CSR build ----
__global__ void k_hist(const int* __restrict__ ei, int* __restrict__ hist) {
  __shared__ int h[256];
  int t = threadIdx.x;
  h[t] = 0;
  __syncthreads();
  int base = blockIdx.x * 4096;
#pragma unroll
  for (int r = 0; r < 16; ++r)
    atomicAdd(&h[ei[NE + base + r * 256 + t] >> 8], 1);
  __syncthreads();
  hist[t * 256 + blockIdx.x] = h[t];
}

__global__ void k_hscan(int* __restrict__ hist, int* __restrict__ btot) {
  __shared__ int s[256];
  int t = threadIdx.x, bkt = blockIdx.x;
  int v = hist[bkt * 256 + t];
  s[t] = v; __syncthreads();
  for (int off = 1; off < 256; off <<= 1) {
    int x = (t >= off) ? s[t - off] : 0;
    __syncthreads();
    s[t] += x;
    __syncthreads();
  }
  hist[bkt * 256 + t] = s[t] - v;
  if (t == 255) btot[bkt] = s[255];
}

__global__ void k_bscan(const int* __restrict__ btot, int* __restrict__ bbase) {
  __shared__ int s[256];
  int t = threadIdx.x;
  int v = btot[t];
  s[t] = v; __syncthreads();
  for (int off = 1; off < 256; off <<= 1) {
    int x = (t >= off) ? s[t - off] : 0;
    __syncthreads();
    s[t] += x;
    __syncthreads();
  }
  bbase[t] = s[t] - v;
}

__global__ void k_passB(const int* __restrict__ ei, const int* __restrict__ hist,
                        const int* __restrict__ bbase, int* __restrict__ pairs) {
  __shared__ int cur[256];
  int t = threadIdx.x;
  cur[t] = bbase[t] + hist[t * 256 + blockIdx.x];
  __syncthreads();
  int base = blockIdx.x * 4096;
#pragma unroll
  for (int r = 0; r < 16; ++r) {
    int e = base + r * 256 + t;
    int src = ei[e], dst = ei[NE + e];
    int pos = atomicAdd(&cur[dst >> 8], 1);
    pairs[pos] = ((dst & 255) << 16) | src;
  }
}

__global__ void k_passC(const int* __restrict__ pairs, const int* __restrict__ bbase,
                        const int* __restrict__ btot, int* __restrict__ rowptr,
                        int* __restrict__ srcs) {
  __shared__ int cnt[256];
  __shared__ int s[256];
  int t = threadIdx.x, bkt = blockIdx.x;
  cnt[t] = 0;
  __syncthreads();
  int base = bbase[bkt], n = btot[bkt];
  for (int i = t; i < n; i += 256) atomicAdd(&cnt[pairs[base + i] >> 16], 1);
  __syncthreads();
  int v = cnt[t];
  s[t] = v; __syncthreads();
  for (int off = 1; off < 256; off <<= 1) {
    int x = (t >= off) ? s[t - off] : 0;
    __syncthreads();
    s[t] += x;
    __syncthreads();
  }
  int rp = base + s[t] - v;
  rowptr[bkt * 256 + t] = rp;
  if (bkt == 0 && t == 0) rowptr[NN] = NE;
  __syncthreads();
  cnt[t] = rp;
  __syncthreads();
  for (int i = t; i < n; i += 256) {
    int p = pairs[base + i];
    int pos = atomicAdd(&cnt[p >> 16], 1);
    srcs[pos] = p & 0xFFFF;
  }
}

// Graph attention v5: half-wave per dst, e5m2 kv8 gather (32B/edge-lane),
// bf16 q/sk/out. Prefetch double-buffer. No max-subtraction.
__global__ void __launch_bounds__(256)
k_gattn(const unsigned short* __restrict__ us_q, const unsigned short* __restrict__ kv8,
        const int* __restrict__ rowptr, const int* __restrict__ srcs,
        const unsigned short* __restrict__ us_sk, unsigned short* __restrict__ tmpb) {
  __shared__ float red[8][32][17];
  int tid = threadIdx.x;
  int lane = tid & 63;
  int slot = (tid >> 5) & 7;
  int e = (lane >> 2) & 7, h = lane & 3;
  int dst = (blockIdx.x << 3) + slot;
  float qv[16];
  {
    const uint4* qp = (const uint4*)(us_q + (size_t)dst * 64 + h * 16);
    uint4 q0 = qp[0], q1 = qp[1];
    qv[0] = bflo(q0.x); qv[1] = bfhi(q0.x); qv[2] = bflo(q0.y); qv[3] = bfhi(q0.y);
    qv[4] = bflo(q0.z); qv[5] = bfhi(q0.z); qv[6] = bflo(q0.w); qv[7] = bfhi(q0.w);
    qv[8] = bflo(q1.x); qv[9] = bfhi(q1.x); qv[10] = bflo(q1.y); qv[11] = bfhi(q1.y);
    qv[12] = bflo(q1.z); qv[13] = bfhi(q1.z); qv[14] = bflo(q1.w); qv[15] = bfhi(q1.w);
  }
  int beg = rowptr[dst], end = rowptr[dst + 1];
  float l = 0.f;
  float acc[16];
#pragma unroll
  for (int i = 0; i < 16; ++i) acc[i] = 0.f;

  int idx = beg + e;
  int src = (idx < end) ? srcs[idx] : 0;
  const uint4* kp = (const uint4*)(kv8 + (size_t)src * 64 + h * 16);
  uint4 A = kp[0], Bv = kp[1];
  for (;;) {
    int nidx = idx + 8;
    bool any_next = __any(nidx < end);
    uint4 nA, nB;
    if (any_next) {
      int nsrc = (nidx < end) ? srcs[nidx] : 0;
      const uint4* np = (const uint4*)(kv8 + (size_t)nsrc * 64 + h * 16);
      nA = np[0]; nB = np[1];
    }
    bool valid = idx < end;
    float s;
    s  = KLO(A.x) * qv[0]   + KHI(A.x) * qv[1]   + KLO(A.y) * qv[2]   + KHI(A.y) * qv[3];
    s += KLO(A.z) * qv[4]   + KHI(A.z) * qv[5]   + KLO(A.w) * qv[6]   + KHI(A.w) * qv[7];
    s += KLO(Bv.x) * qv[8]  + KHI(Bv.x) * qv[9]  + KLO(Bv.y) * qv[10] + KHI(Bv.y) * qv[11];
    s += KLO(Bv.z) * qv[12] + KHI(Bv.z) * qv[13] + KLO(Bv.w) * qv[14] + KHI(Bv.w) * qv[15];
    float pex = valid ? __expf(s * SCL) : 0.f;
    l += pex;
    acc[0]  += pex * VLO(A.x);  acc[1]  += pex * VHI(A.x);
    acc[2]  += pex * VLO(A.y);  acc[3]  += pex * VHI(A.y);
    acc[4]  += pex * VLO(A.z);  acc[5]  += pex * VHI(A.z);
    acc[6]  += pex * VLO(A.w);  acc[7]  += pex * VHI(A.w);
    acc[8]  += pex * VLO(Bv.x); acc[9]  += pex * VHI(Bv.x);
    acc[10] += pex * VLO(Bv.y); acc[11] += pex * VHI(Bv.y);
    acc[12] += pex * VLO(Bv.z); acc[13] += pex * VHI(Bv.z);
    acc[14] += pex * VLO(Bv.w); acc[15] += pex * VHI(Bv.w);
    if (!any_next) break;
    A = nA; Bv = nB;
    idx = nidx;
  }
  l += __shfl_xor(l, 4); l += __shfl_xor(l, 8); l += __shfl_xor(l, 16);
  float* rw = &red[slot][lane & 31][0];
#pragma unroll
  for (int i = 0; i < 16; ++i) rw[i] = acc[i];
  int r32 = lane & 31;
  int h0 = r32 >> 4, i0 = r32 & 15;
  float l0 = __shfl(l, (lane & 32) + h0);
  float l1 = __shfl(l, (lane & 32) + h0 + 2);
  float s0 = 0.f, s1 = 0.f;
#pragma unroll
  for (int ep = 0; ep < 8; ++ep) {
    s0 += red[slot][ep * 4 + h0][i0];
    s1 += red[slot][ep * 4 + h0 + 2][i0];
  }
  bool nonempty = end > beg;
  float a0 = nonempty ? s0 / l0 : 0.f;
  float a1 = nonempty ? s1 / l1 : 0.f;
  size_t o0 = (size_t)dst * 64 + r32;
  tmpb[o0] = f2bf(a0 + bf2f(us_sk[o0]));
  tmpb[o0 + 32] = f2bf(a1 + bf2f(us_sk[o0 + 32]));
}

// Fused: x = LN(f_h + tmpb @ Wo + bo) -> f_h; qt,kt,vt = x @ W* + b* (bf16)
__global__ void __launch_bounds__(256)
k_mlqkvt(const unsigned short* __restrict__ in1, const unsigned short* __restrict__ wt,
         const float* __restrict__ bias, const float* __restrict__ gam,
         const float* __restrict__ bet, float* __restrict__ io,
         const float* __restrict__ bqt, const float* __restrict__ bkt,
         const float* __restrict__ bvt,
         unsigned short* __restrict__ qt, unsigned short* __restrict__ kt,
         unsigned short* __restrict__ vt) {
  __shared__ unsigned short A[64 * 72];
  __shared__ unsigned short B[3 * 64 * 72];
  int tid = threadIdx.x;
  int n0 = blockIdx.x * 64;
  stage_bf(in1 + (size_t)n0 * 64, A, 64 * 8, 64, 72, tid);
  stage_bf(wt + 0, B, 64 * 8, 64, 72, tid);       // Wo
  __syncthreads();
  int lane = tid & 63, w = tid >> 6;
  int c = lane & 15, g = lane >> 4;
  f32x4 acc[4];
#pragma unroll
  for (int j = 0; j < 4; ++j) { acc[j][0] = 0.f; acc[j][1] = 0.f; acc[j][2] = 0.f; acc[j][3] = 0.f; }
  const unsigned short* xrow = A + (w * 16 + c) * 72 + g * 8;
#pragma unroll
  for (int kk = 0; kk < 2; ++kk) {
    bf16x8 af = *(const bf16x8*)(xrow + kk * 32);
#pragma unroll
    for (int j = 0; j < 4; ++j)
      acc[j] = __builtin_amdgcn_mfma_f32_16x16x32_bf16(af,
                 *(const bf16x8*)(B + (j * 16 + c) * 72 + kk * 32 + g * 8), acc[j], 0, 0, 0);
  }
  int rowb = n0 + w * 16 + 4 * g;
  float o[4][4];
#pragma unroll
  for (int j = 0; j < 4; ++j) {
    int col = j * 16 + c;
    float bb = bias[col];
#pragma unroll
    for (int r = 0; r < 4; ++r)
      o[j][r] = acc[j][r] + bb + io[(size_t)(rowb + r) * 64 + col];
  }
#pragma unroll
  for (int r = 0; r < 4; ++r) {
    float s = (o[0][r] + o[1][r]) + (o[2][r] + o[3][r]);
    float s2 = (o[0][r] * o[0][r] + o[1][r] * o[1][r]) + (o[2][r] * o[2][r] + o[3][r] * o[3][r]);
#pragma unroll
    for (int off = 1; off <= 8; off <<= 1) {
      s += __shfl_xor(s, off);
      s2 += __shfl_xor(s2, off);
    }
    float mean = s * (1.0f / 64.0f);
    float var = s2 * (1.0f / 64.0f) - mean * mean;
    float rs = rsqrtf(var + EPSLN);
#pragma unroll
    for (int j = 0; j < 4; ++j)
      o[j][r] = (o[j][r] - mean) * rs * gam[j * 16 + c] + bet[j * 16 + c];
  }
  __syncthreads();
#pragma unroll
  for (int j = 0; j < 4; ++j) {
    int col = j * 16 + c;
#pragma unroll
    for (int r = 0; r < 4; ++r) {
      io[(size_t)(rowb + r) * 64 + col] = o[j][r];
      A[(w * 16 + 4 * g + r) * 72 + col] = f2bf(o[j][r]);
    }
  }
  stage_bf(wt + 8192, B, 64 * 8, 64, 72, tid);
  stage_bf(wt + 12288, B + 4608, 64 * 8, 64, 72, tid);
  stage_bf(wt + 16384, B + 9216, 64 * 8, 64, 72, tid);
  __syncthreads();
  f32x4 aq[4], ak[4], av[4];
#pragma unroll
  for (int j = 0; j < 4; ++j) {
#pragma unroll
    for (int r = 0; r < 4; ++r) { aq[j][r] = 0.f; ak[j][r] = 0.f; av[j][r] = 0.f; }
  }
#pragma unroll
  for (int kk = 0; kk < 2; ++kk) {
    bf16x8 af = *(const bf16x8*)(xrow + kk * 32);
#pragma unroll
    for (int j = 0; j < 4; ++j) {
      int boff = (j * 16 + c) * 72 + kk * 32 + g * 8;
      aq[j] = __builtin_amdgcn_mfma_f32_16x16x32_bf16(af, *(const bf16x8*)(B + boff), aq[j], 0, 0, 0);
      ak[j] = __builtin_amdgcn_mfma_f32_16x16x32_bf16(af, *(const bf16x8*)(B + 4608 + boff), ak[j], 0, 0, 0);
      av[j] = __builtin_amdgcn_mfma_f32_16x16x32_bf16(af, *(const bf16x8*)(B + 9216 + boff), av[j], 0, 0, 0);
    }
  }
#pragma unroll
  for (int j = 0; j < 4; ++j) {
    int col = j * 16 + c;
    float bqj = bqt[col], bkj = bkt[col], bvj = bvt[col];
#pragma unroll
    for (int r = 0; r < 4; ++r) {
      size_t oo = (size_t)(rowb + r) * 64 + col;
      qt[oo] = f2bf(aq[j][r] + bqj);
      kt[oo] = f2bf(ak[j][r] + bkj);
      vt[oo] = f2bf(av[j][r] + bvj);
    }
  }
}

// K8: temporal attention via MFMA (bf16 out)
#define VST 20
#define PST 40
__global__ void __launch_bounds__(256)
k_tattn(const unsigned short* __restrict__ qtb, const unsigned short* __restrict__ ktb,
        const unsigned short* __restrict__ vtb, unsigned short* __restrict__ attnb) {
  int b = blockIdx.x >> 2, hh = blockIdx.x & 3;
  __shared__ unsigned short Qs[NFRM][16];
  __shared__ unsigned short Ks[NFRM][16];
  __shared__ unsigned short Vs[NFRM][VST];
  __shared__ unsigned short Ps[4][16][PST];
  int t = threadIdx.x;
  int wv = t >> 6, lane = t & 63;
  int g = lane >> 4, c = lane & 15;
  {
    size_t src = ((size_t)b * NFRM + t) * DD + hh * 16;
    const uint4* qsrc = (const uint4*)(qtb + src);
    const uint4* ksrc = (const uint4*)(ktb + src);
    const uint2* vsrc = (const uint2*)(vtb + src);
    ((uint4*)Qs[t])[0] = qsrc[0]; ((uint4*)Qs[t])[1] = qsrc[1];
    ((uint4*)Ks[t])[0] = ksrc[0]; ((uint4*)Ks[t])[1] = ksrc[1];
    uint2* vdst = (uint2*)Vs[t];
    vdst[0] = vsrc[0]; vdst[1] = vsrc[1]; vdst[2] = vsrc[2]; vdst[3] = vsrc[3];
  }
  __syncthreads();
  const bf16x8 zf = {0, 0, 0, 0, 0, 0, 0, 0};
  unsigned short (*P)[PST] = Ps[wv];
  for (int qt0 = wv; qt0 < 16; qt0 += 4) {
    bf16x8 qf = zf;
    if (g < 2) qf = *(const bf16x8*)&Qs[qt0 * 16 + c][g * 8];
    f32x4 O = {0.f, 0.f, 0.f, 0.f};
    float lacc[4] = {0.f, 0.f, 0.f, 0.f};
    for (int jp = 0; jp < 8; ++jp) {
#pragma unroll
      for (int half = 0; half < 2; ++half) {
        int jt = jp * 2 + half;
        bf16x8 kf = zf;
        if (g < 2) kf = *(const bf16x8*)&Ks[jt * 16 + c][g * 8];
        f32x4 S = __builtin_amdgcn_mfma_f32_16x16x32_bf16(qf, kf,
                    (f32x4){0.f, 0.f, 0.f, 0.f}, 0, 0, 0);
#pragma unroll
        for (int r = 0; r < 4; ++r) {
          float p = __expf(S[r] * SCL);
          lacc[r] += p;
          P[4 * g + r][half * 16 + c] = f2bf(p);
        }
      }
      bf16x8 pf = *(const bf16x8*)&P[c][g * 8];
      bf16x8 vf;
#pragma unroll
      for (int i = 0; i < 8; ++i) vf[i] = (short)Vs[jp * 32 + g * 8 + i][c];
      O = __builtin_amdgcn_mfma_f32_16x16x32_bf16(pf, vf, O, 0, 0, 0);
    }
#pragma unroll
    for (int r = 0; r < 4; ++r) {
      float s = lacc[r];
      s += __shfl_xor(s, 1); s += __shfl_xor(s, 2);
      s += __shfl_xor(s, 4); s += __shfl_xor(s, 8);
      lacc[r] = 1.0f / s;
    }
    size_t obase = ((size_t)b * NFRM + qt0 * 16) * DD + hh * 16;
#pragma unroll
    for (int r = 0; r < 4; ++r)
      attnb[obase + (size_t)(4 * g + r) * DD + c] = f2bf(O[r] * lacc[r]);
  }
}

// Fused block2: x = LN1(f_h + attn @ Wot + bot); u = relu(x@W1+b1);
// xtb = LN2(x + u@W2 + b2)  (bf16 out)
__global__ void __launch_bounds__(256)
k_blk2(const unsigned short* __restrict__ attn, const unsigned short* __restrict__ wt,
       const float* __restrict__ res, const float* __restrict__ bot,
       const float* __restrict__ l1g, const float* __restrict__ l1b,
       const float* __restrict__ b1, const float* __restrict__ b2,
       const float* __restrict__ l2g, const float* __restrict__ l2b,
       unsigned short* __restrict__ xtb) {
  __shared__ unsigned short XLs[64 * 72];
  __shared__ unsigned short BufW[128 * 72];
  __shared__ unsigned short BufX[64 * 136];
  int tid = threadIdx.x;
  int n0 = blockIdx.x * 64;
  int lane = tid & 63, w = tid >> 6;
  int c = lane & 15, g = lane >> 4;
  int rowb = n0 + w * 16 + 4 * g;
  stage_bf(attn + (size_t)n0 * 64, BufX, 64 * 8, 64, 72, tid);
  stage_bf(wt + 4096, BufW, 64 * 8, 64, 72, tid);
  __syncthreads();
  f32x4 acc[4];
#pragma unroll
  for (int j = 0; j < 4; ++j) { acc[j][0] = 0.f; acc[j][1] = 0.f; acc[j][2] = 0.f; acc[j][3] = 0.f; }
  const unsigned short* xrow = BufX + (w * 16 + c) * 72 + g * 8;
#pragma unroll
  for (int kk = 0; kk < 2; ++kk) {
    bf16x8 af = *(const bf16x8*)(xrow + kk * 32);
#pragma unroll
    for (int j = 0; j < 4; ++j)
      acc[j] = __builtin_amdgcn_mfma_f32_16x16x32_bf16(af,
                 *(const bf16x8*)(BufW + (j * 16 + c) * 72 + kk * 32 + g * 8), acc[j], 0, 0, 0);
  }
  float x[4][4];
#pragma unroll
  for (int j = 0; j < 4; ++j) {
    int col = j * 16 + c;
    float bb = bot[col];
#pragma unroll
    for (int r = 0; r < 4; ++r)
      x[j][r] = acc[j][r] + bb + res[(size_t)(rowb + r) * 64 + col];
  }
#pragma unroll
  for (int r = 0; r < 4; ++r) {
    float s = (x[0][r] + x[1][r]) + (x[2][r] + x[3][r]);
    float s2 = (x[0][r] * x[0][r] + x[1][r] * x[1][r]) + (x[2][r] * x[2][r] + x[3][r] * x[3][r]);
#pragma unroll
    for (int off = 1; off <= 8; off <<= 1) {
      s += __shfl_xor(s, off);
      s2 += __shfl_xor(s2, off);
    }
    float mean = s * (1.0f / 64.0f);
    float var = s2 * (1.0f / 64.0f) - mean * mean;
    float rs = rsqrtf(var + EPSLN);
#pragma unroll
    for (int j = 0; j < 4; ++j)
      x[j][r] = (x[j][r] - mean) * rs * l1g[j * 16 + c] + l1b[j * 16 + c];
  }
  __syncthreads();
#pragma unroll
  for (int j = 0; j < 4; ++j)
#pragma unroll
    for (int r = 0; r < 4; ++r)
      XLs[(w * 16 + 4 * g + r) * 72 + j * 16 + c] = f2bf(x[j][r]);
  stage_bf(wt + 20480, BufW, 128 * 8, 64, 72, tid);
  __syncthreads();
  f32x4 ua[8];
#pragma unroll
  for (int j = 0; j < 8; ++j) { ua[j][0] = 0.f; ua[j][1] = 0.f; ua[j][2] = 0.f; ua[j][3] = 0.f; }
  const unsigned short* xrow2 = XLs + (w * 16 + c) * 72 + g * 8;
#pragma unroll
  for (int kk = 0; kk < 2; ++kk) {
    bf16x8 af = *(const bf16x8*)(xrow2 + kk * 32);
#pragma unroll
    for (int j = 0; j < 8; ++j)
      ua[j] = __builtin_amdgcn_mfma_f32_16x16x32_bf16(af,
                *(const bf16x8*)(BufW + (j * 16 + c) * 72 + kk * 32 + g * 8), ua[j], 0, 0, 0);
  }
#pragma unroll
  for (int j = 0; j < 8; ++j) {
    int col = j * 16 + c;
    float bb = b1[col];
#pragma unroll
    for (int r = 0; r < 4; ++r)
      BufX[(w * 16 + 4 * g + r) * 136 + col] = f2bf(fmaxf(ua[j][r] + bb, 0.f));
  }
  __syncthreads();
  stage_bf(wt + 28672, BufW, 64 * 16, 128, 136, tid);
  __syncthreads();
  f32x4 ya[4];
#pragma unroll
  for (int j = 0; j < 4; ++j) { ya[j][0] = 0.f; ya[j][1] = 0.f; ya[j][2] = 0.f; ya[j][3] = 0.f; }
  const unsigned short* urow = BufX + (w * 16 + c) * 136 + g * 8;
#pragma unroll
  for (int kk = 0; kk < 4; ++kk) {
    bf16x8 af = *(const bf16x8*)(urow + kk * 32);
#pragma unroll
    for (int j = 0; j < 4; ++j)
      ya[j] = __builtin_amdgcn_mfma_f32_16x16x32_bf16(af,
                *(const bf16x8*)(BufW + (j * 16 + c) * 136 + kk * 32 + g * 8), ya[j], 0, 0, 0);
  }
  float o2[4][4];
#pragma unroll
  for (int j = 0; j < 4; ++j) {
    int col = j * 16 + c;
    float bb = b2[col];
#pragma unroll
    for (int r = 0; r < 4; ++r)
      o2[j][r] = ya[j][r] + bb + x[j][r];
  }
#pragma unroll
  for (int r = 0; r < 4; ++r) {
    float s = (o2[0][r] + o2[1][r]) + (o2[2][r] + o2[3][r]);
    float s2 = (o2[0][r] * o2[0][r] + o2[1][r] * o2[1][r]) + (o2[2][r] * o2[2][r] + o2[3][r] * o2[3][r]);
#pragma unroll
    for (int off = 1; off <= 8; off <<= 1) {
      s += __shfl_xor(s, off);
      s2 += __shfl_xor(s2, off);
    }
    float mean = s * (1.0f / 64.0f);
    float var = s2 * (1.0f / 64.0f) - mean * mean;
    float rs = rsqrtf(var + EPSLN);
#pragma unroll
    for (int j = 0; j < 4; ++j)
      xtb[(size_t)(rowb + r) * 64 + j * 16 + c] =
          f2bf((o2[j][r] - mean) * rs * l2g[j * 16 + c] + l2b[j * 16 + c]);
  }
}

// agg1 GEMM via MFMA
__global__ void __launch_bounds__(256)
k_agg1a_m(const unsigned short* __restrict__ xtb, const unsigned short* __restrict__ wa1t,
          float* __restrict__ part) {
  int ks = blockIdx.x >> 2, mt = blockIdx.x & 3;
  int t = threadIdx.x, lane = t & 63, w = t >> 6;
  int c = lane & 15, g = lane >> 4;
  int m0 = mt * 64;
  int k0 = ks * 512;
  f32x4 acc[4];
#pragma unroll
  for (int j = 0; j < 4; ++j) { acc[j][0] = 0.f; acc[j][1] = 0.f; acc[j][2] = 0.f; acc[j][3] = 0.f; }
  const unsigned short* arow = xtb + (size_t)(m0 + w * 16 + c) * 16384 + k0 + g * 8;
  const unsigned short* brow = wa1t + (size_t)c * 16384 + k0 + g * 8;
#pragma unroll 4
  for (int kk = 0; kk < 16; ++kk) {
    bf16x8 af = *(const bf16x8*)(arow + kk * 32);
#pragma unroll
    for (int j = 0; j < 4; ++j)
      acc[j] = __builtin_amdgcn_mfma_f32_16x16x32_bf16(af,
                 *(const bf16x8*)(brow + (size_t)j * 16 * 16384 + kk * 32), acc[j], 0, 0, 0);
  }
  int rowb = m0 + w * 16 + 4 * g;
#pragma unroll
  for (int j = 0; j < 4; ++j)
#pragma unroll
    for (int r = 0; r < 4; ++r)
      part[(size_t)ks * (BSZ * DD) + (size_t)(rowb + r) * 64 + j * 16 + c] = acc[j][r];
}

// K13: head MLP (+ fused partial reduce)
__global__ void k_head(const float* __restrict__ part, const float* __restrict__ ba1,
                       const float* __restrict__ Wa2, const float* __restrict__ ba2,
                       const float* __restrict__ Wh1, const float* __restrict__ bh1,
                       const float* __restrict__ Wh2, const float* __restrict__ bh2,
                       float* __restrict__ out) {
  int b = blockIdx.x, t = threadIdx.x;
  __shared__ float s1[64], s2[32], s3[16];
  float a0 = ba1[t];
#pragma unroll 8
  for (int ks = 0; ks < AKS; ++ks) a0 += part[(size_t)ks * (BSZ * DD) + b * 64 + t];
  s1[t] = fmaxf(a0, 0.f);
  __syncthreads();
  if (t < 32) {
    float a = ba2[t];
#pragma unroll 8
    for (int j = 0; j < 64; ++j) a += s1[j] * Wa2[j * 32 + t];
    s2[t] = fmaxf(a, 0.f);
  }
  __syncthreads();
  if (t < 16) {
    float a = bh1[t];
#pragma unroll
    for (int j = 0; j < 32; ++j) a += s2[j] * Wh1[j * 16 + t];
    s3[t] = fmaxf(a, 0.f);
  }
  __syncthreads();
  if (t == 0) {
    float a = bh2[0];
#pragma unroll
    for (int j = 0; j < 16; ++j) a += s3[j] * Wh2[j];
    out[b] = 1.0f / (1.0f + expf(-a));
  }
}

extern "C" void kernel_launch(void* const* d_in, const int* in_sizes, int n_in,
                              void* d_out, int out_size, void* d_ws, size_t ws_size,
                              hipStream_t stream) {
  const float* x   = (const float*)d_in[0];
  const int*   ei  = (const int*)d_in[1];
  const float* Wi  = (const float*)d_in[2];
  const float* bi  = (const float*)d_in[3];
  const float* pe  = (const float*)d_in[4];
  const float* Wq  = (const float*)d_in[5];
  const float* Wk  = (const float*)d_in[6];
  const float* Wv  = (const float*)d_in[7];
  const float* bq  = (const float*)d_in[8];
  const float* bk  = (const float*)d_in[9];
  const float* bv  = (const float*)d_in[10];
  const float* Ws  = (const float*)d_in[11];
  const float* bs  = (const float*)d_in[12];
  const float* Wo  = (const float*)d_in[13];
  const float* bo  = (const float*)d_in[14];
  const float* gg  = (const float*)d_in[15];
  const float* gb  = (const float*)d_in[16];
  const float* Wqt = (const float*)d_in[17];
  const float* Wkt = (const float*)d_in[18];
  const float* Wvt = (const float*)d_in[19];
  const float* bqt = (const float*)d_in[20];
  const float* bkt = (const float*)d_in[21];
  const float* bvt = (const float*)d_in[22];
  const float* Wot = (const float*)d_in[23];
  const float* bot = (const float*)d_in[24];
  const float* l1g = (const float*)d_in[25];
  const float* l1b = (const float*)d_in[26];
  const float* W1  = (const float*)d_in[27];
  const float* b1  = (const float*)d_in[28];
  const float* W2  = (const float*)d_in[29];
  const float* b2  = (const float*)d_in[30];
  const float* l2g = (const float*)d_in[31];
  const float* l2b = (const float*)d_in[32];
  const float* Wa1 = (const float*)d_in[33];
  const float* ba1 = (const float*)d_in[34];
  const float* Wa2 = (const float*)d_in[35];
  const float* ba2 = (const float*)d_in[36];
  const float* Wh1 = (const float*)d_in[37];
  const float* bh1 = (const float*)d_in[38];
  const float* Wh2 = (const float*)d_in[39];
  const float* bh2 = (const float*)d_in[40];
  float* out = (float*)d_out;

  const size_t ND = (size_t)NN * DD;

  float* wsf = (float*)d_ws;
  float* f_h = wsf;                                        // 16MB residual
  unsigned short* us_q  = (unsigned short*)(f_h + ND);     // 8MB
  unsigned short* kv8   = us_q + ND;                       // 8MB
  unsigned short* us_sk = kv8 + ND;                        // 8MB
  unsigned short* tmpb  = us_sk + ND;                      // 8MB
  unsigned short* us_qt = tmpb + ND;                       // 8MB
  unsigned short* us_kt = us_qt + ND;                      // 8MB
  unsigned short* us_vt = us_kt + ND;                      // 8MB
  unsigned short* attnb = us_vt + ND;                      // 8MB
  unsigned short* xtb   = attnb + ND;                      // 8MB
  float* f_part = (float*)(xtb + ND);                      // 2MB
  int* i_srcs   = (int*)(f_part + (size_t)AKS * BSZ * DD);
  int* i_rowptr = i_srcs + NE;
  int* i_hist   = i_rowptr + NN + 1;
  int* i_btot   = i_hist + 65536;
  int* i_bbase  = i_btot + 256;
  int* i_pairs  = i_bbase + 256;
  unsigned short* wt = (unsigned short*)(i_pairs + NE);    // 53248 us
  unsigned short* wa1t = wt + 53248;                       // 2MB

  dim3 B(256);
  k_wprep<<<dim3(208), B, 0, stream>>>(Wo, Wot, Wqt, Wkt, Wvt, W1, W2, Wq, Wk, Wv, Ws, wt);
  k_wprep2<<<dim3(256), B, 0, stream>>>(Wa1, wa1t);
  k_qkvs_m<<<dim3(NN / 64), B, 0, stream>>>(x, Wi, bi, pe, wt, bq, bk, bv, bs,
                                            f_h, us_q, kv8, us_sk);
  k_hist <<<dim3(256), B, 0, stream>>>(ei, i_hist);
  k_hscan<<<dim3(256), B, 0, stream>>>(i_hist, i_btot);
  k_bscan<<<dim3(1),   B, 0, stream>>>(i_btot, i_bbase);
  k_passB<<<dim3(256), B, 0, stream>>>(ei, i_hist, i_bbase, i_pairs);
  k_passC<<<dim3(256), B, 0, stream>>>(i_pairs, i_bbase, i_btot, i_rowptr, i_srcs);
  k_gattn<<<dim3(NN / 8), B, 0, stream>>>(us_q, kv8, i_rowptr, i_srcs, us_sk, tmpb);
  k_mlqkvt<<<dim3(NN / 64), B, 0, stream>>>(tmpb, wt, bo, gg, gb, f_h,
                                            bqt, bkt, bvt, us_qt, us_kt, us_vt);
  k_tattn<<<dim3(BSZ * HH), B, 0, stream>>>(us_qt, us_kt, us_vt, attnb);
  k_blk2<<<dim3(NN / 64), B, 0, stream>>>(attnb, wt, f_h, bot, l1g, l1b, b1, b2,
                                          l2g, l2b, xtb);
  k_agg1a_m<<<dim3(AKS * 4), B, 0, stream>>>(xtb, wa1t, f_part);
  k_head<<<dim3(BSZ), dim3(64), 0, stream>>>(f_part, ba1, Wa2, ba2, Wh1, bh1, Wh2, bh2, out);
}

// Round 13
// 178.728 us; speedup vs baseline: 1.5379x; 1.0252x over previous
//
#include <hip/hip_runtime.h>
#include <hip/hip_fp16.h>
#include <math.h>

#define NN 65536
#define SIN 24
#define DD 64
#define HH 4
#define HDIM 16
#define NFRM 256
#define NE 1048576
#define BSZ 256
#define EPSLN 1e-5f
#define SCL 0.25f
#define AKS 32   // K-splits for agg1 MFMA GEMM
#define WTN 55296

typedef __attribute__((ext_vector_type(8))) short bf16x8;
typedef __attribute__((ext_vector_type(4))) float f32x4;

__device__ __forceinline__ unsigned short f2bf(float f) {
  unsigned u = __float_as_uint(f);
  return (unsigned short)((u + 0x7FFFu + ((u >> 16) & 1u)) >> 16);
}
__device__ __forceinline__ float bf2f(unsigned short b) {
  return __uint_as_float(((unsigned)b) << 16);
}
__device__ __forceinline__ float bflo(unsigned u) {
  return __uint_as_float(u << 16);
}
__device__ __forceinline__ float bfhi(unsigned u) {
  return __uint_as_float(u & 0xFFFF0000u);
}
// fp32 -> e5m2 byte (fp16 high byte, round-to-nearest)
__device__ __forceinline__ unsigned f2e5(float f) {
  unsigned short h = __half_as_ushort(__float2half(f));
  unsigned r = (unsigned)h + 0x7Fu + ((h >> 8) & 1u);
  return (r >> 8) & 0xFFu;
}
__device__ __forceinline__ float h2fb(unsigned short b) {
  return __half2float(__ushort_as_half(b));
}
#define KLO(u) h2fb((unsigned short)((u) & 0xFF00u))
#define KHI(u) h2fb((unsigned short)(((u) >> 16) & 0xFF00u))
#define VLO(u) h2fb((unsigned short)(((u) << 8) & 0xFF00u))
#define VHI(u) h2fb((unsigned short)(((u) >> 8) & 0xFF00u))

// stage bf16 [rows][DK] -> LDS [rows][ST]
__device__ __forceinline__ void stage_bf(const unsigned short* __restrict__ src,
                                         unsigned short* dst, int n8, int DK, int ST, int tid) {
  int dk8 = DK >> 3;
  for (int idx = tid; idx < n8; idx += 256) {
    int row = idx / dk8, c = (idx % dk8) * 8;
    *(uint4*)(dst + row * ST + c) = *(const uint4*)(src + (size_t)row * DK + c);
  }
}

// Weight prep: all dense weights -> bf16 Wt[Nout][Dk]; + Wi^T padded K=32
__global__ void k_wprep(const float* __restrict__ Wo, const float* __restrict__ Wot,
                        const float* __restrict__ Wqt, const float* __restrict__ Wkt,
                        const float* __restrict__ Wvt, const float* __restrict__ W1,
                        const float* __restrict__ W2, const float* __restrict__ Wq,
                        const float* __restrict__ Wk, const float* __restrict__ Wv,
                        const float* __restrict__ Wsk, const float* __restrict__ Wi,
                        unsigned short* __restrict__ wt) {
  int i = blockIdx.x * 256 + threadIdx.x;
  if (i >= WTN) return;
  float v;
  if (i < 4096)       { int t = i;         int j = t >> 6, d = t & 63; v = Wo[d * 64 + j]; }
  else if (i < 8192)  { int t = i - 4096;  int j = t >> 6, d = t & 63; v = Wot[d * 64 + j]; }
  else if (i < 12288) { int t = i - 8192;  int j = t >> 6, d = t & 63; v = Wqt[d * 64 + j]; }
  else if (i < 16384) { int t = i - 12288; int j = t >> 6, d = t & 63; v = Wkt[d * 64 + j]; }
  else if (i < 20480) { int t = i - 16384; int j = t >> 6, d = t & 63; v = Wvt[d * 64 + j]; }
  else if (i < 28672) { int t = i - 20480; int j = t >> 6, d = t & 63; v = W1[d * 128 + j]; }
  else if (i < 36864) { int t = i - 28672; int j = t >> 7, d = t & 127; v = W2[d * 64 + j]; }
  else if (i < 40960) { int t = i - 36864; int j = t >> 6, d = t & 63; v = Wq[(j >> 4) * 1024 + d * 16 + (j & 15)]; }
  else if (i < 45056) { int t = i - 40960; int j = t >> 6, d = t & 63; v = Wk[(j >> 4) * 1024 + d * 16 + (j & 15)]; }
  else if (i < 49152) { int t = i - 45056; int j = t >> 6, d = t & 63; v = Wv[(j >> 4) * 1024 + d * 16 + (j & 15)]; }
  else if (i < 53248) { int t = i - 49152; int j = t >> 6, d = t & 63; v = Wsk[(j >> 4) * 1024 + d * 16 + (j & 15)]; }
  else                { int t = i - 53248; int j = t >> 5, k = t & 31; v = (k < SIN) ? Wi[k * 64 + j] : 0.f; }
  wt[i] = f2bf(v);
}

// Wa1 [16384][64] fp32 -> wa1t [64][16384] bf16
__global__ void k_wprep2(const float* __restrict__ Wa1, unsigned short* __restrict__ wa1t) {
  __shared__ float tile[64][65];
  int kb = blockIdx.x;
  int t = threadIdx.x;
  int c = t & 63, r0 = t >> 6;
  int k0 = kb * 64;
#pragma unroll
  for (int i = 0; i < 16; ++i) {
    int r = r0 + i * 4;
    tile[r][c] = Wa1[(size_t)(k0 + r) * 64 + c];
  }
  __syncthreads();
#pragma unroll
  for (int i = 0; i < 16; ++i) {
    int o = r0 + i * 4;
    wa1t[(size_t)o * 16384 + k0 + c] = f2bf(tile[c][o]);
  }
}

// Fused input + qkvs (all-MFMA): h = x@Wi + bi + pe (K=32 padded MFMA) -> us_h bf16;
// then q bf16, kv8 (e5m2 packed k|v), sk bf16.
__global__ void __launch_bounds__(256)
k_qkvs_m(const float* __restrict__ x, const unsigned short* __restrict__ wt,
         const float* __restrict__ bi, const float* __restrict__ pe,
         const float* __restrict__ bq, const float* __restrict__ bk,
         const float* __restrict__ bv, const float* __restrict__ bs,
         unsigned short* __restrict__ us_h, unsigned short* __restrict__ us_q,
         unsigned short* __restrict__ kv8, unsigned short* __restrict__ us_sk) {
  __shared__ unsigned short Xs[64 * 72];
  __shared__ unsigned short Ws4[4 * 64 * 72];
  unsigned short* Xi  = Ws4;            // [64][40] (phase 0 only)
  unsigned short* WiS = Ws4 + 64 * 40;  // [64][40]
  int tid = threadIdx.x;
  int n0 = blockIdx.x * 64;
  // phase 0a: stage x (bf16, K padded to 32) + Wi^T
  for (int idx = tid; idx < 2048; idx += 256) {
    int row = idx >> 5, k = idx & 31;
    Xi[row * 40 + k] = (k < SIN) ? f2bf(x[(size_t)(n0 + row) * SIN + k]) : 0;
    WiS[row * 40 + k] = wt[53248 + row * 32 + k];
  }
  __syncthreads();
  int lane = tid & 63, w = tid >> 6;
  int c = lane & 15, g = lane >> 4;
  int rowb = n0 + w * 16 + 4 * g;
  // phase 0b: h = x @ Wi via single K=32 MFMA per j-tile
  f32x4 hb[4];
  {
    bf16x8 xf = *(const bf16x8*)(Xi + (w * 16 + c) * 40 + g * 8);
#pragma unroll
    for (int jj = 0; jj < 4; ++jj)
      hb[jj] = __builtin_amdgcn_mfma_f32_16x16x32_bf16(xf,
                 *(const bf16x8*)(WiS + (jj * 16 + c) * 40 + g * 8),
                 (f32x4){0.f, 0.f, 0.f, 0.f}, 0, 0, 0);
  }
  // epilogue: + bi + pe; write us_h (residual) + Xs (bf16 h for phase 1)
#pragma unroll
  for (int jj = 0; jj < 4; ++jj) {
    int col = jj * 16 + c;
    float bb = bi[col];
#pragma unroll
    for (int r = 0; r < 4; ++r) {
      int row = w * 16 + 4 * g + r;
      float hv = hb[jj][r] + bb + pe[((n0 + row) & (NFRM - 1)) * DD + col];
      unsigned short hbf = f2bf(hv);
      us_h[(size_t)(n0 + row) * DD + col] = hbf;
      Xs[row * 72 + col] = hbf;
    }
  }
  __syncthreads();   // all MFMA reads of Xi/WiS done; Xs complete
  stage_bf(wt + 36864, Ws4, 64 * 8, 64, 72, tid);
  stage_bf(wt + 40960, Ws4 + 4608, 64 * 8, 64, 72, tid);
  stage_bf(wt + 45056, Ws4 + 9216, 64 * 8, 64, 72, tid);
  stage_bf(wt + 49152, Ws4 + 13824, 64 * 8, 64, 72, tid);
  __syncthreads();
  // phase 1: q/k/v/sk MFMA projections
  f32x4 aq[4], ak[4], av[4], as_[4];
#pragma unroll
  for (int jj = 0; jj < 4; ++jj) {
#pragma unroll
    for (int r = 0; r < 4; ++r) { aq[jj][r] = 0.f; ak[jj][r] = 0.f; av[jj][r] = 0.f; as_[jj][r] = 0.f; }
  }
  const unsigned short* xrow = Xs + (w * 16 + c) * 72 + g * 8;
#pragma unroll
  for (int kk = 0; kk < 2; ++kk) {
    bf16x8 af = *(const bf16x8*)(xrow + kk * 32);
#pragma unroll
    for (int jj = 0; jj < 4; ++jj) {
      int boff = (jj * 16 + c) * 72 + kk * 32 + g * 8;
      aq[jj] = __builtin_amdgcn_mfma_f32_16x16x32_bf16(af, *(const bf16x8*)(Ws4 + boff), aq[jj], 0, 0, 0);
      ak[jj] = __builtin_amdgcn_mfma_f32_16x16x32_bf16(af, *(const bf16x8*)(Ws4 + 4608 + boff), ak[jj], 0, 0, 0);
      av[jj] = __builtin_amdgcn_mfma_f32_16x16x32_bf16(af, *(const bf16x8*)(Ws4 + 9216 + boff), av[jj], 0, 0, 0);
      as_[jj] = __builtin_amdgcn_mfma_f32_16x16x32_bf16(af, *(const bf16x8*)(Ws4 + 13824 + boff), as_[jj], 0, 0, 0);
    }
  }
#pragma unroll
  for (int jj = 0; jj < 4; ++jj) {
    int col = jj * 16 + c;
    float bqj = bq[col], bkj = bk[col], bvj = bv[col], bsj = bs[col];
#pragma unroll
    for (int r = 0; r < 4; ++r) {
      size_t o = (size_t)(rowb + r) * 64 + col;
      us_q[o] = f2bf(aq[jj][r] + bqj);
      kv8[o] = (unsigned short)((f2e5(ak[jj][r] + bkj) << 8) | f2e5(av[jj][r] + bvj));
      us_sk[o] = f2bf(as_[jj][r] + bsj);
    }
  }
}

// ---- Bucketed CSR build ----
__global__ void k_hist(const int* __restrict__ ei, int* __restrict__ hist) {
  __shared__ int h2[2][256];
  int t = threadIdx.x;
  h2[0][t] = 0; h2[1][t] = 0;
  __syncthreads();
  int sub = (t >> 6) & 1;
  int base = blockIdx.x * 4096;
#pragma unroll
  for (int r = 0; r < 16; ++r)
    atomicAdd(&h2[sub][ei[NE + base + r * 256 + t] >> 8], 1);
  __syncthreads();
  hist[t * 256 + blockIdx.x] = h2[0][t] + h2[1][t];
}

__global__ void k_hscan(int* __restrict__ hist, int* __restrict__ btot) {
  __shared__ int s[256];
  int t = threadIdx.x, bkt = blockIdx.x;
  int v = hist[bkt * 256 + t];
  s[t] = v; __syncthreads();
  for (int off = 1; off < 256; off <<= 1) {
    int x = (t >= off) ? s[t - off] : 0;
    __syncthreads();
    s[t] += x;
    __syncthreads();
  }
  hist[bkt * 256 + t] = s[t] - v;
  if (t == 255) btot[bkt] = s[255];
}

__global__ void k_bscan(const int* __restrict__ btot, int* __restrict__ bbase) {
  __shared__ int s[256];
  int t = threadIdx.x;
  int v = btot[t];
  s[t] = v; __syncthreads();
  for (int off = 1; off < 256; off <<= 1) {
    int x = (t >= off) ? s[t - off] : 0;
    __syncthreads();
    s[t] += x;
    __syncthreads();
  }
  bbase[t] = s[t] - v;
}

__global__ void k_passB(const int* __restrict__ ei, const int* __restrict__ hist,
                        const int* __restrict__ bbase, int* __restrict__ pairs) {
  __shared__ int cur[256];
  int t = threadIdx.x;
  cur[t] = bbase[t] + hist[t * 256 + blockIdx.x];
  __syncthreads();
  int base = blockIdx.x * 4096;
#pragma unroll
  for (int r = 0; r < 16; ++r) {
    int e = base + r * 256 + t;
    int src = ei[e], dst = ei[NE + e];
    int pos = atomicAdd(&cur[dst >> 8], 1);
    pairs[pos] = ((dst & 255) << 16) | src;
  }
}

__global__ void k_passC(const int* __restrict__ pairs, const int* __restrict__ bbase,
                        const int* __restrict__ btot, int* __restrict__ rowptr,
                        int* __restrict__ srcs) {
  __shared__ int cnt[256];
  __shared__ int s[256];
  int t = threadIdx.x, bkt = blockIdx.x;
  cnt[t] = 0;
  __syncthreads();
  int base = bbase[bkt], n = btot[bkt];
  int pr[18];
#pragma unroll
  for (int j = 0; j < 18; ++j) {
    int i = t + j * 256;
    if (i >= n) break;
    int p = pairs[base + i];
    pr[j] = p;
    atomicAdd(&cnt[p >> 16], 1);
  }
  for (int i = t + 18 * 256; i < n; i += 256)
    atomicAdd(&cnt[pairs[base + i] >> 16], 1);
  __syncthreads();
  int v = cnt[t];
  s[t] = v; __syncthreads();
  for (int off = 1; off < 256; off <<= 1) {
    int x = (t >= off) ? s[t - off] : 0;
    __syncthreads();
    s[t] += x;
    __syncthreads();
  }
  int rp = base + s[t] - v;
  rowptr[bkt * 256 + t] = rp;
  if (bkt == 0 && t == 0) rowptr[NN] = NE;
  __syncthreads();
  cnt[t] = rp;
  __syncthreads();
#pragma unroll
  for (int j = 0; j < 18; ++j) {
    int i = t + j * 256;
    if (i >= n) break;
    int p = pr[j];
    int pos = atomicAdd(&cnt[p >> 16], 1);
    srcs[pos] = p & 0xFFFF;
  }
  for (int i = t + 18 * 256; i < n; i += 256) {
    int p = pairs[base + i];
    int pos = atomicAdd(&cnt[p >> 16], 1);
    srcs[pos] = p & 0xFFFF;
  }
}

// Graph attention v5: half-wave per dst, e5m2 kv8 gather, bf16 q/sk/out.
__global__ void __launch_bounds__(256)
k_gattn(const unsigned short* __restrict__ us_q, const unsigned short* __restrict__ kv8,
        const int* __restrict__ rowptr, const int* __restrict__ srcs,
        const unsigned short* __restrict__ us_sk, unsigned short* __restrict__ tmpb) {
  __shared__ float red[8][32][17];
  int tid = threadIdx.x;
  int lane = tid & 63;
  int slot = (tid >> 5) & 7;
  int e = (lane >> 2) & 7, h = lane & 3;
  int dst = (blockIdx.x << 3) + slot;
  float qv[16];
  {
    const uint4* qp = (const uint4*)(us_q + (size_t)dst * 64 + h * 16);
    uint4 q0 = qp[0], q1 = qp[1];
    qv[0] = bflo(q0.x); qv[1] = bfhi(q0.x); qv[2] = bflo(q0.y); qv[3] = bfhi(q0.y);
    qv[4] = bflo(q0.z); qv[5] = bfhi(q0.z); qv[6] = bflo(q0.w); qv[7] = bfhi(q0.w);
    qv[8] = bflo(q1.x); qv[9] = bfhi(q1.x); qv[10] = bflo(q1.y); qv[11] = bfhi(q1.y);
    qv[12] = bflo(q1.z); qv[13] = bfhi(q1.z); qv[14] = bflo(q1.w); qv[15] = bfhi(q1.w);
  }
  int beg = rowptr[dst], end = rowptr[dst + 1];
  float l = 0.f;
  float acc[16];
#pragma unroll
  for (int i = 0; i < 16; ++i) acc[i] = 0.f;

  int idx = beg + e;
  int src = (idx < end) ? srcs[idx] : 0;
  const uint4* kp = (const uint4*)(kv8 + (size_t)src * 64 + h * 16);
  uint4 A = kp[0], Bv = kp[1];
  for (;;) {
    int nidx = idx + 8;
    bool any_next = __any(nidx < end);
    uint4 nA, nB;
    if (any_next) {
      int nsrc = (nidx < end) ? srcs[nidx] : 0;
      const uint4* np = (const uint4*)(kv8 + (size_t)nsrc * 64 + h * 16);
      nA = np[0]; nB = np[1];
    }
    bool valid = idx < end;
    float s;
    s  = KLO(A.x) * qv[0]   + KHI(A.x) * qv[1]   + KLO(A.y) * qv[2]   + KHI(A.y) * qv[3];
    s += KLO(A.z) * qv[4]   + KHI(A.z) * qv[5]   + KLO(A.w) * qv[6]   + KHI(A.w) * qv[7];
    s += KLO(Bv.x) * qv[8]  + KHI(Bv.x) * qv[9]  + KLO(Bv.y) * qv[10] + KHI(Bv.y) * qv[11];
    s += KLO(Bv.z) * qv[12] + KHI(Bv.z) * qv[13] + KLO(Bv.w) * qv[14] + KHI(Bv.w) * qv[15];
    float pex = valid ? __expf(s * SCL) : 0.f;
    l += pex;
    acc[0]  += pex * VLO(A.x);  acc[1]  += pex * VHI(A.x);
    acc[2]  += pex * VLO(A.y);  acc[3]  += pex * VHI(A.y);
    acc[4]  += pex * VLO(A.z);  acc[5]  += pex * VHI(A.z);
    acc[6]  += pex * VLO(A.w);  acc[7]  += pex * VHI(A.w);
    acc[8]  += pex * VLO(Bv.x); acc[9]  += pex * VHI(Bv.x);
    acc[10] += pex * VLO(Bv.y); acc[11] += pex * VHI(Bv.y);
    acc[12] += pex * VLO(Bv.z); acc[13] += pex * VHI(Bv.z);
    acc[14] += pex * VLO(Bv.w); acc[15] += pex * VHI(Bv.w);
    if (!any_next) break;
    A = nA; Bv = nB;
    idx = nidx;
  }
  l += __shfl_xor(l, 4); l += __shfl_xor(l, 8); l += __shfl_xor(l, 16);
  float* rw = &red[slot][lane & 31][0];
#pragma unroll
  for (int i = 0; i < 16; ++i) rw[i] = acc[i];
  int r32 = lane & 31;
  int h0 = r32 >> 4, i0 = r32 & 15;
  float l0 = __shfl(l, (lane & 32) + h0);
  float l1 = __shfl(l, (lane & 32) + h0 + 2);
  float s0 = 0.f, s1 = 0.f;
#pragma unroll
  for (int ep = 0; ep < 8; ++ep) {
    s0 += red[slot][ep * 4 + h0][i0];
    s1 += red[slot][ep * 4 + h0 + 2][i0];
  }
  bool nonempty = end > beg;
  float a0 = nonempty ? s0 / l0 : 0.f;
  float a1 = nonempty ? s1 / l1 : 0.f;
  size_t o0 = (size_t)dst * 64 + r32;
  tmpb[o0] = f2bf(a0 + bf2f(us_sk[o0]));
  tmpb[o0 + 32] = f2bf(a1 + bf2f(us_sk[o0 + 32]));
}

// Fused: x = LN(us_h + tmpb @ Wo + bo) -> us_h (bf16); qt,kt,vt = x @ W* + b*
__global__ void __launch_bounds__(256)
k_mlqkvt(const unsigned short* __restrict__ in1, const unsigned short* __restrict__ wt,
         const float* __restrict__ bias, const float* __restrict__ gam,
         const float* __restrict__ bet, unsigned short* __restrict__ us_h,
         const float* __restrict__ bqt, const float* __restrict__ bkt,
         const float* __restrict__ bvt,
         unsigned short* __restrict__ qt, unsigned short* __restrict__ kt,
         unsigned short* __restrict__ vt) {
  __shared__ unsigned short A[64 * 72];
  __shared__ unsigned short B[3 * 64 * 72];
  int tid = threadIdx.x;
  int n0 = blockIdx.x * 64;
  stage_bf(in1 + (size_t)n0 * 64, A, 64 * 8, 64, 72, tid);
  stage_bf(wt + 0, B, 64 * 8, 64, 72, tid);       // Wo
  __syncthreads();
  int lane = tid & 63, w = tid >> 6;
  int c = lane & 15, g = lane >> 4;
  f32x4 acc[4];
#pragma unroll
  for (int j = 0; j < 4; ++j) { acc[j][0] = 0.f; acc[j][1] = 0.f; acc[j][2] = 0.f; acc[j][3] = 0.f; }
  const unsigned short* xrow = A + (w * 16 + c) * 72 + g * 8;
#pragma unroll
  for (int kk = 0; kk < 2; ++kk) {
    bf16x8 af = *(const bf16x8*)(xrow + kk * 32);
#pragma unroll
    for (int j = 0; j < 4; ++j)
      acc[j] = __builtin_amdgcn_mfma_f32_16x16x32_bf16(af,
                 *(const bf16x8*)(B + (j * 16 + c) * 72 + kk * 32 + g * 8), acc[j], 0, 0, 0);
  }
  int rowb = n0 + w * 16 + 4 * g;
  float o[4][4];
#pragma unroll
  for (int j = 0; j < 4; ++j) {
    int col = j * 16 + c;
    float bb = bias[col];
#pragma unroll
    for (int r = 0; r < 4; ++r)
      o[j][r] = acc[j][r] + bb + bf2f(us_h[(size_t)(rowb + r) * 64 + col]);
  }
#pragma unroll
  for (int r = 0; r < 4; ++r) {
    float s = (o[0][r] + o[1][r]) + (o[2][r] + o[3][r]);
    float s2 = (o[0][r] * o[0][r] + o[1][r] * o[1][r]) + (o[2][r] * o[2][r] + o[3][r] * o[3][r]);
#pragma unroll
    for (int off = 1; off <= 8; off <<= 1) {
      s += __shfl_xor(s, off);
      s2 += __shfl_xor(s2, off);
    }
    float mean = s * (1.0f / 64.0f);
    float var = s2 * (1.0f / 64.0f) - mean * mean;
    float rs = rsqrtf(var + EPSLN);
#pragma unroll
    for (int j = 0; j < 4; ++j)
      o[j][r] = (o[j][r] - mean) * rs * gam[j * 16 + c] + bet[j * 16 + c];
  }
  __syncthreads();
#pragma unroll
  for (int j = 0; j < 4; ++j) {
    int col = j * 16 + c;
#pragma unroll
    for (int r = 0; r < 4; ++r) {
      unsigned short ob = f2bf(o[j][r]);
      us_h[(size_t)(rowb + r) * 64 + col] = ob;
      A[(w * 16 + 4 * g + r) * 72 + col] = ob;
    }
  }
  stage_bf(wt + 8192, B, 64 * 8, 64, 72, tid);
  stage_bf(wt + 12288, B + 4608, 64 * 8, 64, 72, tid);
  stage_bf(wt + 16384, B + 9216, 64 * 8, 64, 72, tid);
  __syncthreads();
  f32x4 aq[4], ak[4], av[4];
#pragma unroll
  for (int j = 0; j < 4; ++j) {
#pragma unroll
    for (int r = 0; r < 4; ++r) { aq[j][r] = 0.f; ak[j][r] = 0.f; av[j][r] = 0.f; }
  }
#pragma unroll
  for (int kk = 0; kk < 2; ++kk) {
    bf16x8 af = *(const bf16x8*)(xrow + kk * 32);
#pragma unroll
    for (int j = 0; j < 4; ++j) {
      int boff = (j * 16 + c) * 72 + kk * 32 + g * 8;
      aq[j] = __builtin_amdgcn_mfma_f32_16x16x32_bf16(af, *(const bf16x8*)(B + boff), aq[j], 0, 0, 0);
      ak[j] = __builtin_amdgcn_mfma_f32_16x16x32_bf16(af, *(const bf16x8*)(B + 4608 + boff), ak[j], 0, 0, 0);
      av[j] = __builtin_amdgcn_mfma_f32_16x16x32_bf16(af, *(const bf16x8*)(B + 9216 + boff), av[j], 0, 0, 0);
    }
  }
#pragma unroll
  for (int j = 0; j < 4; ++j) {
    int col = j * 16 + c;
    float bqj = bqt[col], bkj = bkt[col], bvj = bvt[col];
#pragma unroll
    for (int r = 0; r < 4; ++r) {
      size_t oo = (size_t)(rowb + r) * 64 + col;
      qt[oo] = f2bf(aq[j][r] + bqj);
      kt[oo] = f2bf(ak[j][r] + bkj);
      vt[oo] = f2bf(av[j][r] + bvj);
    }
  }
}

// K8: temporal attention via MFMA (bf16 out)
#define VST 20
#define PST 40
__global__ void __launch_bounds__(256)
k_tattn(const unsigned short* __restrict__ qtb, const unsigned short* __restrict__ ktb,
        const unsigned short* __restrict__ vtb, unsigned short* __restrict__ attnb) {
  int b = blockIdx.x >> 2, hh = blockIdx.x & 3;
  __shared__ unsigned short Qs[NFRM][16];
  __shared__ unsigned short Ks[NFRM][16];
  __shared__ unsigned short Vs[NFRM][VST];
  __shared__ unsigned short Ps[4][16][PST];
  int t = threadIdx.x;
  int wv = t >> 6, lane = t & 63;
  int g = lane >> 4, c = lane & 15;
  {
    size_t src = ((size_t)b * NFRM + t) * DD + hh * 16;
    const uint4* qsrc = (const uint4*)(qtb + src);
    const uint4* ksrc = (const uint4*)(ktb + src);
    const uint2* vsrc = (const uint2*)(vtb + src);
    ((uint4*)Qs[t])[0] = qsrc[0]; ((uint4*)Qs[t])[1] = qsrc[1];
    ((uint4*)Ks[t])[0] = ksrc[0]; ((uint4*)Ks[t])[1] = ksrc[1];
    uint2* vdst = (uint2*)Vs[t];
    vdst[0] = vsrc[0]; vdst[1] = vsrc[1]; vdst[2] = vsrc[2]; vdst[3] = vsrc[3];
  }
  __syncthreads();
  const bf16x8 zf = {0, 0, 0, 0, 0, 0, 0, 0};
  unsigned short (*P)[PST] = Ps[wv];
  for (int qt0 = wv; qt0 < 16; qt0 += 4) {
    bf16x8 qf = zf;
    if (g < 2) qf = *(const bf16x8*)&Qs[qt0 * 16 + c][g * 8];
    f32x4 O = {0.f, 0.f, 0.f, 0.f};
    float lacc[4] = {0.f, 0.f, 0.f, 0.f};
    for (int jp = 0; jp < 8; ++jp) {
#pragma unroll
      for (int half = 0; half < 2; ++half) {
        int jt = jp * 2 + half;
        bf16x8 kf = zf;
        if (g < 2) kf = *(const bf16x8*)&Ks[jt * 16 + c][g * 8];
        f32x4 S = __builtin_amdgcn_mfma_f32_16x16x32_bf16(qf, kf,
                    (f32x4){0.f, 0.f, 0.f, 0.f}, 0, 0, 0);
#pragma unroll
        for (int r = 0; r < 4; ++r) {
          float p = __expf(S[r] * SCL);
          lacc[r] += p;
          P[4 * g + r][half * 16 + c] = f2bf(p);
        }
      }
      bf16x8 pf = *(const bf16x8*)&P[c][g * 8];
      bf16x8 vf;
#pragma unroll
      for (int i = 0; i < 8; ++i) vf[i] = (short)Vs[jp * 32 + g * 8 + i][c];
      O = __builtin_amdgcn_mfma_f32_16x16x32_bf16(pf, vf, O, 0, 0, 0);
    }
#pragma unroll
    for (int r = 0; r < 4; ++r) {
      float s = lacc[r];
      s += __shfl_xor(s, 1); s += __shfl_xor(s, 2);
      s += __shfl_xor(s, 4); s += __shfl_xor(s, 8);
      lacc[r] = 1.0f / s;
    }
    size_t obase = ((size_t)b * NFRM + qt0 * 16) * DD + hh * 16;
#pragma unroll
    for (int r = 0; r < 4; ++r)
      attnb[obase + (size_t)(4 * g + r) * DD + c] = f2bf(O[r] * lacc[r]);
  }
}

// Fused block2: x = LN1(us_h + attn @ Wot + bot); u = relu(x@W1+b1);
// xtb = LN2(x + u@W2 + b2)  (bf16 out)
__global__ void __launch_bounds__(256)
k_blk2(const unsigned short* __restrict__ attn, const unsigned short* __restrict__ wt,
       const unsigned short* __restrict__ res, const float* __restrict__ bot,
       const float* __restrict__ l1g, const float* __restrict__ l1b,
       const float* __restrict__ b1, const float* __restrict__ b2,
       const float* __restrict__ l2g, const float* __restrict__ l2b,
       unsigned short* __restrict__ xtb) {
  __shared__ unsigned short XLs[64 * 72];
  __shared__ unsigned short BufW[128 * 72];
  __shared__ unsigned short BufX[64 * 136];
  int tid = threadIdx.x;
  int n0 = blockIdx.x * 64;
  int lane = tid & 63, w = tid >> 6;
  int c = lane & 15, g = lane >> 4;
  int rowb = n0 + w * 16 + 4 * g;
  stage_bf(attn + (size_t)n0 * 64, BufX, 64 * 8, 64, 72, tid);
  stage_bf(wt + 4096, BufW, 64 * 8, 64, 72, tid);
  __syncthreads();
  f32x4 acc[4];
#pragma unroll
  for (int j = 0; j < 4; ++j) { acc[j][0] = 0.f; acc[j][1] = 0.f; acc[j][2] = 0.f; acc[j][3] = 0.f; }
  const unsigned short* xrow = BufX + (w * 16 + c) * 72 + g * 8;
#pragma unroll
  for (int kk = 0; kk < 2; ++kk) {
    bf16x8 af = *(const bf16x8*)(xrow + kk * 32);
#pragma unroll
    for (int j = 0; j < 4; ++j)
      acc[j] = __builtin_amdgcn_mfma_f32_16x16x32_bf16(af,
                 *(const bf16x8*)(BufW + (j * 16 + c) * 72 + kk * 32 + g * 8), acc[j], 0, 0, 0);
  }
  float x[4][4];
#pragma unroll
  for (int j = 0; j < 4; ++j) {
    int col = j * 16 + c;
    float bb = bot[col];
#pragma unroll
    for (int r = 0; r < 4; ++r)
      x[j][r] = acc[j][r] + bb + bf2f(res[(size_t)(rowb + r) * 64 + col]);
  }
#pragma unroll
  for (int r = 0; r < 4; ++r) {
    float s = (x[0][r] + x[1][r]) + (x[2][r] + x[3][r]);
    float s2 = (x[0][r] * x[0][r] + x[1][r] * x[1][r]) + (x[2][r] * x[2][r] + x[3][r] * x[3][r]);
#pragma unroll
    for (int off = 1; off <= 8; off <<= 1) {
      s += __shfl_xor(s, off);
      s2 += __shfl_xor(s2, off);
    }
    float mean = s * (1.0f / 64.0f);
    float var = s2 * (1.0f / 64.0f) - mean * mean;
    float rs = rsqrtf(var + EPSLN);
#pragma unroll
    for (int j = 0; j < 4; ++j)
      x[j][r] = (x[j][r] - mean) * rs * l1g[j * 16 + c] + l1b[j * 16 + c];
  }
  __syncthreads();
#pragma unroll
  for (int j = 0; j < 4; ++j)
#pragma unroll
    for (int r = 0; r < 4; ++r)
      XLs[(w * 16 + 4 * g + r) * 72 + j * 16 + c] = f2bf(x[j][r]);
  stage_bf(wt + 20480, BufW, 128 * 8, 64, 72, tid);
  __syncthreads();
  f32x4 ua[8];
#pragma unroll
  for (int j = 0; j < 8; ++j) { ua[j][0] = 0.f; ua[j][1] = 0.f; ua[j][2] = 0.f; ua[j][3] = 0.f; }
  const unsigned short* xrow2 = XLs + (w * 16 + c) * 72 + g * 8;
#pragma unroll
  for (int kk = 0; kk < 2; ++kk) {
    bf16x8 af = *(const bf16x8*)(xrow2 + kk * 32);
#pragma unroll
    for (int j = 0; j < 8; ++j)
      ua[j] = __builtin_amdgcn_mfma_f32_16x16x32_bf16(af,
                *(const bf16x8*)(BufW + (j * 16 + c) * 72 + kk * 32 + g * 8), ua[j], 0, 0, 0);
  }
#pragma unroll
  for (int j = 0; j < 8; ++j) {
    int col = j * 16 + c;
    float bb = b1[col];
#pragma unroll
    for (int r = 0; r < 4; ++r)
      BufX[(w * 16 + 4 * g + r) * 136 + col] = f2bf(fmaxf(ua[j][r] + bb, 0.f));
  }
  __syncthreads();
  stage_bf(wt + 28672, BufW, 64 * 16, 128, 136, tid);
  __syncthreads();
  f32x4 ya[4];
#pragma unroll
  for (int j = 0; j < 4; ++j) { ya[j][0] = 0.f; ya[j][1] = 0.f; ya[j][2] = 0.f; ya[j][3] = 0.f; }
  const unsigned short* urow = BufX + (w * 16 + c) * 136 + g * 8;
#pragma unroll
  for (int kk = 0; kk < 4; ++kk) {
    bf16x8 af = *(const bf16x8*)(urow + kk * 32);
#pragma unroll
    for (int j = 0; j < 4; ++j)
      ya[j] = __builtin_amdgcn_mfma_f32_16x16x32_bf16(af,
                *(const bf16x8*)(BufW + (j * 16 + c) * 136 + kk * 32 + g * 8), ya[j], 0, 0, 0);
  }
  float o2[4][4];
#pragma unroll
  for (int j = 0; j < 4; ++j) {
    int col = j * 16 + c;
    float bb = b2[col];
#pragma unroll
    for (int r = 0; r < 4; ++r)
      o2[j][r] = ya[j][r] + bb + x[j][r];
  }
#pragma unroll
  for (int r = 0; r < 4; ++r) {
    float s = (o2[0][r] + o2[1][r]) + (o2[2][r] + o2[3][r]);
    float s2 = (o2[0][r] * o2[0][r] + o2[1][r] * o2[1][r]) + (o2[2][r] * o2[2][r] + o2[3][r] * o2[3][r]);
#pragma unroll
    for (int off = 1; off <= 8; off <<= 1) {
      s += __shfl_xor(s, off);
      s2 += __shfl_xor(s2, off);
    }
    float mean = s * (1.0f / 64.0f);
    float var = s2 * (1.0f / 64.0f) - mean * mean;
    float rs = rsqrtf(var + EPSLN);
#pragma unroll
    for (int j = 0; j < 4; ++j)
      xtb[(size_t)(rowb + r) * 64 + j * 16 + c] =
          f2bf((o2[j][r] - mean) * rs * l2g[j * 16 + c] + l2b[j * 16 + c]);
  }
}

// agg1 GEMM via MFMA
__global__ void __launch_bounds__(256)
k_agg1a_m(const unsigned short* __restrict__ xtb, const unsigned short* __restrict__ wa1t,
          float* __restrict__ part) {
  int ks = blockIdx.x >> 2, mt = blockIdx.x & 3;
  int t = threadIdx.x, lane = t & 63, w = t >> 6;
  int c = lane & 15, g = lane >> 4;
  int m0 = mt * 64;
  int k0 = ks * 512;
  f32x4 acc[4];
#pragma unroll
  for (int j = 0; j < 4; ++j) { acc[j][0] = 0.f; acc[j][1] = 0.f; acc[j][2] = 0.f; acc[j][3] = 0.f; }
  const unsigned short* arow = xtb + (size_t)(m0 + w * 16 + c) * 16384 + k0 + g * 8;
  const unsigned short* brow = wa1t + (size_t)c * 16384 + k0 + g * 8;
#pragma unroll 4
  for (int kk = 0; kk < 16; ++kk) {
    bf16x8 af = *(const bf16x8*)(arow + kk * 32);
#pragma unroll
    for (int j = 0; j < 4; ++j)
      acc[j] = __builtin_amdgcn_mfma_f32_16x16x32_bf16(af,
                 *(const bf16x8*)(brow + (size_t)j * 16 * 16384 + kk * 32), acc[j], 0, 0, 0);
  }
  int rowb = m0 + w * 16 + 4 * g;
#pragma unroll
  for (int j = 0; j < 4; ++j)
#pragma unroll
    for (int r = 0; r < 4; ++r)
      part[(size_t)ks * (BSZ * DD) + (size_t)(rowb + r) * 64 + j * 16 + c] = acc[j][r];
}

// K13: head MLP (+ fused partial reduce)
__global__ void k_head(const float* __restrict__ part, const float* __restrict__ ba1,
                       const float* __restrict__ Wa2, const float* __restrict__ ba2,
                       const float* __restrict__ Wh1, const float* __restrict__ bh1,
                       const float* __restrict__ Wh2, const float* __restrict__ bh2,
                       float* __restrict__ out) {
  int b = blockIdx.x, t = threadIdx.x;
  __shared__ float s1[64], s2[32], s3[16];
  float a0 = ba1[t];
#pragma unroll 8
  for (int ks = 0; ks < AKS; ++ks) a0 += part[(size_t)ks * (BSZ * DD) + b * 64 + t];
  s1[t] = fmaxf(a0, 0.f);
  __syncthreads();
  if (t < 32) {
    float a = ba2[t];
#pragma unroll 8
    for (int j = 0; j < 64; ++j) a += s1[j] * Wa2[j * 32 + t];
    s2[t] = fmaxf(a, 0.f);
  }
  __syncthreads();
  if (t < 16) {
    float a = bh1[t];
#pragma unroll
    for (int j = 0; j < 32; ++j) a += s2[j] * Wh1[j * 16 + t];
    s3[t] = fmaxf(a, 0.f);
  }
  __syncthreads();
  if (t == 0) {
    float a = bh2[0];
#pragma unroll
    for (int j = 0; j < 16; ++j) a += s3[j] * Wh2[j];
    out[b] = 1.0f / (1.0f + expf(-a));
  }
}

extern "C" void kernel_launch(void* const* d_in, const int* in_sizes, int n_in,
                              void* d_out, int out_size, void* d_ws, size_t ws_size,
                              hipStream_t stream) {
  const float* x   = (const float*)d_in[0];
  const int*   ei  = (const int*)d_in[1];
  const float* Wi  = (const float*)d_in[2];
  const float* bi  = (const float*)d_in[3];
  const float* pe  = (const float*)d_in[4];
  const float* Wq  = (const float*)d_in[5];
  const float* Wk  = (const float*)d_in[6];
  const float* Wv  = (const float*)d_in[7];
  const float* bq  = (const float*)d_in[8];
  const float* bk  = (const float*)d_in[9];
  const float* bv  = (const float*)d_in[10];
  const float* Ws  = (const float*)d_in[11];
  const float* bs  = (const float*)d_in[12];
  const float* Wo  = (const float*)d_in[13];
  const float* bo  = (const float*)d_in[14];
  const float* gg  = (const float*)d_in[15];
  const float* gb  = (const float*)d_in[16];
  const float* Wqt = (const float*)d_in[17];
  const float* Wkt = (const float*)d_in[18];
  const float* Wvt = (const float*)d_in[19];
  const float* bqt = (const float*)d_in[20];
  const float* bkt = (const float*)d_in[21];
  const float* bvt = (const float*)d_in[22];
  const float* Wot = (const float*)d_in[23];
  const float* bot = (const float*)d_in[24];
  const float* l1g = (const float*)d_in[25];
  const float* l1b = (const float*)d_in[26];
  const float* W1  = (const float*)d_in[27];
  const float* b1  = (const float*)d_in[28];
  const float* W2  = (const float*)d_in[29];
  const float* b2  = (const float*)d_in[30];
  const float* l2g = (const float*)d_in[31];
  const float* l2b = (const float*)d_in[32];
  const float* Wa1 = (const float*)d_in[33];
  const float* ba1 = (const float*)d_in[34];
  const float* Wa2 = (const float*)d_in[35];
  const float* ba2 = (const float*)d_in[36];
  const float* Wh1 = (const float*)d_in[37];
  const float* bh1 = (const float*)d_in[38];
  const float* Wh2 = (const float*)d_in[39];
  const float* bh2 = (const float*)d_in[40];
  float* out = (float*)d_out;

  const size_t ND = (size_t)NN * DD;

  unsigned short* us_h  = (unsigned short*)d_ws;          // 8MB residual (bf16)
  unsigned short* us_q  = us_h + ND;
  unsigned short* kv8   = us_q + ND;
  unsigned short* us_sk = kv8 + ND;
  unsigned short* tmpb  = us_sk + ND;
  unsigned short* us_qt = tmpb + ND;
  unsigned short* us_kt = us_qt + ND;
  unsigned short* us_vt = us_kt + ND;
  unsigned short* attnb = us_vt + ND;
  unsigned short* xtb   = attnb + ND;
  float* f_part = (float*)(xtb + ND);
  int* i_srcs   = (int*)(f_part + (size_t)AKS * BSZ * DD);
  int* i_rowptr = i_srcs + NE;
  int* i_hist   = i_rowptr + NN + 4;   // +4 keeps 16B alignment downstream
  int* i_btot   = i_hist + 65536;
  int* i_bbase  = i_btot + 256;
  int* i_pairs  = i_bbase + 256;
  unsigned short* wt = (unsigned short*)(i_pairs + NE);   // WTN ushorts
  unsigned short* wa1t = wt + WTN;

  dim3 B(256);
  k_wprep<<<dim3((WTN + 255) / 256), B, 0, stream>>>(Wo, Wot, Wqt, Wkt, Wvt, W1, W2,
                                                     Wq, Wk, Wv, Ws, Wi, wt);
  k_wprep2<<<dim3(256), B, 0, stream>>>(Wa1, wa1t);
  k_qkvs_m<<<dim3(NN / 64), B, 0, stream>>>(x, wt, bi, pe, bq, bk, bv, bs,
                                            us_h, us_q, kv8, us_sk);
  k_hist <<<dim3(256), B, 0, stream>>>(ei, i_hist);
  k_hscan<<<dim3(256), B, 0, stream>>>(i_hist, i_btot);
  k_bscan<<<dim3(1),   B, 0, stream>>>(i_btot, i_bbase);
  k_passB<<<dim3(256), B, 0, stream>>>(ei, i_hist, i_bbase, i_pairs);
  k_passC<<<dim3(256), B, 0, stream>>>(i_pairs, i_bbase, i_btot, i_rowptr, i_srcs);
  k_gattn<<<dim3(NN / 8), B, 0, stream>>>(us_q, kv8, i_rowptr, i_srcs, us_sk, tmpb);
  k_mlqkvt<<<dim3(NN / 64), B, 0, stream>>>(tmpb, wt, bo, gg, gb, us_h,
                                            bqt, bkt, bvt, us_qt, us_kt, us_vt);
  k_tattn<<<dim3(BSZ * HH), B, 0, stream>>>(us_qt, us_kt, us_vt, attnb);
  k_blk2<<<dim3(NN / 64), B, 0, stream>>>(attnb, wt, us_h, bot, l1g, l1b, b1, b2,
                                          l2g, l2b, xtb);
  k_agg1a_m<<<dim3(AKS * 4), B, 0, stream>>>(xtb, wa1t, f_part);
  k_head<<<dim3(BSZ), dim3(64), 0, stream>>>(f_part, ba1, Wa2, ba2, Wh1, bh1, Wh2, bh2, out);
}

// Round 14
// 170.833 us; speedup vs baseline: 1.6090x; 1.0462x over previous
//
#include <hip/hip_runtime.h>
#include <hip/hip_fp16.h>
#include <math.h>

#define NN 65536
#define SIN 24
#define DD 64
#define HH 4
#define HDIM 16
#define NFRM 256
#define NE 1048576
#define BSZ 256
#define EPSLN 1e-5f
#define SCL 0.25f
#define AKS 32
#define WTN 55296

typedef __attribute__((ext_vector_type(8))) short bf16x8;
typedef __attribute__((ext_vector_type(4))) float f32x4;

__device__ __forceinline__ unsigned short f2bf(float f) {
  unsigned u = __float_as_uint(f);
  return (unsigned short)((u + 0x7FFFu + ((u >> 16) & 1u)) >> 16);
}
__device__ __forceinline__ float bf2f(unsigned short b) {
  return __uint_as_float(((unsigned)b) << 16);
}
__device__ __forceinline__ float bflo(unsigned u) {
  return __uint_as_float(u << 16);
}
__device__ __forceinline__ float bfhi(unsigned u) {
  return __uint_as_float(u & 0xFFFF0000u);
}
__device__ __forceinline__ unsigned f2e5(float f) {
  unsigned short h = __half_as_ushort(__float2half(f));
  unsigned r = (unsigned)h + 0x7Fu + ((h >> 8) & 1u);
  return (r >> 8) & 0xFFu;
}
__device__ __forceinline__ float h2fb(unsigned short b) {
  return __half2float(__ushort_as_half(b));
}
#define KLO(u) h2fb((unsigned short)((u) & 0xFF00u))
#define KHI(u) h2fb((unsigned short)(((u) >> 16) & 0xFF00u))
#define VLO(u) h2fb((unsigned short)(((u) << 8) & 0xFF00u))
#define VHI(u) h2fb((unsigned short)(((u) >> 8) & 0xFF00u))

__device__ __forceinline__ void stage_bf(const unsigned short* __restrict__ src,
                                         unsigned short* dst, int n8, int DK, int ST, int tid) {
  int dk8 = DK >> 3;
  for (int idx = tid; idx < n8; idx += 256) {
    int row = idx / dk8, c = (idx % dk8) * 8;
    *(uint4*)(dst + row * ST + c) = *(const uint4*)(src + (size_t)row * DK + c);
  }
}

// Weight prep
__global__ void k_wprep(const float* __restrict__ Wo, const float* __restrict__ Wot,
                        const float* __restrict__ Wqt, const float* __restrict__ Wkt,
                        const float* __restrict__ Wvt, const float* __restrict__ W1,
                        const float* __restrict__ W2, const float* __restrict__ Wq,
                        const float* __restrict__ Wk, const float* __restrict__ Wv,
                        const float* __restrict__ Wsk, const float* __restrict__ Wi,
                        unsigned short* __restrict__ wt) {
  int i = blockIdx.x * 256 + threadIdx.x;
  if (i >= WTN) return;
  float v;
  if (i < 4096)       { int t = i;         int j = t >> 6, d = t & 63; v = Wo[d * 64 + j]; }
  else if (i < 8192)  { int t = i - 4096;  int j = t >> 6, d = t & 63; v = Wot[d * 64 + j]; }
  else if (i < 12288) { int t = i - 8192;  int j = t >> 6, d = t & 63; v = Wqt[d * 64 + j]; }
  else if (i < 16384) { int t = i - 12288; int j = t >> 6, d = t & 63; v = Wkt[d * 64 + j]; }
  else if (i < 20480) { int t = i - 16384; int j = t >> 6, d = t & 63; v = Wvt[d * 64 + j]; }
  else if (i < 28672) { int t = i - 20480; int j = t >> 6, d = t & 63; v = W1[d * 128 + j]; }
  else if (i < 36864) { int t = i - 28672; int j = t >> 7, d = t & 127; v = W2[d * 64 + j]; }
  else if (i < 40960) { int t = i - 36864; int j = t >> 6, d = t & 63; v = Wq[(j >> 4) * 1024 + d * 16 + (j & 15)]; }
  else if (i < 45056) { int t = i - 40960; int j = t >> 6, d = t & 63; v = Wk[(j >> 4) * 1024 + d * 16 + (j & 15)]; }
  else if (i < 49152) { int t = i - 45056; int j = t >> 6, d = t & 63; v = Wv[(j >> 4) * 1024 + d * 16 + (j & 15)]; }
  else if (i < 53248) { int t = i - 49152; int j = t >> 6, d = t & 63; v = Wsk[(j >> 4) * 1024 + d * 16 + (j & 15)]; }
  else                { int t = i - 53248; int j = t >> 5, k = t & 31; v = (k < SIN) ? Wi[k * 64 + j] : 0.f; }
  wt[i] = f2bf(v);
}

__global__ void k_wprep2(const float* __restrict__ Wa1, unsigned short* __restrict__ wa1t) {
  __shared__ float tile[64][65];
  int kb = blockIdx.x;
  int t = threadIdx.x;
  int c = t & 63, r0 = t >> 6;
  int k0 = kb * 64;
#pragma unroll
  for (int i = 0; i < 16; ++i) {
    int r = r0 + i * 4;
    tile[r][c] = Wa1[(size_t)(k0 + r) * 64 + c];
  }
  __syncthreads();
#pragma unroll
  for (int i = 0; i < 16; ++i) {
    int o = r0 + i * 4;
    wa1t[(size_t)o * 16384 + k0 + c] = f2bf(tile[c][o]);
  }
}

// Fused input + qkvs (all-MFMA)
__global__ void __launch_bounds__(256)
k_qkvs_m(const float* __restrict__ x, const unsigned short* __restrict__ wt,
         const float* __restrict__ bi, const float* __restrict__ pe,
         const float* __restrict__ bq, const float* __restrict__ bk,
         const float* __restrict__ bv, const float* __restrict__ bs,
         unsigned short* __restrict__ us_h, unsigned short* __restrict__ us_q,
         unsigned short* __restrict__ kv8, unsigned short* __restrict__ us_sk) {
  __shared__ unsigned short Xs[64 * 72];
  __shared__ unsigned short Ws4[4 * 64 * 72];
  unsigned short* Xi  = Ws4;
  unsigned short* WiS = Ws4 + 64 * 40;
  int tid = threadIdx.x;
  int n0 = blockIdx.x * 64;
  for (int idx = tid; idx < 2048; idx += 256) {
    int row = idx >> 5, k = idx & 31;
    Xi[row * 40 + k] = (k < SIN) ? f2bf(x[(size_t)(n0 + row) * SIN + k]) : 0;
    WiS[row * 40 + k] = wt[53248 + row * 32 + k];
  }
  __syncthreads();
  int lane = tid & 63, w = tid >> 6;
  int c = lane & 15, g = lane >> 4;
  int rowb = n0 + w * 16 + 4 * g;
  f32x4 hb[4];
  {
    bf16x8 xf = *(const bf16x8*)(Xi + (w * 16 + c) * 40 + g * 8);
#pragma unroll
    for (int jj = 0; jj < 4; ++jj)
      hb[jj] = __builtin_amdgcn_mfma_f32_16x16x32_bf16(xf,
                 *(const bf16x8*)(WiS + (jj * 16 + c) * 40 + g * 8),
                 (f32x4){0.f, 0.f, 0.f, 0.f}, 0, 0, 0);
  }
#pragma unroll
  for (int jj = 0; jj < 4; ++jj) {
    int col = jj * 16 + c;
    float bb = bi[col];
#pragma unroll
    for (int r = 0; r < 4; ++r) {
      int row = w * 16 + 4 * g + r;
      float hv = hb[jj][r] + bb + pe[((n0 + row) & (NFRM - 1)) * DD + col];
      unsigned short hbf = f2bf(hv);
      us_h[(size_t)(n0 + row) * DD + col] = hbf;
      Xs[row * 72 + col] = hbf;
    }
  }
  __syncthreads();
  stage_bf(wt + 36864, Ws4, 64 * 8, 64, 72, tid);
  stage_bf(wt + 40960, Ws4 + 4608, 64 * 8, 64, 72, tid);
  stage_bf(wt + 45056, Ws4 + 9216, 64 * 8, 64, 72, tid);
  stage_bf(wt + 49152, Ws4 + 13824, 64 * 8, 64, 72, tid);
  __syncthreads();
  f32x4 aq[4], ak[4], av[4], as_[4];
#pragma unroll
  for (int jj = 0; jj < 4; ++jj) {
#pragma unroll
    for (int r = 0; r < 4; ++r) { aq[jj][r] = 0.f; ak[jj][r] = 0.f; av[jj][r] = 0.f; as_[jj][r] = 0.f; }
  }
  const unsigned short* xrow = Xs + (w * 16 + c) * 72 + g * 8;
#pragma unroll
  for (int kk = 0; kk < 2; ++kk) {
    bf16x8 af = *(const bf16x8*)(xrow + kk * 32);
#pragma unroll
    for (int jj = 0; jj < 4; ++jj) {
      int boff = (jj * 16 + c) * 72 + kk * 32 + g * 8;
      aq[jj] = __builtin_amdgcn_mfma_f32_16x16x32_bf16(af, *(const bf16x8*)(Ws4 + boff), aq[jj], 0, 0, 0);
      ak[jj] = __builtin_amdgcn_mfma_f32_16x16x32_bf16(af, *(const bf16x8*)(Ws4 + 4608 + boff), ak[jj], 0, 0, 0);
      av[jj] = __builtin_amdgcn_mfma_f32_16x16x32_bf16(af, *(const bf16x8*)(Ws4 + 9216 + boff), av[jj], 0, 0, 0);
      as_[jj] = __builtin_amdgcn_mfma_f32_16x16x32_bf16(af, *(const bf16x8*)(Ws4 + 13824 + boff), as_[jj], 0, 0, 0);
    }
  }
#pragma unroll
  for (int jj = 0; jj < 4; ++jj) {
    int col = jj * 16 + c;
    float bqj = bq[col], bkj = bk[col], bvj = bv[col], bsj = bs[col];
#pragma unroll
    for (int r = 0; r < 4; ++r) {
      size_t o = (size_t)(rowb + r) * 64 + col;
      us_q[o] = f2bf(aq[jj][r] + bqj);
      kv8[o] = (unsigned short)((f2e5(ak[jj][r] + bkj) << 8) | f2e5(av[jj][r] + bvj));
      us_sk[o] = f2bf(as_[jj][r] + bsj);
    }
  }
}

// ---- Bucketed CSR build ----
__global__ void k_hist(const int* __restrict__ ei, int* __restrict__ hist) {
  __shared__ int h2[2][256];
  int t = threadIdx.x;
  h2[0][t] = 0; h2[1][t] = 0;
  __syncthreads();
  int sub = (t >> 6) & 1;
  int base = blockIdx.x * 4096;
#pragma unroll
  for (int r = 0; r < 16; ++r)
    atomicAdd(&h2[sub][ei[NE + base + r * 256 + t] >> 8], 1);
  __syncthreads();
  hist[t * 256 + blockIdx.x] = h2[0][t] + h2[1][t];
}

__global__ void k_hscan(int* __restrict__ hist, int* __restrict__ btot) {
  __shared__ int s[256];
  int t = threadIdx.x, bkt = blockIdx.x;
  int v = hist[bkt * 256 + t];
  s[t] = v; __syncthreads();
  for (int off = 1; off < 256; off <<= 1) {
    int x = (t >= off) ? s[t - off] : 0;
    __syncthreads();
    s[t] += x;
    __syncthreads();
  }
  hist[bkt * 256 + t] = s[t] - v;
  if (t == 255) btot[bkt] = s[255];
}

__global__ void k_bscan(const int* __restrict__ btot, int* __restrict__ bbase) {
  __shared__ int s[256];
  int t = threadIdx.x;
  int v = btot[t];
  s[t] = v; __syncthreads();
  for (int off = 1; off < 256; off <<= 1) {
    int x = (t >= off) ? s[t - off] : 0;
    __syncthreads();
    s[t] += x;
    __syncthreads();
  }
  bbase[t] = s[t] - v;
}

__global__ void k_passB(const int* __restrict__ ei, const int* __restrict__ hist,
                        const int* __restrict__ bbase, int* __restrict__ pairs) {
  __shared__ int cur[256];
  int t = threadIdx.x;
  cur[t] = bbase[t] + hist[t * 256 + blockIdx.x];
  __syncthreads();
  int base = blockIdx.x * 4096;
#pragma unroll
  for (int r = 0; r < 16; ++r) {
    int e = base + r * 256 + t;
    int src = ei[e], dst = ei[NE + e];
    int pos = atomicAdd(&cur[dst >> 8], 1);
    pairs[pos] = ((dst & 255) << 16) | src;
  }
}

__global__ void k_passC(const int* __restrict__ pairs, const int* __restrict__ bbase,
                        const int* __restrict__ btot, int* __restrict__ rowptr,
                        int* __restrict__ srcs) {
  __shared__ int cnt[256];
  __shared__ int s[256];
  int t = threadIdx.x, bkt = blockIdx.x;
  cnt[t] = 0;
  __syncthreads();
  int base = bbase[bkt], n = btot[bkt];
  int pr[18];
#pragma unroll
  for (int j = 0; j < 18; ++j) {
    int i = t + j * 256;
    if (i >= n) break;
    int p = pairs[base + i];
    pr[j] = p;
    atomicAdd(&cnt[p >> 16], 1);
  }
  for (int i = t + 18 * 256; i < n; i += 256)
    atomicAdd(&cnt[pairs[base + i] >> 16], 1);
  __syncthreads();
  int v = cnt[t];
  s[t] = v; __syncthreads();
  for (int off = 1; off < 256; off <<= 1) {
    int x = (t >= off) ? s[t - off] : 0;
    __syncthreads();
    s[t] += x;
    __syncthreads();
  }
  int rp = base + s[t] - v;
  rowptr[bkt * 256 + t] = rp;
  if (bkt == 0 && t == 0) rowptr[NN] = NE;
  __syncthreads();
  cnt[t] = rp;
  __syncthreads();
#pragma unroll
  for (int j = 0; j < 18; ++j) {
    int i = t + j * 256;
    if (i >= n) break;
    int p = pr[j];
    int pos = atomicAdd(&cnt[p >> 16], 1);
    srcs[pos] = p & 0xFFFF;
  }
  for (int i = t + 18 * 256; i < n; i += 256) {
    int p = pairs[base + i];
    int pos = atomicAdd(&cnt[p >> 16], 1);
    srcs[pos] = p & 0xFFFF;
  }
}

// Graph attention v5 (unchanged)
__global__ void __launch_bounds__(256)
k_gattn(const unsigned short* __restrict__ us_q, const unsigned short* __restrict__ kv8,
        const int* __restrict__ rowptr, const int* __restrict__ srcs,
        const unsigned short* __restrict__ us_sk, unsigned short* __restrict__ tmpb) {
  __shared__ float red[8][32][17];
  int tid = threadIdx.x;
  int lane = tid & 63;
  int slot = (tid >> 5) & 7;
  int e = (lane >> 2) & 7, h = lane & 3;
  int dst = (blockIdx.x << 3) + slot;
  float qv[16];
  {
    const uint4* qp = (const uint4*)(us_q + (size_t)dst * 64 + h * 16);
    uint4 q0 = qp[0], q1 = qp[1];
    qv[0] = bflo(q0.x); qv[1] = bfhi(q0.x); qv[2] = bflo(q0.y); qv[3] = bfhi(q0.y);
    qv[4] = bflo(q0.z); qv[5] = bfhi(q0.z); qv[6] = bflo(q0.w); qv[7] = bfhi(q0.w);
    qv[8] = bflo(q1.x); qv[9] = bfhi(q1.x); qv[10] = bflo(q1.y); qv[11] = bfhi(q1.y);
    qv[12] = bflo(q1.z); qv[13] = bfhi(q1.z); qv[14] = bflo(q1.w); qv[15] = bfhi(q1.w);
  }
  int beg = rowptr[dst], end = rowptr[dst + 1];
  float l = 0.f;
  float acc[16];
#pragma unroll
  for (int i = 0; i < 16; ++i) acc[i] = 0.f;

  int idx = beg + e;
  int src = (idx < end) ? srcs[idx] : 0;
  const uint4* kp = (const uint4*)(kv8 + (size_t)src * 64 + h * 16);
  uint4 A = kp[0], Bv = kp[1];
  for (;;) {
    int nidx = idx + 8;
    bool any_next = __any(nidx < end);
    uint4 nA, nB;
    if (any_next) {
      int nsrc = (nidx < end) ? srcs[nidx] : 0;
      const uint4* np = (const uint4*)(kv8 + (size_t)nsrc * 64 + h * 16);
      nA = np[0]; nB = np[1];
    }
    bool valid = idx < end;
    float s;
    s  = KLO(A.x) * qv[0]   + KHI(A.x) * qv[1]   + KLO(A.y) * qv[2]   + KHI(A.y) * qv[3];
    s += KLO(A.z) * qv[4]   + KHI(A.z) * qv[5]   + KLO(A.w) * qv[6]   + KHI(A.w) * qv[7];
    s += KLO(Bv.x) * qv[8]  + KHI(Bv.x) * qv[9]  + KLO(Bv.y) * qv[10] + KHI(Bv.y) * qv[11];
    s += KLO(Bv.z) * qv[12] + KHI(Bv.z) * qv[13] + KLO(Bv.w) * qv[14] + KHI(Bv.w) * qv[15];
    float pex = valid ? __expf(s * SCL) : 0.f;
    l += pex;
    acc[0]  += pex * VLO(A.x);  acc[1]  += pex * VHI(A.x);
    acc[2]  += pex * VLO(A.y);  acc[3]  += pex * VHI(A.y);
    acc[4]  += pex * VLO(A.z);  acc[5]  += pex * VHI(A.z);
    acc[6]  += pex * VLO(A.w);  acc[7]  += pex * VHI(A.w);
    acc[8]  += pex * VLO(Bv.x); acc[9]  += pex * VHI(Bv.x);
    acc[10] += pex * VLO(Bv.y); acc[11] += pex * VHI(Bv.y);
    acc[12] += pex * VLO(Bv.z); acc[13] += pex * VHI(Bv.z);
    acc[14] += pex * VLO(Bv.w); acc[15] += pex * VHI(Bv.w);
    if (!any_next) break;
    A = nA; Bv = nB;
    idx = nidx;
  }
  l += __shfl_xor(l, 4); l += __shfl_xor(l, 8); l += __shfl_xor(l, 16);
  float* rw = &red[slot][lane & 31][0];
#pragma unroll
  for (int i = 0; i < 16; ++i) rw[i] = acc[i];
  int r32 = lane & 31;
  int h0 = r32 >> 4, i0 = r32 & 15;
  float l0 = __shfl(l, (lane & 32) + h0);
  float l1 = __shfl(l, (lane & 32) + h0 + 2);
  float s0 = 0.f, s1 = 0.f;
#pragma unroll
  for (int ep = 0; ep < 8; ++ep) {
    s0 += red[slot][ep * 4 + h0][i0];
    s1 += red[slot][ep * 4 + h0 + 2][i0];
  }
  bool nonempty = end > beg;
  float a0 = nonempty ? s0 / l0 : 0.f;
  float a1 = nonempty ? s1 / l1 : 0.f;
  size_t o0 = (size_t)dst * 64 + r32;
  tmpb[o0] = f2bf(a0 + bf2f(us_sk[o0]));
  tmpb[o0 + 32] = f2bf(a1 + bf2f(us_sk[o0 + 32]));
}

// Fused: x = LN(us_h + tmpb @ Wo + bo) -> us_h; qt,kt,vt head-major [HH][N][16]
__global__ void __launch_bounds__(256)
k_mlqkvt(const unsigned short* __restrict__ in1, const unsigned short* __restrict__ wt,
         const float* __restrict__ bias, const float* __restrict__ gam,
         const float* __restrict__ bet, unsigned short* __restrict__ us_h,
         const float* __restrict__ bqt, const float* __restrict__ bkt,
         const float* __restrict__ bvt,
         unsigned short* __restrict__ qt, unsigned short* __restrict__ kt,
         unsigned short* __restrict__ vt) {
  __shared__ unsigned short A[64 * 72];
  __shared__ unsigned short B[3 * 64 * 72];
  int tid = threadIdx.x;
  int n0 = blockIdx.x * 64;
  stage_bf(in1 + (size_t)n0 * 64, A, 64 * 8, 64, 72, tid);
  stage_bf(wt + 0, B, 64 * 8, 64, 72, tid);       // Wo
  __syncthreads();
  int lane = tid & 63, w = tid >> 6;
  int c = lane & 15, g = lane >> 4;
  f32x4 acc[4];
#pragma unroll
  for (int j = 0; j < 4; ++j) { acc[j][0] = 0.f; acc[j][1] = 0.f; acc[j][2] = 0.f; acc[j][3] = 0.f; }
  const unsigned short* xrow = A + (w * 16 + c) * 72 + g * 8;
#pragma unroll
  for (int kk = 0; kk < 2; ++kk) {
    bf16x8 af = *(const bf16x8*)(xrow + kk * 32);
#pragma unroll
    for (int j = 0; j < 4; ++j)
      acc[j] = __builtin_amdgcn_mfma_f32_16x16x32_bf16(af,
                 *(const bf16x8*)(B + (j * 16 + c) * 72 + kk * 32 + g * 8), acc[j], 0, 0, 0);
  }
  int rowb = n0 + w * 16 + 4 * g;
  float o[4][4];
#pragma unroll
  for (int j = 0; j < 4; ++j) {
    int col = j * 16 + c;
    float bb = bias[col];
#pragma unroll
    for (int r = 0; r < 4; ++r)
      o[j][r] = acc[j][r] + bb + bf2f(us_h[(size_t)(rowb + r) * 64 + col]);
  }
#pragma unroll
  for (int r = 0; r < 4; ++r) {
    float s = (o[0][r] + o[1][r]) + (o[2][r] + o[3][r]);
    float s2 = (o[0][r] * o[0][r] + o[1][r] * o[1][r]) + (o[2][r] * o[2][r] + o[3][r] * o[3][r]);
#pragma unroll
    for (int off = 1; off <= 8; off <<= 1) {
      s += __shfl_xor(s, off);
      s2 += __shfl_xor(s2, off);
    }
    float mean = s * (1.0f / 64.0f);
    float var = s2 * (1.0f / 64.0f) - mean * mean;
    float rs = rsqrtf(var + EPSLN);
#pragma unroll
    for (int j = 0; j < 4; ++j)
      o[j][r] = (o[j][r] - mean) * rs * gam[j * 16 + c] + bet[j * 16 + c];
  }
  __syncthreads();
#pragma unroll
  for (int j = 0; j < 4; ++j) {
    int col = j * 16 + c;
#pragma unroll
    for (int r = 0; r < 4; ++r) {
      unsigned short ob = f2bf(o[j][r]);
      us_h[(size_t)(rowb + r) * 64 + col] = ob;
      A[(w * 16 + 4 * g + r) * 72 + col] = ob;
    }
  }
  stage_bf(wt + 8192, B, 64 * 8, 64, 72, tid);
  stage_bf(wt + 12288, B + 4608, 64 * 8, 64, 72, tid);
  stage_bf(wt + 16384, B + 9216, 64 * 8, 64, 72, tid);
  __syncthreads();
  f32x4 aq[4], ak[4], av[4];
#pragma unroll
  for (int j = 0; j < 4; ++j) {
#pragma unroll
    for (int r = 0; r < 4; ++r) { aq[j][r] = 0.f; ak[j][r] = 0.f; av[j][r] = 0.f; }
  }
#pragma unroll
  for (int kk = 0; kk < 2; ++kk) {
    bf16x8 af = *(const bf16x8*)(xrow + kk * 32);
#pragma unroll
    for (int j = 0; j < 4; ++j) {
      int boff = (j * 16 + c) * 72 + kk * 32 + g * 8;
      aq[j] = __builtin_amdgcn_mfma_f32_16x16x32_bf16(af, *(const bf16x8*)(B + boff), aq[j], 0, 0, 0);
      ak[j] = __builtin_amdgcn_mfma_f32_16x16x32_bf16(af, *(const bf16x8*)(B + 4608 + boff), ak[j], 0, 0, 0);
      av[j] = __builtin_amdgcn_mfma_f32_16x16x32_bf16(af, *(const bf16x8*)(B + 9216 + boff), av[j], 0, 0, 0);
    }
  }
  // head-major store: head = j, dim = c
#pragma unroll
  for (int j = 0; j < 4; ++j) {
    int col = j * 16 + c;
    float bqj = bqt[col], bkj = bkt[col], bvj = bvt[col];
#pragma unroll
    for (int r = 0; r < 4; ++r) {
      size_t oo = (size_t)j * (NN * 16) + (size_t)(rowb + r) * 16 + c;
      qt[oo] = f2bf(aq[j][r] + bqj);
      kt[oo] = f2bf(ak[j][r] + bkj);
      vt[oo] = f2bf(av[j][r] + bvj);
    }
  }
}

// K8: temporal attention via MFMA; head-major inputs; Vt transposed in LDS.
#define PST 40
#define VTS 264
__global__ void __launch_bounds__(256)
k_tattn(const unsigned short* __restrict__ qtb, const unsigned short* __restrict__ ktb,
        const unsigned short* __restrict__ vtb, unsigned short* __restrict__ attnb) {
  int b = blockIdx.x >> 2, hh = blockIdx.x & 3;
  __shared__ unsigned short Qs[NFRM][16];
  __shared__ unsigned short Ks[NFRM][16];
  __shared__ unsigned short Vt[16][VTS];
  __shared__ unsigned short Ps[4][16][PST];
  int t = threadIdx.x;
  int wv = t >> 6, lane = t & 63;
  int g = lane >> 4, c = lane & 15;
  {
    size_t src = (size_t)hh * (NN * 16) + ((size_t)b * NFRM + t) * 16;
    const uint4* qsrc = (const uint4*)(qtb + src);
    const uint4* ksrc = (const uint4*)(ktb + src);
    const uint4* vsrc = (const uint4*)(vtb + src);
    ((uint4*)Qs[t])[0] = qsrc[0]; ((uint4*)Qs[t])[1] = qsrc[1];
    ((uint4*)Ks[t])[0] = ksrc[0]; ((uint4*)Ks[t])[1] = ksrc[1];
    uint4 v0 = vsrc[0], v1 = vsrc[1];
    unsigned vv[8] = {v0.x, v0.y, v0.z, v0.w, v1.x, v1.y, v1.z, v1.w};
#pragma unroll
    for (int d = 0; d < 8; ++d) {
      Vt[2 * d][t] = (unsigned short)(vv[d] & 0xFFFFu);
      Vt[2 * d + 1][t] = (unsigned short)(vv[d] >> 16);
    }
  }
  __syncthreads();
  const bf16x8 zf = {0, 0, 0, 0, 0, 0, 0, 0};
  unsigned short (*P)[PST] = Ps[wv];
  for (int qt0 = wv; qt0 < 16; qt0 += 4) {
    bf16x8 qf = zf;
    if (g < 2) qf = *(const bf16x8*)&Qs[qt0 * 16 + c][g * 8];
    f32x4 O = {0.f, 0.f, 0.f, 0.f};
    float lacc[4] = {0.f, 0.f, 0.f, 0.f};
    for (int jp = 0; jp < 8; ++jp) {
#pragma unroll
      for (int half = 0; half < 2; ++half) {
        int jt = jp * 2 + half;
        bf16x8 kf = zf;
        if (g < 2) kf = *(const bf16x8*)&Ks[jt * 16 + c][g * 8];
        f32x4 S = __builtin_amdgcn_mfma_f32_16x16x32_bf16(qf, kf,
                    (f32x4){0.f, 0.f, 0.f, 0.f}, 0, 0, 0);
#pragma unroll
        for (int r = 0; r < 4; ++r) {
          float p = __expf(S[r] * SCL);
          lacc[r] += p;
          P[4 * g + r][half * 16 + c] = f2bf(p);
        }
      }
      bf16x8 pf = *(const bf16x8*)&P[c][g * 8];
      bf16x8 vf = *(const bf16x8*)&Vt[c][jp * 32 + g * 8];
      O = __builtin_amdgcn_mfma_f32_16x16x32_bf16(pf, vf, O, 0, 0, 0);
    }
#pragma unroll
    for (int r = 0; r < 4; ++r) {
      float s = lacc[r];
      s += __shfl_xor(s, 1); s += __shfl_xor(s, 2);
      s += __shfl_xor(s, 4); s += __shfl_xor(s, 8);
      lacc[r] = 1.0f / s;
    }
    size_t obase = ((size_t)b * NFRM + qt0 * 16) * DD + hh * 16;
#pragma unroll
    for (int r = 0; r < 4; ++r)
      attnb[obase + (size_t)(4 * g + r) * DD + c] = f2bf(O[r] * lacc[r]);
  }
}

// Fused block2 (unchanged)
__global__ void __launch_bounds__(256)
k_blk2(const unsigned short* __restrict__ attn, const unsigned short* __restrict__ wt,
       const unsigned short* __restrict__ res, const float* __restrict__ bot,
       const float* __restrict__ l1g, const float* __restrict__ l1b,
       const float* __restrict__ b1, const float* __restrict__ b2,
       const float* __restrict__ l2g, const float* __restrict__ l2b,
       unsigned short* __restrict__ xtb) {
  __shared__ unsigned short XLs[64 * 72];
  __shared__ unsigned short BufW[128 * 72];
  __shared__ unsigned short BufX[64 * 136];
  int tid = threadIdx.x;
  int n0 = blockIdx.x * 64;
  int lane = tid & 63, w = tid >> 6;
  int c = lane & 15, g = lane >> 4;
  int rowb = n0 + w * 16 + 4 * g;
  stage_bf(attn + (size_t)n0 * 64, BufX, 64 * 8, 64, 72, tid);
  stage_bf(wt + 4096, BufW, 64 * 8, 64, 72, tid);
  __syncthreads();
  f32x4 acc[4];
#pragma unroll
  for (int j = 0; j < 4; ++j) { acc[j][0] = 0.f; acc[j][1] = 0.f; acc[j][2] = 0.f; acc[j][3] = 0.f; }
  const unsigned short* xrow = BufX + (w * 16 + c) * 72 + g * 8;
#pragma unroll
  for (int kk = 0; kk < 2; ++kk) {
    bf16x8 af = *(const bf16x8*)(xrow + kk * 32);
#pragma unroll
    for (int j = 0; j < 4; ++j)
      acc[j] = __builtin_amdgcn_mfma_f32_16x16x32_bf16(af,
                 *(const bf16x8*)(BufW + (j * 16 + c) * 72 + kk * 32 + g * 8), acc[j], 0, 0, 0);
  }
  float x[4][4];
#pragma unroll
  for (int j = 0; j < 4; ++j) {
    int col = j * 16 + c;
    float bb = bot[col];
#pragma unroll
    for (int r = 0; r < 4; ++r)
      x[j][r] = acc[j][r] + bb + bf2f(res[(size_t)(rowb + r) * 64 + col]);
  }
#pragma unroll
  for (int r = 0; r < 4; ++r) {
    float s = (x[0][r] + x[1][r]) + (x[2][r] + x[3][r]);
    float s2 = (x[0][r] * x[0][r] + x[1][r] * x[1][r]) + (x[2][r] * x[2][r] + x[3][r] * x[3][r]);
#pragma unroll
    for (int off = 1; off <= 8; off <<= 1) {
      s += __shfl_xor(s, off);
      s2 += __shfl_xor(s2, off);
    }
    float mean = s * (1.0f / 64.0f);
    float var = s2 * (1.0f / 64.0f) - mean * mean;
    float rs = rsqrtf(var + EPSLN);
#pragma unroll
    for (int j = 0; j < 4; ++j)
      x[j][r] = (x[j][r] - mean) * rs * l1g[j * 16 + c] + l1b[j * 16 + c];
  }
  __syncthreads();
#pragma unroll
  for (int j = 0; j < 4; ++j)
#pragma unroll
    for (int r = 0; r < 4; ++r)
      XLs[(w * 16 + 4 * g + r) * 72 + j * 16 + c] = f2bf(x[j][r]);
  stage_bf(wt + 20480, BufW, 128 * 8, 64, 72, tid);
  __syncthreads();
  f32x4 ua[8];
#pragma unroll
  for (int j = 0; j < 8; ++j) { ua[j][0] = 0.f; ua[j][1] = 0.f; ua[j][2] = 0.f; ua[j][3] = 0.f; }
  const unsigned short* xrow2 = XLs + (w * 16 + c) * 72 + g * 8;
#pragma unroll
  for (int kk = 0; kk < 2; ++kk) {
    bf16x8 af = *(const bf16x8*)(xrow2 + kk * 32);
#pragma unroll
    for (int j = 0; j < 8; ++j)
      ua[j] = __builtin_amdgcn_mfma_f32_16x16x32_bf16(af,
                *(const bf16x8*)(BufW + (j * 16 + c) * 72 + kk * 32 + g * 8), ua[j], 0, 0, 0);
  }
#pragma unroll
  for (int j = 0; j < 8; ++j) {
    int col = j * 16 + c;
    float bb = b1[col];
#pragma unroll
    for (int r = 0; r < 4; ++r)
      BufX[(w * 16 + 4 * g + r) * 136 + col] = f2bf(fmaxf(ua[j][r] + bb, 0.f));
  }
  __syncthreads();
  stage_bf(wt + 28672, BufW, 64 * 16, 128, 136, tid);
  __syncthreads();
  f32x4 ya[4];
#pragma unroll
  for (int j = 0; j < 4; ++j) { ya[j][0] = 0.f; ya[j][1] = 0.f; ya[j][2] = 0.f; ya[j][3] = 0.f; }
  const unsigned short* urow = BufX + (w * 16 + c) * 136 + g * 8;
#pragma unroll
  for (int kk = 0; kk < 4; ++kk) {
    bf16x8 af = *(const bf16x8*)(urow + kk * 32);
#pragma unroll
    for (int j = 0; j < 4; ++j)
      ya[j] = __builtin_amdgcn_mfma_f32_16x16x32_bf16(af,
                *(const bf16x8*)(BufW + (j * 16 + c) * 136 + kk * 32 + g * 8), ya[j], 0, 0, 0);
  }
  float o2[4][4];
#pragma unroll
  for (int j = 0; j < 4; ++j) {
    int col = j * 16 + c;
    float bb = b2[col];
#pragma unroll
    for (int r = 0; r < 4; ++r)
      o2[j][r] = ya[j][r] + bb + x[j][r];
  }
#pragma unroll
  for (int r = 0; r < 4; ++r) {
    float s = (o2[0][r] + o2[1][r]) + (o2[2][r] + o2[3][r]);
    float s2 = (o2[0][r] * o2[0][r] + o2[1][r] * o2[1][r]) + (o2[2][r] * o2[2][r] + o2[3][r] * o2[3][r]);
#pragma unroll
    for (int off = 1; off <= 8; off <<= 1) {
      s += __shfl_xor(s, off);
      s2 += __shfl_xor(s2, off);
    }
    float mean = s * (1.0f / 64.0f);
    float var = s2 * (1.0f / 64.0f) - mean * mean;
    float rs = rsqrtf(var + EPSLN);
#pragma unroll
    for (int j = 0; j < 4; ++j)
      xtb[(size_t)(rowb + r) * 64 + j * 16 + c] =
          f2bf((o2[j][r] - mean) * rs * l2g[j * 16 + c] + l2b[j * 16 + c]);
  }
}

// agg1 GEMM via MFMA
__global__ void __launch_bounds__(256)
k_agg1a_m(const unsigned short* __restrict__ xtb, const unsigned short* __restrict__ wa1t,
          float* __restrict__ part) {
  int ks = blockIdx.x >> 2, mt = blockIdx.x & 3;
  int t = threadIdx.x, lane = t & 63, w = t >> 6;
  int c = lane & 15, g = lane >> 4;
  int m0 = mt * 64;
  int k0 = ks * 512;
  f32x4 acc[4];
#pragma unroll
  for (int j = 0; j < 4; ++j) { acc[j][0] = 0.f; acc[j][1] = 0.f; acc[j][2] = 0.f; acc[j][3] = 0.f; }
  const unsigned short* arow = xtb + (size_t)(m0 + w * 16 + c) * 16384 + k0 + g * 8;
  const unsigned short* brow = wa1t + (size_t)c * 16384 + k0 + g * 8;
#pragma unroll 4
  for (int kk = 0; kk < 16; ++kk) {
    bf16x8 af = *(const bf16x8*)(arow + kk * 32);
#pragma unroll
    for (int j = 0; j < 4; ++j)
      acc[j] = __builtin_amdgcn_mfma_f32_16x16x32_bf16(af,
                 *(const bf16x8*)(brow + (size_t)j * 16 * 16384 + kk * 32), acc[j], 0, 0, 0);
  }
  int rowb = m0 + w * 16 + 4 * g;
#pragma unroll
  for (int j = 0; j < 4; ++j)
#pragma unroll
    for (int r = 0; r < 4; ++r)
      part[(size_t)ks * (BSZ * DD) + (size_t)(rowb + r) * 64 + j * 16 + c] = acc[j][r];
}

// K13: head MLP
__global__ void k_head(const float* __restrict__ part, const float* __restrict__ ba1,
                       const float* __restrict__ Wa2, const float* __restrict__ ba2,
                       const float* __restrict__ Wh1, const float* __restrict__ bh1,
                       const float* __restrict__ Wh2, const float* __restrict__ bh2,
                       float* __restrict__ out) {
  int b = blockIdx.x, t = threadIdx.x;
  __shared__ float s1[64], s2[32], s3[16];
  float a0 = ba1[t];
#pragma unroll 8
  for (int ks = 0; ks < AKS; ++ks) a0 += part[(size_t)ks * (BSZ * DD) + b * 64 + t];
  s1[t] = fmaxf(a0, 0.f);
  __syncthreads();
  if (t < 32) {
    float a = ba2[t];
#pragma unroll 8
    for (int j = 0; j < 64; ++j) a += s1[j] * Wa2[j * 32 + t];
    s2[t] = fmaxf(a, 0.f);
  }
  __syncthreads();
  if (t < 16) {
    float a = bh1[t];
#pragma unroll
    for (int j = 0; j < 32; ++j) a += s2[j] * Wh1[j * 16 + t];
    s3[t] = fmaxf(a, 0.f);
  }
  __syncthreads();
  if (t == 0) {
    float a = bh2[0];
#pragma unroll
    for (int j = 0; j < 16; ++j) a += s3[j] * Wh2[j];
    out[b] = 1.0f / (1.0f + expf(-a));
  }
}

extern "C" void kernel_launch(void* const* d_in, const int* in_sizes, int n_in,
                              void* d_out, int out_size, void* d_ws, size_t ws_size,
                              hipStream_t stream) {
  const float* x   = (const float*)d_in[0];
  const int*   ei  = (const int*)d_in[1];
  const float* Wi  = (const float*)d_in[2];
  const float* bi  = (const float*)d_in[3];
  const float* pe  = (const float*)d_in[4];
  const float* Wq  = (const float*)d_in[5];
  const float* Wk  = (const float*)d_in[6];
  const float* Wv  = (const float*)d_in[7];
  const float* bq  = (const float*)d_in[8];
  const float* bk  = (const float*)d_in[9];
  const float* bv  = (const float*)d_in[10];
  const float* Ws  = (const float*)d_in[11];
  const float* bs  = (const float*)d_in[12];
  const float* Wo  = (const float*)d_in[13];
  const float* bo  = (const float*)d_in[14];
  const float* gg  = (const float*)d_in[15];
  const float* gb  = (const float*)d_in[16];
  const float* Wqt = (const float*)d_in[17];
  const float* Wkt = (const float*)d_in[18];
  const float* Wvt = (const float*)d_in[19];
  const float* bqt = (const float*)d_in[20];
  const float* bkt = (const float*)d_in[21];
  const float* bvt = (const float*)d_in[22];
  const float* Wot = (const float*)d_in[23];
  const float* bot = (const float*)d_in[24];
  const float* l1g = (const float*)d_in[25];
  const float* l1b = (const float*)d_in[26];
  const float* W1  = (const float*)d_in[27];
  const float* b1  = (const float*)d_in[28];
  const float* W2  = (const float*)d_in[29];
  const float* b2  = (const float*)d_in[30];
  const float* l2g = (const float*)d_in[31];
  const float* l2b = (const float*)d_in[32];
  const float* Wa1 = (const float*)d_in[33];
  const float* ba1 = (const float*)d_in[34];
  const float* Wa2 = (const float*)d_in[35];
  const float* ba2 = (const float*)d_in[36];
  const float* Wh1 = (const float*)d_in[37];
  const float* bh1 = (const float*)d_in[38];
  const float* Wh2 = (const float*)d_in[39];
  const float* bh2 = (const float*)d_in[40];
  float* out = (float*)d_out;

  const size_t ND = (size_t)NN * DD;

  unsigned short* us_h  = (unsigned short*)d_ws;
  unsigned short* us_q  = us_h + ND;
  unsigned short* kv8   = us_q + ND;
  unsigned short* us_sk = kv8 + ND;
  unsigned short* tmpb  = us_sk + ND;
  unsigned short* us_qt = tmpb + ND;
  unsigned short* us_kt = us_qt + ND;
  unsigned short* us_vt = us_kt + ND;
  unsigned short* attnb = us_vt + ND;
  unsigned short* xtb   = attnb + ND;
  float* f_part = (float*)(xtb + ND);
  int* i_srcs   = (int*)(f_part + (size_t)AKS * BSZ * DD);
  int* i_rowptr = i_srcs + NE;
  int* i_hist   = i_rowptr + NN + 4;
  int* i_btot   = i_hist + 65536;
  int* i_bbase  = i_btot + 256;
  int* i_pairs  = i_bbase + 256;
  unsigned short* wt = (unsigned short*)(i_pairs + NE);
  unsigned short* wa1t = wt + WTN;

  dim3 B(256);
  k_wprep<<<dim3((WTN + 255) / 256), B, 0, stream>>>(Wo, Wot, Wqt, Wkt, Wvt, W1, W2,
                                                     Wq, Wk, Wv, Ws, Wi, wt);
  k_wprep2<<<dim3(256), B, 0, stream>>>(Wa1, wa1t);
  k_qkvs_m<<<dim3(NN / 64), B, 0, stream>>>(x, wt, bi, pe, bq, bk, bv, bs,
                                            us_h, us_q, kv8, us_sk);
  k_hist <<<dim3(256), B, 0, stream>>>(ei, i_hist);
  k_hscan<<<dim3(256), B, 0, stream>>>(i_hist, i_btot);
  k_bscan<<<dim3(1),   B, 0, stream>>>(i_btot, i_bbase);
  k_passB<<<dim3(256), B, 0, stream>>>(ei, i_hist, i_bbase, i_pairs);
  k_passC<<<dim3(256), B, 0, stream>>>(i_pairs, i_bbase, i_btot, i_rowptr, i_srcs);
  k_gattn<<<dim3(NN / 8), B, 0, stream>>>(us_q, kv8, i_rowptr, i_srcs, us_sk, tmpb);
  k_mlqkvt<<<dim3(NN / 64), B, 0, stream>>>(tmpb, wt, bo, gg, gb, us_h,
                                            bqt, bkt, bvt, us_qt, us_kt, us_vt);
  k_tattn<<<dim3(BSZ * HH), B, 0, stream>>>(us_qt, us_kt, us_vt, attnb);
  k_blk2<<<dim3(NN / 64), B, 0, stream>>>(attnb, wt, us_h, bot, l1g, l1b, b1, b2,
                                          l2g, l2b, xtb);
  k_agg1a_m<<<dim3(AKS * 4), B, 0, stream>>>(xtb, wa1t, f_part);
  k_head<<<dim3(BSZ), dim3(64), 0, stream>>>(f_part, ba1, Wa2, ba2, Wh1, bh1, Wh2, bh2, out);
}

// Round 15
// 167.756 us; speedup vs baseline: 1.6385x; 1.0183x over previous
//
#include <hip/hip_runtime.h>
#include <hip/hip_fp16.h>
#include <math.h>

#define NN 65536
#define SIN 24
#define DD 64
#define HH 4
#define HDIM 16
#define NFRM 256
#define NE 1048576
#define BSZ 256
#define EPSLN 1e-5f
#define SCL 0.25f
#define AKS 32
#define WTN 55296

typedef __attribute__((ext_vector_type(8))) short bf16x8;
typedef __attribute__((ext_vector_type(4))) float f32x4;

__device__ __forceinline__ unsigned short f2bf(float f) {
  unsigned u = __float_as_uint(f);
  return (unsigned short)((u + 0x7FFFu + ((u >> 16) & 1u)) >> 16);
}
__device__ __forceinline__ float bf2f(unsigned short b) {
  return __uint_as_float(((unsigned)b) << 16);
}
__device__ __forceinline__ float bflo(unsigned u) {
  return __uint_as_float(u << 16);
}
__device__ __forceinline__ float bfhi(unsigned u) {
  return __uint_as_float(u & 0xFFFF0000u);
}
__device__ __forceinline__ unsigned f2e5(float f) {
  unsigned short h = __half_as_ushort(__float2half(f));
  unsigned r = (unsigned)h + 0x7Fu + ((h >> 8) & 1u);
  return (r >> 8) & 0xFFu;
}
__device__ __forceinline__ float h2fb(unsigned short b) {
  return __half2float(__ushort_as_half(b));
}
#define KLO(u) h2fb((unsigned short)((u) & 0xFF00u))
#define KHI(u) h2fb((unsigned short)(((u) >> 16) & 0xFF00u))
#define VLO(u) h2fb((unsigned short)(((u) << 8) & 0xFF00u))
#define VHI(u) h2fb((unsigned short)(((u) >> 8) & 0xFF00u))

__device__ __forceinline__ void stage_bf(const unsigned short* __restrict__ src,
                                         unsigned short* dst, int n8, int DK, int ST, int tid) {
  int dk8 = DK >> 3;
  for (int idx = tid; idx < n8; idx += 256) {
    int row = idx / dk8, c = (idx % dk8) * 8;
    *(uint4*)(dst + row * ST + c) = *(const uint4*)(src + (size_t)row * DK + c);
  }
}

// Weight prep
__global__ void k_wprep(const float* __restrict__ Wo, const float* __restrict__ Wot,
                        const float* __restrict__ Wqt, const float* __restrict__ Wkt,
                        const float* __restrict__ Wvt, const float* __restrict__ W1,
                        const float* __restrict__ W2, const float* __restrict__ Wq,
                        const float* __restrict__ Wk, const float* __restrict__ Wv,
                        const float* __restrict__ Wsk, const float* __restrict__ Wi,
                        unsigned short* __restrict__ wt) {
  int i = blockIdx.x * 256 + threadIdx.x;
  if (i >= WTN) return;
  float v;
  if (i < 4096)       { int t = i;         int j = t >> 6, d = t & 63; v = Wo[d * 64 + j]; }
  else if (i < 8192)  { int t = i - 4096;  int j = t >> 6, d = t & 63; v = Wot[d * 64 + j]; }
  else if (i < 12288) { int t = i - 8192;  int j = t >> 6, d = t & 63; v = Wqt[d * 64 + j]; }
  else if (i < 16384) { int t = i - 12288; int j = t >> 6, d = t & 63; v = Wkt[d * 64 + j]; }
  else if (i < 20480) { int t = i - 16384; int j = t >> 6, d = t & 63; v = Wvt[d * 64 + j]; }
  else if (i < 28672) { int t = i - 20480; int j = t >> 6, d = t & 63; v = W1[d * 128 + j]; }
  else if (i < 36864) { int t = i - 28672; int j = t >> 7, d = t & 127; v = W2[d * 64 + j]; }
  else if (i < 40960) { int t = i - 36864; int j = t >> 6, d = t & 63; v = Wq[(j >> 4) * 1024 + d * 16 + (j & 15)]; }
  else if (i < 45056) { int t = i - 40960; int j = t >> 6, d = t & 63; v = Wk[(j >> 4) * 1024 + d * 16 + (j & 15)]; }
  else if (i < 49152) { int t = i - 45056; int j = t >> 6, d = t & 63; v = Wv[(j >> 4) * 1024 + d * 16 + (j & 15)]; }
  else if (i < 53248) { int t = i - 49152; int j = t >> 6, d = t & 63; v = Wsk[(j >> 4) * 1024 + d * 16 + (j & 15)]; }
  else                { int t = i - 53248; int j = t >> 5, k = t & 31; v = (k < SIN) ? Wi[k * 64 + j] : 0.f; }
  wt[i] = f2bf(v);
}

__global__ void k_wprep2(const float* __restrict__ Wa1, unsigned short* __restrict__ wa1t) {
  __shared__ float tile[64][65];
  int kb = blockIdx.x;
  int t = threadIdx.x;
  int c = t & 63, r0 = t >> 6;
  int k0 = kb * 64;
#pragma unroll
  for (int i = 0; i < 16; ++i) {
    int r = r0 + i * 4;
    tile[r][c] = Wa1[(size_t)(k0 + r) * 64 + c];
  }
  __syncthreads();
#pragma unroll
  for (int i = 0; i < 16; ++i) {
    int o = r0 + i * 4;
    wa1t[(size_t)o * 16384 + k0 + c] = f2bf(tile[c][o]);
  }
}

// Fused input + qkvs (all-MFMA)
__global__ void __launch_bounds__(256)
k_qkvs_m(const float* __restrict__ x, const unsigned short* __restrict__ wt,
         const float* __restrict__ bi, const float* __restrict__ pe,
         const float* __restrict__ bq, const float* __restrict__ bk,
         const float* __restrict__ bv, const float* __restrict__ bs,
         unsigned short* __restrict__ us_h, unsigned short* __restrict__ us_q,
         unsigned short* __restrict__ kv8, unsigned short* __restrict__ us_sk) {
  __shared__ unsigned short Xs[64 * 72];
  __shared__ unsigned short Ws4[4 * 64 * 72];
  unsigned short* Xi  = Ws4;
  unsigned short* WiS = Ws4 + 64 * 40;
  int tid = threadIdx.x;
  int n0 = blockIdx.x * 64;
  for (int idx = tid; idx < 2048; idx += 256) {
    int row = idx >> 5, k = idx & 31;
    Xi[row * 40 + k] = (k < SIN) ? f2bf(x[(size_t)(n0 + row) * SIN + k]) : 0;
    WiS[row * 40 + k] = wt[53248 + row * 32 + k];
  }
  __syncthreads();
  int lane = tid & 63, w = tid >> 6;
  int c = lane & 15, g = lane >> 4;
  int rowb = n0 + w * 16 + 4 * g;
  f32x4 hb[4];
  {
    bf16x8 xf = *(const bf16x8*)(Xi + (w * 16 + c) * 40 + g * 8);
#pragma unroll
    for (int jj = 0; jj < 4; ++jj)
      hb[jj] = __builtin_amdgcn_mfma_f32_16x16x32_bf16(xf,
                 *(const bf16x8*)(WiS + (jj * 16 + c) * 40 + g * 8),
                 (f32x4){0.f, 0.f, 0.f, 0.f}, 0, 0, 0);
  }
#pragma unroll
  for (int jj = 0; jj < 4; ++jj) {
    int col = jj * 16 + c;
    float bb = bi[col];
#pragma unroll
    for (int r = 0; r < 4; ++r) {
      int row = w * 16 + 4 * g + r;
      float hv = hb[jj][r] + bb + pe[((n0 + row) & (NFRM - 1)) * DD + col];
      unsigned short hbf = f2bf(hv);
      us_h[(size_t)(n0 + row) * DD + col] = hbf;
      Xs[row * 72 + col] = hbf;
    }
  }
  __syncthreads();
  stage_bf(wt + 36864, Ws4, 64 * 8, 64, 72, tid);
  stage_bf(wt + 40960, Ws4 + 4608, 64 * 8, 64, 72, tid);
  stage_bf(wt + 45056, Ws4 + 9216, 64 * 8, 64, 72, tid);
  stage_bf(wt + 49152, Ws4 + 13824, 64 * 8, 64, 72, tid);
  __syncthreads();
  f32x4 aq[4], ak[4], av[4], as_[4];
#pragma unroll
  for (int jj = 0; jj < 4; ++jj) {
#pragma unroll
    for (int r = 0; r < 4; ++r) { aq[jj][r] = 0.f; ak[jj][r] = 0.f; av[jj][r] = 0.f; as_[jj][r] = 0.f; }
  }
  const unsigned short* xrow = Xs + (w * 16 + c) * 72 + g * 8;
#pragma unroll
  for (int kk = 0; kk < 2; ++kk) {
    bf16x8 af = *(const bf16x8*)(xrow + kk * 32);
#pragma unroll
    for (int jj = 0; jj < 4; ++jj) {
      int boff = (jj * 16 + c) * 72 + kk * 32 + g * 8;
      aq[jj] = __builtin_amdgcn_mfma_f32_16x16x32_bf16(af, *(const bf16x8*)(Ws4 + boff), aq[jj], 0, 0, 0);
      ak[jj] = __builtin_amdgcn_mfma_f32_16x16x32_bf16(af, *(const bf16x8*)(Ws4 + 4608 + boff), ak[jj], 0, 0, 0);
      av[jj] = __builtin_amdgcn_mfma_f32_16x16x32_bf16(af, *(const bf16x8*)(Ws4 + 9216 + boff), av[jj], 0, 0, 0);
      as_[jj] = __builtin_amdgcn_mfma_f32_16x16x32_bf16(af, *(const bf16x8*)(Ws4 + 13824 + boff), as_[jj], 0, 0, 0);
    }
  }
#pragma unroll
  for (int jj = 0; jj < 4; ++jj) {
    int col = jj * 16 + c;
    float bqj = bq[col], bkj = bk[col], bvj = bv[col], bsj = bs[col];
#pragma unroll
    for (int r = 0; r < 4; ++r) {
      size_t o = (size_t)(rowb + r) * 64 + col;
      us_q[o] = f2bf(aq[jj][r] + bqj);
      kv8[o] = (unsigned short)((f2e5(ak[jj][r] + bkj) << 8) | f2e5(av[jj][r] + bvj));
      us_sk[o] = f2bf(as_[jj][r] + bsj);
    }
  }
}

// ---- Bucketed CSR build ----
__global__ void k_hist(const int* __restrict__ ei, int* __restrict__ hist) {
  __shared__ int h2[2][256];
  int t = threadIdx.x;
  h2[0][t] = 0; h2[1][t] = 0;
  __syncthreads();
  int sub = (t >> 6) & 1;
  int base = blockIdx.x * 4096;
#pragma unroll
  for (int r = 0; r < 16; ++r)
    atomicAdd(&h2[sub][ei[NE + base + r * 256 + t] >> 8], 1);
  __syncthreads();
  hist[t * 256 + blockIdx.x] = h2[0][t] + h2[1][t];
}

__global__ void k_hscan(int* __restrict__ hist, int* __restrict__ btot) {
  __shared__ int s[256];
  int t = threadIdx.x, bkt = blockIdx.x;
  int v = hist[bkt * 256 + t];
  s[t] = v; __syncthreads();
  for (int off = 1; off < 256; off <<= 1) {
    int x = (t >= off) ? s[t - off] : 0;
    __syncthreads();
    s[t] += x;
    __syncthreads();
  }
  hist[bkt * 256 + t] = s[t] - v;
  if (t == 255) btot[bkt] = s[255];
}

// passB: bucket bases derived locally from btot (no separate bscan)
__global__ void k_passB(const int* __restrict__ ei, const int* __restrict__ hist,
                        const int* __restrict__ btot, int* __restrict__ pairs) {
  __shared__ int cur[256];
  __shared__ int sc[256];
  int t = threadIdx.x;
  int v = btot[t];
  sc[t] = v; __syncthreads();
  for (int off = 1; off < 256; off <<= 1) {
    int x = (t >= off) ? sc[t - off] : 0;
    __syncthreads();
    sc[t] += x;
    __syncthreads();
  }
  cur[t] = (sc[t] - v) + hist[t * 256 + blockIdx.x];
  __syncthreads();
  int base = blockIdx.x * 4096;
#pragma unroll
  for (int r = 0; r < 16; ++r) {
    int e = base + r * 256 + t;
    int src = ei[e], dst = ei[NE + e];
    int pos = atomicAdd(&cur[dst >> 8], 1);
    pairs[pos] = ((dst & 255) << 16) | src;
  }
}

// passC: ushort srcs out; bucket base derived locally
__global__ void k_passC(const int* __restrict__ pairs, const int* __restrict__ btot,
                        int* __restrict__ rowptr, unsigned short* __restrict__ srcs) {
  __shared__ int cnt[256];
  __shared__ int s[256];
  __shared__ int eb[256];
  int t = threadIdx.x, bkt = blockIdx.x;
  {
    int v0 = btot[t];
    s[t] = v0; __syncthreads();
    for (int off = 1; off < 256; off <<= 1) {
      int x = (t >= off) ? s[t - off] : 0;
      __syncthreads();
      s[t] += x;
      __syncthreads();
    }
    eb[t] = s[t] - v0;
  }
  cnt[t] = 0;
  __syncthreads();
  int base = eb[bkt], n = btot[bkt];
  int pr[18];
#pragma unroll
  for (int j = 0; j < 18; ++j) {
    int i = t + j * 256;
    if (i >= n) break;
    int p = pairs[base + i];
    pr[j] = p;
    atomicAdd(&cnt[p >> 16], 1);
  }
  for (int i = t + 18 * 256; i < n; i += 256)
    atomicAdd(&cnt[pairs[base + i] >> 16], 1);
  __syncthreads();
  int v = cnt[t];
  s[t] = v; __syncthreads();
  for (int off = 1; off < 256; off <<= 1) {
    int x = (t >= off) ? s[t - off] : 0;
    __syncthreads();
    s[t] += x;
    __syncthreads();
  }
  int rp = base + s[t] - v;
  rowptr[bkt * 256 + t] = rp;
  if (bkt == 0 && t == 0) rowptr[NN] = NE;
  __syncthreads();
  cnt[t] = rp;
  __syncthreads();
#pragma unroll
  for (int j = 0; j < 18; ++j) {
    int i = t + j * 256;
    if (i >= n) break;
    int p = pr[j];
    int pos = atomicAdd(&cnt[p >> 16], 1);
    srcs[pos] = (unsigned short)(p & 0xFFFF);
  }
  for (int i = t + 18 * 256; i < n; i += 256) {
    int p = pairs[base + i];
    int pos = atomicAdd(&cnt[p >> 16], 1);
    srcs[pos] = (unsigned short)(p & 0xFFFF);
  }
}

// Graph attention v6: half-wave per dst; srcs pre-loaded for batches 1-2
// (independent loads, off the gather chain); e5m2 kv8 gather; bf16 I/O.
__global__ void __launch_bounds__(256)
k_gattn(const unsigned short* __restrict__ us_q, const unsigned short* __restrict__ kv8,
        const int* __restrict__ rowptr, const unsigned short* __restrict__ srcs,
        const unsigned short* __restrict__ us_sk, unsigned short* __restrict__ tmpb) {
  __shared__ float red[8][32][17];
  int tid = threadIdx.x;
  int lane = tid & 63;
  int slot = (tid >> 5) & 7;
  int e = (lane >> 2) & 7, h = lane & 3;
  int dst = (blockIdx.x << 3) + slot;
  float qv[16];
  {
    const uint4* qp = (const uint4*)(us_q + (size_t)dst * 64 + h * 16);
    uint4 q0 = qp[0], q1 = qp[1];
    qv[0] = bflo(q0.x); qv[1] = bfhi(q0.x); qv[2] = bflo(q0.y); qv[3] = bfhi(q0.y);
    qv[4] = bflo(q0.z); qv[5] = bfhi(q0.z); qv[6] = bflo(q0.w); qv[7] = bfhi(q0.w);
    qv[8] = bflo(q1.x); qv[9] = bfhi(q1.x); qv[10] = bflo(q1.y); qv[11] = bfhi(q1.y);
    qv[12] = bflo(q1.z); qv[13] = bfhi(q1.z); qv[14] = bflo(q1.w); qv[15] = bfhi(q1.w);
  }
  int beg = rowptr[dst], end = rowptr[dst + 1];
  float l = 0.f;
  float acc[16];
#pragma unroll
  for (int i = 0; i < 16; ++i) acc[i] = 0.f;

  int idx = beg + e;
  int src0 = (idx < end) ? (int)srcs[idx] : 0;
  int psrc1 = (idx + 8 < end) ? (int)srcs[idx + 8] : 0;
  int psrc2 = (idx + 16 < end) ? (int)srcs[idx + 16] : 0;
  const uint4* kp = (const uint4*)(kv8 + (size_t)src0 * 64 + h * 16);
  uint4 A = kp[0], Bv = kp[1];
  int batch = 0;
  for (;;) {
    int nidx = idx + 8;
    bool any_next = __any(nidx < end);
    uint4 nA, nB;
    if (any_next) {
      int nsrc = (batch == 0) ? psrc1
               : (batch == 1) ? psrc2
               : ((nidx < end) ? (int)srcs[nidx] : 0);
      const uint4* np = (const uint4*)(kv8 + (size_t)nsrc * 64 + h * 16);
      nA = np[0]; nB = np[1];
    }
    bool valid = idx < end;
    float s;
    s  = KLO(A.x) * qv[0]   + KHI(A.x) * qv[1]   + KLO(A.y) * qv[2]   + KHI(A.y) * qv[3];
    s += KLO(A.z) * qv[4]   + KHI(A.z) * qv[5]   + KLO(A.w) * qv[6]   + KHI(A.w) * qv[7];
    s += KLO(Bv.x) * qv[8]  + KHI(Bv.x) * qv[9]  + KLO(Bv.y) * qv[10] + KHI(Bv.y) * qv[11];
    s += KLO(Bv.z) * qv[12] + KHI(Bv.z) * qv[13] + KLO(Bv.w) * qv[14] + KHI(Bv.w) * qv[15];
    float pex = valid ? __expf(s * SCL) : 0.f;
    l += pex;
    acc[0]  += pex * VLO(A.x);  acc[1]  += pex * VHI(A.x);
    acc[2]  += pex * VLO(A.y);  acc[3]  += pex * VHI(A.y);
    acc[4]  += pex * VLO(A.z);  acc[5]  += pex * VHI(A.z);
    acc[6]  += pex * VLO(A.w);  acc[7]  += pex * VHI(A.w);
    acc[8]  += pex * VLO(Bv.x); acc[9]  += pex * VHI(Bv.x);
    acc[10] += pex * VLO(Bv.y); acc[11] += pex * VHI(Bv.y);
    acc[12] += pex * VLO(Bv.z); acc[13] += pex * VHI(Bv.z);
    acc[14] += pex * VLO(Bv.w); acc[15] += pex * VHI(Bv.w);
    if (!any_next) break;
    A = nA; Bv = nB;
    idx = nidx;
    ++batch;
  }
  l += __shfl_xor(l, 4); l += __shfl_xor(l, 8); l += __shfl_xor(l, 16);
  float* rw = &red[slot][lane & 31][0];
#pragma unroll
  for (int i = 0; i < 16; ++i) rw[i] = acc[i];
  int r32 = lane & 31;
  int h0 = r32 >> 4, i0 = r32 & 15;
  float l0 = __shfl(l, (lane & 32) + h0);
  float l1 = __shfl(l, (lane & 32) + h0 + 2);
  float s0 = 0.f, s1 = 0.f;
#pragma unroll
  for (int ep = 0; ep < 8; ++ep) {
    s0 += red[slot][ep * 4 + h0][i0];
    s1 += red[slot][ep * 4 + h0 + 2][i0];
  }
  bool nonempty = end > beg;
  float a0 = nonempty ? s0 / l0 : 0.f;
  float a1 = nonempty ? s1 / l1 : 0.f;
  size_t o0 = (size_t)dst * 64 + r32;
  tmpb[o0] = f2bf(a0 + bf2f(us_sk[o0]));
  tmpb[o0 + 32] = f2bf(a1 + bf2f(us_sk[o0 + 32]));
}

// Fused: x = LN(us_h + tmpb @ Wo + bo) -> us_h; qt,kt,vt head-major [HH][N][16]
__global__ void __launch_bounds__(256)
k_mlqkvt(const unsigned short* __restrict__ in1, const unsigned short* __restrict__ wt,
         const float* __restrict__ bias, const float* __restrict__ gam,
         const float* __restrict__ bet, unsigned short* __restrict__ us_h,
         const float* __restrict__ bqt, const float* __restrict__ bkt,
         const float* __restrict__ bvt,
         unsigned short* __restrict__ qt, unsigned short* __restrict__ kt,
         unsigned short* __restrict__ vt) {
  __shared__ unsigned short A[64 * 72];
  __shared__ unsigned short B[3 * 64 * 72];
  int tid = threadIdx.x;
  int n0 = blockIdx.x * 64;
  stage_bf(in1 + (size_t)n0 * 64, A, 64 * 8, 64, 72, tid);
  stage_bf(wt + 0, B, 64 * 8, 64, 72, tid);
  __syncthreads();
  int lane = tid & 63, w = tid >> 6;
  int c = lane & 15, g = lane >> 4;
  f32x4 acc[4];
#pragma unroll
  for (int j = 0; j < 4; ++j) { acc[j][0] = 0.f; acc[j][1] = 0.f; acc[j][2] = 0.f; acc[j][3] = 0.f; }
  const unsigned short* xrow = A + (w * 16 + c) * 72 + g * 8;
#pragma unroll
  for (int kk = 0; kk < 2; ++kk) {
    bf16x8 af = *(const bf16x8*)(xrow + kk * 32);
#pragma unroll
    for (int j = 0; j < 4; ++j)
      acc[j] = __builtin_amdgcn_mfma_f32_16x16x32_bf16(af,
                 *(const bf16x8*)(B + (j * 16 + c) * 72 + kk * 32 + g * 8), acc[j], 0, 0, 0);
  }
  int rowb = n0 + w * 16 + 4 * g;
  float o[4][4];
#pragma unroll
  for (int j = 0; j < 4; ++j) {
    int col = j * 16 + c;
    float bb = bias[col];
#pragma unroll
    for (int r = 0; r < 4; ++r)
      o[j][r] = acc[j][r] + bb + bf2f(us_h[(size_t)(rowb + r) * 64 + col]);
  }
#pragma unroll
  for (int r = 0; r < 4; ++r) {
    float s = (o[0][r] + o[1][r]) + (o[2][r] + o[3][r]);
    float s2 = (o[0][r] * o[0][r] + o[1][r] * o[1][r]) + (o[2][r] * o[2][r] + o[3][r] * o[3][r]);
#pragma unroll
    for (int off = 1; off <= 8; off <<= 1) {
      s += __shfl_xor(s, off);
      s2 += __shfl_xor(s2, off);
    }
    float mean = s * (1.0f / 64.0f);
    float var = s2 * (1.0f / 64.0f) - mean * mean;
    float rs = rsqrtf(var + EPSLN);
#pragma unroll
    for (int j = 0; j < 4; ++j)
      o[j][r] = (o[j][r] - mean) * rs * gam[j * 16 + c] + bet[j * 16 + c];
  }
  __syncthreads();
#pragma unroll
  for (int j = 0; j < 4; ++j) {
    int col = j * 16 + c;
#pragma unroll
    for (int r = 0; r < 4; ++r) {
      unsigned short ob = f2bf(o[j][r]);
      us_h[(size_t)(rowb + r) * 64 + col] = ob;
      A[(w * 16 + 4 * g + r) * 72 + col] = ob;
    }
  }
  stage_bf(wt + 8192, B, 64 * 8, 64, 72, tid);
  stage_bf(wt + 12288, B + 4608, 64 * 8, 64, 72, tid);
  stage_bf(wt + 16384, B + 9216, 64 * 8, 64, 72, tid);
  __syncthreads();
  f32x4 aq[4], ak[4], av[4];
#pragma unroll
  for (int j = 0; j < 4; ++j) {
#pragma unroll
    for (int r = 0; r < 4; ++r) { aq[j][r] = 0.f; ak[j][r] = 0.f; av[j][r] = 0.f; }
  }
#pragma unroll
  for (int kk = 0; kk < 2; ++kk) {
    bf16x8 af = *(const bf16x8*)(xrow + kk * 32);
#pragma unroll
    for (int j = 0; j < 4; ++j) {
      int boff = (j * 16 + c) * 72 + kk * 32 + g * 8;
      aq[j] = __builtin_amdgcn_mfma_f32_16x16x32_bf16(af, *(const bf16x8*)(B + boff), aq[j], 0, 0, 0);
      ak[j] = __builtin_amdgcn_mfma_f32_16x16x32_bf16(af, *(const bf16x8*)(B + 4608 + boff), ak[j], 0, 0, 0);
      av[j] = __builtin_amdgcn_mfma_f32_16x16x32_bf16(af, *(const bf16x8*)(B + 9216 + boff), av[j], 0, 0, 0);
    }
  }
#pragma unroll
  for (int j = 0; j < 4; ++j) {
    int col = j * 16 + c;
    float bqj = bqt[col], bkj = bkt[col], bvj = bvt[col];
#pragma unroll
    for (int r = 0; r < 4; ++r) {
      size_t oo = (size_t)j * (NN * 16) + (size_t)(rowb + r) * 16 + c;
      qt[oo] = f2bf(aq[j][r] + bqj);
      kt[oo] = f2bf(ak[j][r] + bkj);
      vt[oo] = f2bf(av[j][r] + bvj);
    }
  }
}

// K8: temporal attention via MFMA; head-major inputs; Vt transposed in LDS.
#define PST 40
#define VTS 264
__global__ void __launch_bounds__(256)
k_tattn(const unsigned short* __restrict__ qtb, const unsigned short* __restrict__ ktb,
        const unsigned short* __restrict__ vtb, unsigned short* __restrict__ attnb) {
  int b = blockIdx.x >> 2, hh = blockIdx.x & 3;
  __shared__ unsigned short Qs[NFRM][16];
  __shared__ unsigned short Ks[NFRM][16];
  __shared__ unsigned short Vt[16][VTS];
  __shared__ unsigned short Ps[4][16][PST];
  int t = threadIdx.x;
  int wv = t >> 6, lane = t & 63;
  int g = lane >> 4, c = lane & 15;
  {
    size_t src = (size_t)hh * (NN * 16) + ((size_t)b * NFRM + t) * 16;
    const uint4* qsrc = (const uint4*)(qtb + src);
    const uint4* ksrc = (const uint4*)(ktb + src);
    const uint4* vsrc = (const uint4*)(vtb + src);
    ((uint4*)Qs[t])[0] = qsrc[0]; ((uint4*)Qs[t])[1] = qsrc[1];
    ((uint4*)Ks[t])[0] = ksrc[0]; ((uint4*)Ks[t])[1] = ksrc[1];
    uint4 v0 = vsrc[0], v1 = vsrc[1];
    unsigned vv[8] = {v0.x, v0.y, v0.z, v0.w, v1.x, v1.y, v1.z, v1.w};
#pragma unroll
    for (int d = 0; d < 8; ++d) {
      Vt[2 * d][t] = (unsigned short)(vv[d] & 0xFFFFu);
      Vt[2 * d + 1][t] = (unsigned short)(vv[d] >> 16);
    }
  }
  __syncthreads();
  const bf16x8 zf = {0, 0, 0, 0, 0, 0, 0, 0};
  unsigned short (*P)[PST] = Ps[wv];
  for (int qt0 = wv; qt0 < 16; qt0 += 4) {
    bf16x8 qf = zf;
    if (g < 2) qf = *(const bf16x8*)&Qs[qt0 * 16 + c][g * 8];
    f32x4 O = {0.f, 0.f, 0.f, 0.f};
    float lacc[4] = {0.f, 0.f, 0.f, 0.f};
    for (int jp = 0; jp < 8; ++jp) {
#pragma unroll
      for (int half = 0; half < 2; ++half) {
        int jt = jp * 2 + half;
        bf16x8 kf = zf;
        if (g < 2) kf = *(const bf16x8*)&Ks[jt * 16 + c][g * 8];
        f32x4 S = __builtin_amdgcn_mfma_f32_16x16x32_bf16(qf, kf,
                    (f32x4){0.f, 0.f, 0.f, 0.f}, 0, 0, 0);
#pragma unroll
        for (int r = 0; r < 4; ++r) {
          float p = __expf(S[r] * SCL);
          lacc[r] += p;
          P[4 * g + r][half * 16 + c] = f2bf(p);
        }
      }
      bf16x8 pf = *(const bf16x8*)&P[c][g * 8];
      bf16x8 vf = *(const bf16x8*)&Vt[c][jp * 32 + g * 8];
      O = __builtin_amdgcn_mfma_f32_16x16x32_bf16(pf, vf, O, 0, 0, 0);
    }
#pragma unroll
    for (int r = 0; r < 4; ++r) {
      float s = lacc[r];
      s += __shfl_xor(s, 1); s += __shfl_xor(s, 2);
      s += __shfl_xor(s, 4); s += __shfl_xor(s, 8);
      lacc[r] = 1.0f / s;
    }
    size_t obase = ((size_t)b * NFRM + qt0 * 16) * DD + hh * 16;
#pragma unroll
    for (int r = 0; r < 4; ++r)
      attnb[obase + (size_t)(4 * g + r) * DD + c] = f2bf(O[r] * lacc[r]);
  }
}

// Fused block2
__global__ void __launch_bounds__(256)
k_blk2(const unsigned short* __restrict__ attn, const unsigned short* __restrict__ wt,
       const unsigned short* __restrict__ res, const float* __restrict__ bot,
       const float* __restrict__ l1g, const float* __restrict__ l1b,
       const float* __restrict__ b1, const float* __restrict__ b2,
       const float* __restrict__ l2g, const float* __restrict__ l2b,
       unsigned short* __restrict__ xtb) {
  __shared__ unsigned short XLs[64 * 72];
  __shared__ unsigned short BufW[128 * 72];
  __shared__ unsigned short BufX[64 * 136];
  int tid = threadIdx.x;
  int n0 = blockIdx.x * 64;
  int lane = tid & 63, w = tid >> 6;
  int c = lane & 15, g = lane >> 4;
  int rowb = n0 + w * 16 + 4 * g;
  stage_bf(attn + (size_t)n0 * 64, BufX, 64 * 8, 64, 72, tid);
  stage_bf(wt + 4096, BufW, 64 * 8, 64, 72, tid);
  __syncthreads();
  f32x4 acc[4];
#pragma unroll
  for (int j = 0; j < 4; ++j) { acc[j][0] = 0.f; acc[j][1] = 0.f; acc[j][2] = 0.f; acc[j][3] = 0.f; }
  const unsigned short* xrow = BufX + (w * 16 + c) * 72 + g * 8;
#pragma unroll
  for (int kk = 0; kk < 2; ++kk) {
    bf16x8 af = *(const bf16x8*)(xrow + kk * 32);
#pragma unroll
    for (int j = 0; j < 4; ++j)
      acc[j] = __builtin_amdgcn_mfma_f32_16x16x32_bf16(af,
                 *(const bf16x8*)(BufW + (j * 16 + c) * 72 + kk * 32 + g * 8), acc[j], 0, 0, 0);
  }
  float x[4][4];
#pragma unroll
  for (int j = 0; j < 4; ++j) {
    int col = j * 16 + c;
    float bb = bot[col];
#pragma unroll
    for (int r = 0; r < 4; ++r)
      x[j][r] = acc[j][r] + bb + bf2f(res[(size_t)(rowb + r) * 64 + col]);
  }
#pragma unroll
  for (int r = 0; r < 4; ++r) {
    float s = (x[0][r] + x[1][r]) + (x[2][r] + x[3][r]);
    float s2 = (x[0][r] * x[0][r] + x[1][r] * x[1][r]) + (x[2][r] * x[2][r] + x[3][r] * x[3][r]);
#pragma unroll
    for (int off = 1; off <= 8; off <<= 1) {
      s += __shfl_xor(s, off);
      s2 += __shfl_xor(s2, off);
    }
    float mean = s * (1.0f / 64.0f);
    float var = s2 * (1.0f / 64.0f) - mean * mean;
    float rs = rsqrtf(var + EPSLN);
#pragma unroll
    for (int j = 0; j < 4; ++j)
      x[j][r] = (x[j][r] - mean) * rs * l1g[j * 16 + c] + l1b[j * 16 + c];
  }
  __syncthreads();
#pragma unroll
  for (int j = 0; j < 4; ++j)
#pragma unroll
    for (int r = 0; r < 4; ++r)
      XLs[(w * 16 + 4 * g + r) * 72 + j * 16 + c] = f2bf(x[j][r]);
  stage_bf(wt + 20480, BufW, 128 * 8, 64, 72, tid);
  __syncthreads();
  f32x4 ua[8];
#pragma unroll
  for (int j = 0; j < 8; ++j) { ua[j][0] = 0.f; ua[j][1] = 0.f; ua[j][2] = 0.f; ua[j][3] = 0.f; }
  const unsigned short* xrow2 = XLs + (w * 16 + c) * 72 + g * 8;
#pragma unroll
  for (int kk = 0; kk < 2; ++kk) {
    bf16x8 af = *(const bf16x8*)(xrow2 + kk * 32);
#pragma unroll
    for (int j = 0; j < 8; ++j)
      ua[j] = __builtin_amdgcn_mfma_f32_16x16x32_bf16(af,
                *(const bf16x8*)(BufW + (j * 16 + c) * 72 + kk * 32 + g * 8), ua[j], 0, 0, 0);
  }
#pragma unroll
  for (int j = 0; j < 8; ++j) {
    int col = j * 16 + c;
    float bb = b1[col];
#pragma unroll
    for (int r = 0; r < 4; ++r)
      BufX[(w * 16 + 4 * g + r) * 136 + col] = f2bf(fmaxf(ua[j][r] + bb, 0.f));
  }
  __syncthreads();
  stage_bf(wt + 28672, BufW, 64 * 16, 128, 136, tid);
  __syncthreads();
  f32x4 ya[4];
#pragma unroll
  for (int j = 0; j < 4; ++j) { ya[j][0] = 0.f; ya[j][1] = 0.f; ya[j][2] = 0.f; ya[j][3] = 0.f; }
  const unsigned short* urow = BufX + (w * 16 + c) * 136 + g * 8;
#pragma unroll
  for (int kk = 0; kk < 4; ++kk) {
    bf16x8 af = *(const bf16x8*)(urow + kk * 32);
#pragma unroll
    for (int j = 0; j < 4; ++j)
      ya[j] = __builtin_amdgcn_mfma_f32_16x16x32_bf16(af,
                *(const bf16x8*)(BufW + (j * 16 + c) * 136 + kk * 32 + g * 8), ya[j], 0, 0, 0);
  }
  float o2[4][4];
#pragma unroll
  for (int j = 0; j < 4; ++j) {
    int col = j * 16 + c;
    float bb = b2[col];
#pragma unroll
    for (int r = 0; r < 4; ++r)
      o2[j][r] = ya[j][r] + bb + x[j][r];
  }
#pragma unroll
  for (int r = 0; r < 4; ++r) {
    float s = (o2[0][r] + o2[1][r]) + (o2[2][r] + o2[3][r]);
    float s2 = (o2[0][r] * o2[0][r] + o2[1][r] * o2[1][r]) + (o2[2][r] * o2[2][r] + o2[3][r] * o2[3][r]);
#pragma unroll
    for (int off = 1; off <= 8; off <<= 1) {
      s += __shfl_xor(s, off);
      s2 += __shfl_xor(s2, off);
    }
    float mean = s * (1.0f / 64.0f);
    float var = s2 * (1.0f / 64.0f) - mean * mean;
    float rs = rsqrtf(var + EPSLN);
#pragma unroll
    for (int j = 0; j < 4; ++j)
      xtb[(size_t)(rowb + r) * 64 + j * 16 + c] =
          f2bf((o2[j][r] - mean) * rs * l2g[j * 16 + c] + l2b[j * 16 + c]);
  }
}

// agg1 GEMM via MFMA
__global__ void __launch_bounds__(256)
k_agg1a_m(const unsigned short* __restrict__ xtb, const unsigned short* __restrict__ wa1t,
          float* __restrict__ part) {
  int ks = blockIdx.x >> 2, mt = blockIdx.x & 3;
  int t = threadIdx.x, lane = t & 63, w = t >> 6;
  int c = lane & 15, g = lane >> 4;
  int m0 = mt * 64;
  int k0 = ks * 512;
  f32x4 acc[4];
#pragma unroll
  for (int j = 0; j < 4; ++j) { acc[j][0] = 0.f; acc[j][1] = 0.f; acc[j][2] = 0.f; acc[j][3] = 0.f; }
  const unsigned short* arow = xtb + (size_t)(m0 + w * 16 + c) * 16384 + k0 + g * 8;
  const unsigned short* brow = wa1t + (size_t)c * 16384 + k0 + g * 8;
#pragma unroll 4
  for (int kk = 0; kk < 16; ++kk) {
    bf16x8 af = *(const bf16x8*)(arow + kk * 32);
#pragma unroll
    for (int j = 0; j < 4; ++j)
      acc[j] = __builtin_amdgcn_mfma_f32_16x16x32_bf16(af,
                 *(const bf16x8*)(brow + (size_t)j * 16 * 16384 + kk * 32), acc[j], 0, 0, 0);
  }
  int rowb = m0 + w * 16 + 4 * g;
#pragma unroll
  for (int j = 0; j < 4; ++j)
#pragma unroll
    for (int r = 0; r < 4; ++r)
      part[(size_t)ks * (BSZ * DD) + (size_t)(rowb + r) * 64 + j * 16 + c] = acc[j][r];
}

// K13: head MLP
__global__ void k_head(const float* __restrict__ part, const float* __restrict__ ba1,
                       const float* __restrict__ Wa2, const float* __restrict__ ba2,
                       const float* __restrict__ Wh1, const float* __restrict__ bh1,
                       const float* __restrict__ Wh2, const float* __restrict__ bh2,
                       float* __restrict__ out) {
  int b = blockIdx.x, t = threadIdx.x;
  __shared__ float s1[64], s2[32], s3[16];
  float a0 = ba1[t];
#pragma unroll 8
  for (int ks = 0; ks < AKS; ++ks) a0 += part[(size_t)ks * (BSZ * DD) + b * 64 + t];
  s1[t] = fmaxf(a0, 0.f);
  __syncthreads();
  if (t < 32) {
    float a = ba2[t];
#pragma unroll 8
    for (int j = 0; j < 64; ++j) a += s1[j] * Wa2[j * 32 + t];
    s2[t] = fmaxf(a, 0.f);
  }
  __syncthreads();
  if (t < 16) {
    float a = bh1[t];
#pragma unroll
    for (int j = 0; j < 32; ++j) a += s2[j] * Wh1[j * 16 + t];
    s3[t] = fmaxf(a, 0.f);
  }
  __syncthreads();
  if (t == 0) {
    float a = bh2[0];
#pragma unroll
    for (int j = 0; j < 16; ++j) a += s3[j] * Wh2[j];
    out[b] = 1.0f / (1.0f + expf(-a));
  }
}

extern "C" void kernel_launch(void* const* d_in, const int* in_sizes, int n_in,
                              void* d_out, int out_size, void* d_ws, size_t ws_size,
                              hipStream_t stream) {
  const float* x   = (const float*)d_in[0];
  const int*   ei  = (const int*)d_in[1];
  const float* Wi  = (const float*)d_in[2];
  const float* bi  = (const float*)d_in[3];
  const float* pe  = (const float*)d_in[4];
  const float* Wq  = (const float*)d_in[5];
  const float* Wk  = (const float*)d_in[6];
  const float* Wv  = (const float*)d_in[7];
  const float* bq  = (const float*)d_in[8];
  const float* bk  = (const float*)d_in[9];
  const float* bv  = (const float*)d_in[10];
  const float* Ws  = (const float*)d_in[11];
  const float* bs  = (const float*)d_in[12];
  const float* Wo  = (const float*)d_in[13];
  const float* bo  = (const float*)d_in[14];
  const float* gg  = (const float*)d_in[15];
  const float* gb  = (const float*)d_in[16];
  const float* Wqt = (const float*)d_in[17];
  const float* Wkt = (const float*)d_in[18];
  const float* Wvt = (const float*)d_in[19];
  const float* bqt = (const float*)d_in[20];
  const float* bkt = (const float*)d_in[21];
  const float* bvt = (const float*)d_in[22];
  const float* Wot = (const float*)d_in[23];
  const float* bot = (const float*)d_in[24];
  const float* l1g = (const float*)d_in[25];
  const float* l1b = (const float*)d_in[26];
  const float* W1  = (const float*)d_in[27];
  const float* b1  = (const float*)d_in[28];
  const float* W2  = (const float*)d_in[29];
  const float* b2  = (const float*)d_in[30];
  const float* l2g = (const float*)d_in[31];
  const float* l2b = (const float*)d_in[32];
  const float* Wa1 = (const float*)d_in[33];
  const float* ba1 = (const float*)d_in[34];
  const float* Wa2 = (const float*)d_in[35];
  const float* ba2 = (const float*)d_in[36];
  const float* Wh1 = (const float*)d_in[37];
  const float* bh1 = (const float*)d_in[38];
  const float* Wh2 = (const float*)d_in[39];
  const float* bh2 = (const float*)d_in[40];
  float* out = (float*)d_out;

  const size_t ND = (size_t)NN * DD;

  unsigned short* us_h  = (unsigned short*)d_ws;
  unsigned short* us_q  = us_h + ND;
  unsigned short* kv8   = us_q + ND;
  unsigned short* us_sk = kv8 + ND;
  unsigned short* tmpb  = us_sk + ND;
  unsigned short* us_qt = tmpb + ND;
  unsigned short* us_kt = us_qt + ND;
  unsigned short* us_vt = us_kt + ND;
  unsigned short* attnb = us_vt + ND;
  unsigned short* xtb   = attnb + ND;
  float* f_part = (float*)(xtb + ND);
  unsigned short* us_srcs = (unsigned short*)(f_part + (size_t)AKS * BSZ * DD);  // [NE]
  int* i_rowptr = (int*)(us_srcs + NE);
  int* i_hist   = i_rowptr + NN + 4;
  int* i_btot   = i_hist + 65536;
  int* i_pairs  = i_btot + 256;
  unsigned short* wt = (unsigned short*)(i_pairs + NE);
  unsigned short* wa1t = wt + WTN;

  dim3 B(256);
  k_wprep<<<dim3((WTN + 255) / 256), B, 0, stream>>>(Wo, Wot, Wqt, Wkt, Wvt, W1, W2,
                                                     Wq, Wk, Wv, Ws, Wi, wt);
  k_wprep2<<<dim3(256), B, 0, stream>>>(Wa1, wa1t);
  k_qkvs_m<<<dim3(NN / 64), B, 0, stream>>>(x, wt, bi, pe, bq, bk, bv, bs,
                                            us_h, us_q, kv8, us_sk);
  k_hist <<<dim3(256), B, 0, stream>>>(ei, i_hist);
  k_hscan<<<dim3(256), B, 0, stream>>>(i_hist, i_btot);
  k_passB<<<dim3(256), B, 0, stream>>>(ei, i_hist, i_btot, i_pairs);
  k_passC<<<dim3(256), B, 0, stream>>>(i_pairs, i_btot, i_rowptr, us_srcs);
  k_gattn<<<dim3(NN / 8), B, 0, stream>>>(us_q, kv8, i_rowptr, us_srcs, us_sk, tmpb);
  k_mlqkvt<<<dim3(NN / 64), B, 0, stream>>>(tmpb, wt, bo, gg, gb, us_h,
                                            bqt, bkt, bvt, us_qt, us_kt, us_vt);
  k_tattn<<<dim3(BSZ * HH), B, 0, stream>>>(us_qt, us_kt, us_vt, attnb);
  k_blk2<<<dim3(NN / 64), B, 0, stream>>>(attnb, wt, us_h, bot, l1g, l1b, b1, b2,
                                          l2g, l2b, xtb);
  k_agg1a_m<<<dim3(AKS * 4), B, 0, stream>>>(xtb, wa1t, f_part);
  k_head<<<dim3(BSZ), dim3(64), 0, stream>>>(f_part, ba1, Wa2, ba2, Wh1, bh1, Wh2, bh2, out);
}